// Round 4
// baseline (5282.245 us; speedup 1.0000x reference)
//
#include <hip/hip_runtime.h>
#include <math.h>
#include <stdint.h>

#define N_ 512
#define D_ 64
#define K_ 10
#define S_ 10
#define INDIM_ 784
#define H_ 512
#define DP1 (D_ + 1)

// ---------------- JAX Threefry-2x32 (20 rounds) ----------------
__device__ __forceinline__ uint32_t rotl32(uint32_t v, int r) { return (v << r) | (v >> (32 - r)); }

__device__ __forceinline__ void threefry2x32(uint32_t k0, uint32_t k1,
                                             uint32_t x0, uint32_t x1,
                                             uint32_t& o0, uint32_t& o1) {
  uint32_t k2 = k0 ^ k1 ^ 0x1BD11BDAu;
  x0 += k0; x1 += k1;
#define TFR(r) { x0 += x1; x1 = rotl32(x1, r); x1 ^= x0; }
  TFR(13) TFR(15) TFR(26) TFR(6)
  x0 += k1; x1 += k2 + 1u;
  TFR(17) TFR(29) TFR(16) TFR(24)
  x0 += k2; x1 += k0 + 2u;
  TFR(13) TFR(15) TFR(26) TFR(6)
  x0 += k0; x1 += k1 + 3u;
  TFR(17) TFR(29) TFR(16) TFR(24)
  x0 += k1; x1 += k2 + 4u;
  TFR(13) TFR(15) TFR(26) TFR(6)
  x0 += k2; x1 += k0 + 5u;
#undef TFR
  o0 = x0; o1 = x1;
}

__device__ __forceinline__ uint32_t jax_bits32(uint32_t k0, uint32_t k1, uint32_t idx) {
  uint32_t o0, o1; threefry2x32(k0, k1, 0u, idx, o0, o1);
  return o0 ^ o1;
}

__device__ __forceinline__ float bits_to_u01(uint32_t bits) {
  return __uint_as_float((bits >> 9) | 0x3F800000u) - 1.0f;
}

__device__ __forceinline__ float erfinv_f32(float x) {
  float w = -log1pf(-x * x);
  float p;
  if (w < 5.0f) {
    w = w - 2.5f;
    p = 2.81022636e-08f;
    p = fmaf(p, w, 3.43273939e-07f);
    p = fmaf(p, w, -3.5233877e-06f);
    p = fmaf(p, w, -4.39150654e-06f);
    p = fmaf(p, w, 0.00021858087f);
    p = fmaf(p, w, -0.00125372503f);
    p = fmaf(p, w, -0.00417768164f);
    p = fmaf(p, w, 0.246640727f);
    p = fmaf(p, w, 1.50140941f);
  } else {
    w = sqrtf(w) - 3.0f;
    p = -0.000200214257f;
    p = fmaf(p, w, 0.000100950558f);
    p = fmaf(p, w, 0.00134934322f);
    p = fmaf(p, w, -0.00367342844f);
    p = fmaf(p, w, 0.00573950773f);
    p = fmaf(p, w, -0.0076224613f);
    p = fmaf(p, w, 0.00943887047f);
    p = fmaf(p, w, 1.00167406f);
    p = fmaf(p, w, 2.83297682f);
  }
  return p * x;
}

__device__ __forceinline__ float jax_normal_f32(uint32_t k0, uint32_t k1, uint32_t idx) {
  uint32_t bits = jax_bits32(k0, k1, idx);
  float u = bits_to_u01(bits);
  const float lo = -0.99999994f;
  float v = u * (1.0f - lo) + lo;
  v = fmaxf(lo, v);
  return 1.41421356f * erfinv_f32(v);
}

__device__ __forceinline__ float jax_gumbel_f32(uint32_t k0, uint32_t k1, uint32_t idx) {
  uint32_t bits = jax_bits32(k0, k1, idx);
  float u = bits_to_u01(bits);
  const float tiny = 1.17549435e-38f;
  float v = u * (1.0f - tiny) + tiny;
  v = fmaxf(tiny, v);
  return -logf(-logf(v));
}

__device__ __forceinline__ float sp32(float x) { return fmaxf(x, 0.f) + log1pf(expf(-fabsf(x))); }
// correctly-rounded-ish f32 softplus: compute in f64, round once (matches glibc near-CR libm)
__device__ __forceinline__ float sp32cr(float x) {
  double xd = (double)x;
  return (float)(fmax(xd, 0.0) + log1p(exp(-fabs(xd))));
}
__device__ __forceinline__ double sp64(double x) { return fmax(x, 0.0) + log1p(exp(-fabs(x))); }

// ---------------- encoder ----------------
__global__ __launch_bounds__(256) void k_enc_h(const float* __restrict__ y,
                                               const float* __restrict__ W1,
                                               const float* __restrict__ b1,
                                               double* __restrict__ h) {
  int n = blockIdx.x, t = threadIdx.x;
  const float* yr = y + n * INDIM_;
  double a0 = 0.0, a1 = 0.0;
  for (int d = 0; d < INDIM_; ++d) {
    double yv = (double)yr[d];
    a0 += yv * (double)W1[d * H_ + t];
    a1 += yv * (double)W1[d * H_ + t + 256];
  }
  h[n * H_ + t] = tanh(a0 + (double)b1[t]);
  h[n * H_ + t + 256] = tanh(a1 + (double)b1[t + 256]);
}

// also emits f32-emulated d32 (eta2_phi1 diag) and mu_phi1 (f32 chain as np does)
__global__ __launch_bounds__(128) void k_enc_muvar(const double* __restrict__ h,
                                                   const float* __restrict__ Wmu,
                                                   const float* __restrict__ bmu,
                                                   const float* __restrict__ Wv,
                                                   const float* __restrict__ bv,
                                                   double* __restrict__ mu,
                                                   double* __restrict__ dvec,
                                                   float* __restrict__ d32,
                                                   float* __restrict__ muph) {
  __shared__ float mu32s[D_], var32s[D_];
  int n = blockIdx.x, t = threadIdx.x;
  int c = t & 63;
  const float* Wsel = (t < 64) ? Wmu : Wv;
  const double* hr = h + n * H_;
  double acc = 0.0;
  for (int q = 0; q < H_; ++q) acc += hr[q] * (double)Wsel[q * D_ + c];
  if (t < 64) {
    double m = acc + (double)bmu[c];
    mu[n * D_ + c] = m;
    mu32s[c] = (float)m;
  } else {
    double a = acc + (double)bv[c];
    double var = sp64(a) + 1e-6;
    dvec[n * D_ + c] = -0.5 / var;
    float var32 = sp32cr((float)a) + 1e-6f;
    var32s[c] = var32;
    d32[n * D_ + c] = (-0.5f) / var32;
  }
  __syncthreads();
  if (t < 64) {
    float var32 = var32s[c];
    float dd = (-0.5f) / var32;
    float eta1 = mu32s[c] / var32;
    float neg2d = -2.0f * dd;
    muph[n * D_ + c] = eta1 / neg2d;
  }
}

// ---------------- GMM unpack (f64 path for samples): J_k, invJ_k, log pi ----------------
__global__ __launch_bounds__(64) void k_gmm(const float* __restrict__ Lraw,
                                            const float* __restrict__ piraw,
                                            double* __restrict__ Jout,
                                            double* __restrict__ iJout,
                                            double* __restrict__ logpi) {
  __shared__ float Lk[D_][DP1];
  __shared__ double dg[D_];
  __shared__ double Li[D_][DP1];
  int k = blockIdx.x, i = threadIdx.x;
  const float* Lr = Lraw + k * D_ * D_;
  for (int j = 0; j < i; ++j) Lk[i][j] = Lr[i * D_ + j];
  dg[i] = sp64((double)Lr[i * D_ + i]);
  __syncthreads();
#define LKD(r, c) ((c) < (r) ? (double)Lk[r][c] : dg[r])
  for (int j = 0; j < D_; ++j) {
    int m = min(i, j);
    double s = 0.0;
    for (int q = 0; q <= m; ++q) s += LKD(i, q) * LKD(j, q);
    Jout[k * D_ * D_ + i * D_ + j] = -0.5 * s;
  }
  {
    int j = i;
    Li[j][j] = 1.0 / dg[j];
    for (int r = j + 1; r < D_; ++r) {
      double s = 0.0;
      for (int m = j; m < r; ++m) s += LKD(r, m) * Li[m][j];
      Li[r][j] = -s / dg[r];
    }
  }
  __syncthreads();
  for (int j = 0; j < D_; ++j) {
    int m0 = max(i, j);
    double s = 0.0;
    for (int m = m0; m < D_; ++m) s += Li[m][i] * Li[m][j];
    iJout[k * D_ * D_ + i * D_ + j] = -2.0 * s;
  }
#undef LKD
  if (k == 0 && i == 0) {
    double m = (double)piraw[0];
    for (int q = 1; q < K_; ++q) m = fmax(m, (double)piraw[q]);
    double ss = 0.0;
    for (int q = 0; q < K_; ++q) ss += exp((double)piraw[q] - m);
    double lse = m + log(ss);
    for (int q = 0; q < K_; ++q) logpi[q] = (double)piraw[q] - lse;
  }
}

// ---------------- f32 LAPACK-emulation: J32 (f32 sgemm-fold) + sgetf2 LU (per k) ----------------
__global__ __launch_bounds__(64) void k_lu32(const float* __restrict__ Lraw,
                                             float* __restrict__ J32g,
                                             float* __restrict__ LU32g,
                                             int* __restrict__ pivg) {
  __shared__ float Lk[D_][DP1];
  __shared__ float A[D_][DP1];
  __shared__ float col[D_];
  __shared__ int piv_s[D_];
  int k = blockIdx.x, i = threadIdx.x;
  const float* Lr = Lraw + k * D_ * D_;
  for (int j = 0; j < D_; ++j)
    Lk[i][j] = (j < i) ? Lr[i * D_ + j] : ((j == i) ? sp32cr(Lr[i * D_ + i]) : 0.0f);
  __syncthreads();
  // J = -0.5 * (Lk @ Lk^T): pure-f32 ascending-k fmaf fold (numpy/OpenBLAS sgemm DAG),
  // then exact *(-0.5f). Zero products beyond min(i,j) are exact no-ops.
  for (int j = 0; j < D_; ++j) {
    float s = 0.0f;
    for (int q = 0; q < D_; ++q) s = fmaf(Lk[i][q], Lk[j][q], s);
    float v = -0.5f * s;
    A[i][j] = v;
    J32g[k * D_ * D_ + i * D_ + j] = v;
  }
  __syncthreads();
  // sgetf2: LU with partial pivoting (LAPACK reference order)
  for (int j = 0; j < D_; ++j) {
    col[i] = fabsf(A[i][j]);
    __syncthreads();
    if (i == 0) {
      int p = j; float mx = col[j];
      for (int r = j + 1; r < D_; ++r) if (col[r] > mx) { mx = col[r]; p = r; }
      piv_s[j] = p;
    }
    __syncthreads();
    int p = piv_s[j];
    if (p != j) { float tmp = A[j][i]; A[j][i] = A[p][i]; A[p][i] = tmp; }  // full row swap
    __syncthreads();
    float rec = 1.0f / A[j][j];
    if (i > j) A[i][j] = A[i][j] * rec;          // sscal: reciprocal-multiply
    __syncthreads();
    if (i > j) {
      float x = A[i][j];
      for (int l = j + 1; l < D_; ++l) A[i][l] = fmaf(x, -A[j][l], A[i][l]);  // sger (fma)
    }
    __syncthreads();
  }
  for (int j = 0; j < D_; ++j) LU32g[k * D_ * D_ + i * D_ + j] = A[i][j];
  pivg[k * D_ + i] = piv_s[i];
}

// ---------------- f32-emulated quad2 = mu_phi1^T w_eta2 mu_phi1 per (n,k) ----------------
__global__ __launch_bounds__(64) void k_quad32(const float* __restrict__ J32g,
                                               const float* __restrict__ LU32g,
                                               const int* __restrict__ pivg,
                                               const float* __restrict__ d32g,
                                               const float* __restrict__ muphg,
                                               double* __restrict__ quadg) {
  __shared__ float LU[D_][DP1];
  __shared__ float T[D_][DP1];
  __shared__ float dsh[D_], mph[D_];
  __shared__ int piv_s[D_];
  __shared__ double red[D_];
  int nk = blockIdx.x;
  int n = nk / K_, k = nk - n * K_;
  int tj = threadIdx.x;
  for (int i2 = 0; i2 < D_; ++i2) {
    LU[i2][tj] = LU32g[k * D_ * D_ + i2 * D_ + tj];
    T[i2][tj]  = J32g[k * D_ * D_ + i2 * D_ + tj];
  }
  dsh[tj] = d32g[n * D_ + tj];
  mph[tj] = muphg[n * D_ + tj];
  piv_s[tj] = pivg[k * D_ + tj];
  __syncthreads();
  // eta2_tilde = J + diag(d)  (f32 add on diagonal)
  T[tj][tj] = T[tj][tj] + dsh[tj];
  __syncthreads();
  // sgetrs: LASWP on RHS rows (each thread owns column tj)
  for (int j = 0; j < D_; ++j) {
    int p = piv_s[j];
    if (p != j) { float t0 = T[j][tj]; T[j][tj] = T[p][tj]; T[p][tj] = t0; }
  }
  // trsm unit-lower forward
  for (int r = 0; r < D_; ++r) {
    float x = T[r][tj];
    for (int i2 = r + 1; i2 < D_; ++i2) T[i2][tj] = fmaf(LU[i2][r], -x, T[i2][tj]);
  }
  // trsm upper non-unit backward
  for (int r = D_ - 1; r >= 0; --r) {
    float x = T[r][tj] / LU[r][r];
    T[r][tj] = x;
    for (int i2 = 0; i2 < r; ++i2) T[i2][tj] = fmaf(LU[i2][r], -x, T[i2][tj]);
  }
  __syncthreads();
  // w = 0.5*(Dg*solved + (Dg*solved)^T); quad partial over column tj
  double part = 0.0;
  for (int d2 = 0; d2 < D_; ++d2) {
    float a = dsh[d2] * T[d2][tj];
    float b = dsh[tj] * T[tj][d2];
    float w = 0.5f * (a + b);
    float t1 = mph[d2] * w;
    float t2 = t1 * mph[tj];
    part += (double)t2;
  }
  red[tj] = part; __syncthreads();
  for (int off = 32; off > 0; off >>= 1) {
    if (tj < off) red[tj] += red[tj + off];
    __syncthreads();
  }
  if (tj == 0) quadg[nk] = red[0];
}

// ---------------- shared 64x64 SPD helpers ----------------
__device__ __forceinline__ void chol64d(double (*S)[DP1], int i) {
  for (int j = 0; j < D_; ++j) {
    if (i == j) S[j][j] = sqrt(S[j][j]);
    __syncthreads();
    if (i > j) S[i][j] = S[i][j] / S[j][j];
    __syncthreads();
    if (i > j) {
      double lij = S[i][j];
      for (int l = j + 1; l <= i; ++l) S[i][l] -= lij * S[l][j];
    }
    __syncthreads();
  }
}

__device__ __forceinline__ void trisolve_fb(double (*S)[DP1], double* r, int i) {
  for (int j = 0; j < D_; ++j) {
    if (i == j) r[j] = r[j] / S[j][j];
    __syncthreads();
    if (i > j) r[i] -= S[i][j] * r[j];
    __syncthreads();
  }
  for (int j = D_ - 1; j >= 0; --j) {
    if (i == j) r[j] = r[j] / S[j][j];
    __syncthreads();
    if (i < j) r[i] -= S[j][i] * r[j];
    __syncthreads();
  }
}

__device__ __forceinline__ double redsum64(double* red, int i, double v) {
  red[i] = v; __syncthreads();
  for (int off = 32; off > 0; off >>= 1) {
    if (i < off) red[i] += red[i + off];
    __syncthreads();
  }
  double r0 = red[0];
  __syncthreads();
  return r0;
}

// ---------------- per-(n,k): logprob (uses f32-emu quad) + x_samples ----------------
__global__ __launch_bounds__(64) void k_pernk(const double* __restrict__ dvec,
                                              const double* __restrict__ mu,
                                              const float* __restrict__ muk,
                                              const double* __restrict__ Jg,
                                              const double* __restrict__ iJg,
                                              const double* __restrict__ logpi,
                                              const double* __restrict__ quadg,
                                              double* __restrict__ logprob,
                                              float* __restrict__ xs) {
  __shared__ double S[D_][DP1];
  __shared__ double rv[D_], tv[D_], red[D_], dsh[D_], msh[D_];
  __shared__ double rr[D_][S_];
  int nk = blockIdx.x;
  int n = nk / K_, k = nk - n * K_;
  int i = threadIdx.x;

  double dn = dvec[n * D_ + i];
  double mn = mu[n * D_ + i];
  dsh[i] = dn; msh[i] = mn;
  const double* Jk = Jg + k * D_ * D_;
  const double* iJ = iJg + k * D_ * D_;

  // ---- A1 = -(Dg + J) (SPD); solve A1 z = mu_k; s_nk = sum((Dg+J)^{-1} mu_k)
  for (int j = 0; j < D_; ++j) S[i][j] = -Jk[i * D_ + j];
  S[i][i] -= dn;
  rv[i] = (double)muk[k * D_ + i];
  __syncthreads();
  chol64d(S, i);
  trisolve_fb(S, rv, i);
  double s_nk = -redsum64(red, i, rv[i]);
  double w1 = s_nk * dn;

  // ---- P = -w_eta2 = -(Dg J^{-1} Dg) - Dg (SPD)
  for (int j = 0; j < D_; ++j) S[i][j] = -(dn * iJ[i * D_ + j] * dsh[j]);
  S[i][i] -= dn;
  __syncthreads();
  double dot_mu_w1 = redsum64(red, i, mn * w1);
  chol64d(S, i);
  double sl = redsum64(red, i, log(S[i][i]));
  rv[i] = w1;
  __syncthreads();
  trisolve_fb(S, rv, i);
  tv[i] = rv[i];
  double dot_w1_t = redsum64(red, i, w1 * rv[i]);
  if (i == 0) {
    logprob[nk] = dot_mu_w1 + quadg[nk] - 0.25 * dot_w1_t
                + 32.0 * 0.6931471805599453 + sl
                - 32.0 * 1.8378770664093453
                + logpi[k];
  }

  // ---- samples
  {
    uint32_t base = (uint32_t)((nk * D_ + i) * S_);
    for (int s = 0; s < S_; ++s)
      rr[i][s] = (double)jax_normal_f32(0u, 42u, base + s);
  }
  __syncthreads();
  for (int q = D_ - 1; q >= 0; --q) {
    if (i == q) {
      double inv = 1.0 / S[q][q];
      for (int s = 0; s < S_; ++s) rr[q][s] *= inv;
    }
    __syncthreads();
    if (i < q) {
      double l = S[q][i];
      for (int s = 0; s < S_; ++s) rr[i][s] -= l * rr[q][s];
    }
    __syncthreads();
  }
  double xm = 0.5 * tv[i];
  for (int s = 0; s < S_; ++s)
    xs[(nk * S_ + s) * D_ + i] = (float)(xm + 0.7071067811865476 * rr[i][s]);
}

// ---------------- softmax over K + categorical (s=0) + x_subsamples ----------------
__global__ __launch_bounds__(64) void k_softcat(const double* __restrict__ logprob,
                                                const float* __restrict__ xs,
                                                float* __restrict__ outz,
                                                float* __restrict__ outx) {
  __shared__ double lz[K_];
  __shared__ int zc;
  int n = blockIdx.x, t = threadIdx.x;
  if (t == 0) {
    double lp[K_];
    double m = -1e300;
    for (int q = 0; q < K_; ++q) { lp[q] = logprob[n * K_ + q]; m = fmax(m, lp[q]); }
    double ss = 0.0;
    for (int q = 0; q < K_; ++q) ss += exp(lp[q] - m);
    double lsum = log(ss);
    float best = -INFINITY; int bi = 0;
    for (int q = 0; q < K_; ++q) {
      double l = (lp[q] - m) - lsum;
      lz[q] = l;
      float g = jax_gumbel_f32(0u, 7u, (uint32_t)(n * 100 + q));
      float sc = g + (float)l;
      if (sc > best) { best = sc; bi = q; }
    }
    zc = bi;
  }
  __syncthreads();
  if (t < K_) outz[n * K_ + t] = (float)lz[t];
  outx[n * D_ + t] = xs[(n * K_ + zc) * S_ * D_ + t];
}

// ---------------- decoder: 16 rows/block, fp32 ----------------
__global__ __launch_bounds__(256) void k_dec(const float* __restrict__ xs,
                                             const float* __restrict__ W1,
                                             const float* __restrict__ b1,
                                             const float* __restrict__ Wmu,
                                             const float* __restrict__ bmu,
                                             const float* __restrict__ Wv,
                                             const float* __restrict__ bvv,
                                             float* __restrict__ outm,
                                             float* __restrict__ outv) {
  __shared__ float xr[16][D_];
  __shared__ float hd[16][H_];
  int t = threadIdx.x;
  int blk = blockIdx.x;
  int row0 = blk * 16;
  for (int ii = 0; ii < 4; ++ii) {
    int idx = t + 256 * ii;
    (&xr[0][0])[idx] = xs[(size_t)row0 * D_ + idx];
  }
  __syncthreads();
  {
    float a0[16], a1[16];
    for (int r = 0; r < 16; ++r) { a0[r] = 0.f; a1[r] = 0.f; }
    for (int d = 0; d < D_; ++d) {
      float w0 = W1[d * H_ + t];
      float w1 = W1[d * H_ + t + 256];
      for (int r = 0; r < 16; ++r) {
        float xv = xr[r][d];
        a0[r] = fmaf(xv, w0, a0[r]);
        a1[r] = fmaf(xv, w1, a1[r]);
      }
    }
    float bb0 = b1[t], bb1 = b1[t + 256];
    for (int r = 0; r < 16; ++r) {
      hd[r][t] = tanhf(a0[r] + bb0);
      hd[r][t + 256] = tanhf(a1[r] + bb1);
    }
  }
  __syncthreads();
  for (int cc = 0; cc < 4; ++cc) {
    int c = t + 256 * cc;
    if (c >= INDIM_) break;
    float am[16], av[16];
    for (int r = 0; r < 16; ++r) { am[r] = 0.f; av[r] = 0.f; }
    for (int hh = 0; hh < H_; ++hh) {
      float wm = Wmu[hh * INDIM_ + c];
      float wv = Wv[hh * INDIM_ + c];
      for (int r = 0; r < 16; ++r) {
        float hv = hd[r][hh];
        am[r] = fmaf(hv, wm, am[r]);
        av[r] = fmaf(hv, wv, av[r]);
      }
    }
    float bm = bmu[c], bv2 = bvv[c];
    for (int r = 0; r < 16; ++r) {
      size_t o = (size_t)(row0 + r) * INDIM_ + c;
      outm[o] = am[r] + bm;
      outv[o] = sp32(av[r] + bv2) + 1e-6f;
    }
  }
}

// ---------------- launch ----------------
extern "C" void kernel_launch(void* const* d_in, const int* in_sizes, int n_in,
                              void* d_out, int out_size, void* d_ws, size_t ws_size,
                              hipStream_t stream) {
  const float* y     = (const float*)d_in[0];
  const float* eW1   = (const float*)d_in[1];
  const float* eb1   = (const float*)d_in[2];
  const float* eWmu  = (const float*)d_in[3];
  const float* ebmu  = (const float*)d_in[4];
  const float* eWv   = (const float*)d_in[5];
  const float* ebv   = (const float*)d_in[6];
  const float* muk   = (const float*)d_in[7];
  const float* Lraw  = (const float*)d_in[8];
  const float* piraw = (const float*)d_in[9];
  const float* dW1   = (const float*)d_in[10];
  const float* db1   = (const float*)d_in[11];
  const float* dWmu  = (const float*)d_in[12];
  const float* dbmu  = (const float*)d_in[13];
  const float* dWv   = (const float*)d_in[14];
  const float* dbv   = (const float*)d_in[15];

  // workspace layout
  double* W      = (double*)d_ws;
  double* h      = W;             // 262144 doubles
  double* mu     = W + 262144;    // 32768
  double* dvec   = W + 294912;    // 32768
  double* J      = W + 327680;    // 40960
  double* iJ     = W + 368640;    // 40960
  double* logpi  = W + 409600;    // 16
  double* logpr  = W + 409616;    // 5120
  double* quadg  = W + 414736;    // 5120
  double* base2  = W + 419856;
  float*  xs     = (float*)base2;                 // 3,276,800 floats
  float*  J32    = xs + 3276800;                  // 40960 floats
  float*  LU32   = J32 + 40960;                   // 40960
  float*  d32    = LU32 + 40960;                  // 32768
  float*  muph   = d32 + 32768;                   // 32768
  int*    piv    = (int*)(muph + 32768);          // 640 ints

  float* outm = (float*)d_out;            // (N,K,S,784)
  float* outv = outm + 40140800;          // (N,K,S,784)
  float* outx = outm + 80281600;          // (N,64)
  float* outz = outm + 80314368;          // (N,10)

  k_enc_h    <<<N_, 256, 0, stream>>>(y, eW1, eb1, h);
  k_enc_muvar<<<N_, 128, 0, stream>>>(h, eWmu, ebmu, eWv, ebv, mu, dvec, d32, muph);
  k_gmm      <<<K_, 64, 0, stream>>>(Lraw, piraw, J, iJ, logpi);
  k_lu32     <<<K_, 64, 0, stream>>>(Lraw, J32, LU32, piv);
  k_quad32   <<<N_ * K_, 64, 0, stream>>>(J32, LU32, piv, d32, muph, quadg);
  k_pernk    <<<N_ * K_, 64, 0, stream>>>(dvec, mu, muk, J, iJ, logpi, quadg, logpr, xs);
  k_softcat  <<<N_, 64, 0, stream>>>(logpr, xs, outz, outx);
  k_dec      <<<(N_ * K_ * S_) / 16, 256, 0, stream>>>(xs, dW1, db1, dWmu, dbmu, dWv, dbv, outm, outv);
}

// Round 5
// 3257.045 us; speedup vs baseline: 1.6218x; 1.6218x over previous
//
#include <hip/hip_runtime.h>
#include <math.h>
#include <stdint.h>

#define N_ 512
#define D_ 64
#define K_ 10
#define S_ 10
#define INDIM_ 784
#define H_ 512
#define DP1 (D_ + 1)

typedef __attribute__((ext_vector_type(8))) short short8v;
typedef __attribute__((ext_vector_type(4))) float f32x4;

// ---------------- JAX Threefry-2x32 (20 rounds) ----------------
__device__ __forceinline__ uint32_t rotl32(uint32_t v, int r) { return (v << r) | (v >> (32 - r)); }

__device__ __forceinline__ void threefry2x32(uint32_t k0, uint32_t k1,
                                             uint32_t x0, uint32_t x1,
                                             uint32_t& o0, uint32_t& o1) {
  uint32_t k2 = k0 ^ k1 ^ 0x1BD11BDAu;
  x0 += k0; x1 += k1;
#define TFR(r) { x0 += x1; x1 = rotl32(x1, r); x1 ^= x0; }
  TFR(13) TFR(15) TFR(26) TFR(6)
  x0 += k1; x1 += k2 + 1u;
  TFR(17) TFR(29) TFR(16) TFR(24)
  x0 += k2; x1 += k0 + 2u;
  TFR(13) TFR(15) TFR(26) TFR(6)
  x0 += k0; x1 += k1 + 3u;
  TFR(17) TFR(29) TFR(16) TFR(24)
  x0 += k1; x1 += k2 + 4u;
  TFR(13) TFR(15) TFR(26) TFR(6)
  x0 += k2; x1 += k0 + 5u;
#undef TFR
  o0 = x0; o1 = x1;
}

__device__ __forceinline__ uint32_t jax_bits32(uint32_t k0, uint32_t k1, uint32_t idx) {
  uint32_t o0, o1; threefry2x32(k0, k1, 0u, idx, o0, o1);
  return o0 ^ o1;
}

__device__ __forceinline__ float bits_to_u01(uint32_t bits) {
  return __uint_as_float((bits >> 9) | 0x3F800000u) - 1.0f;
}

__device__ __forceinline__ float erfinv_f32(float x) {
  float w = -log1pf(-x * x);
  float p;
  if (w < 5.0f) {
    w = w - 2.5f;
    p = 2.81022636e-08f;
    p = fmaf(p, w, 3.43273939e-07f);
    p = fmaf(p, w, -3.5233877e-06f);
    p = fmaf(p, w, -4.39150654e-06f);
    p = fmaf(p, w, 0.00021858087f);
    p = fmaf(p, w, -0.00125372503f);
    p = fmaf(p, w, -0.00417768164f);
    p = fmaf(p, w, 0.246640727f);
    p = fmaf(p, w, 1.50140941f);
  } else {
    w = sqrtf(w) - 3.0f;
    p = -0.000200214257f;
    p = fmaf(p, w, 0.000100950558f);
    p = fmaf(p, w, 0.00134934322f);
    p = fmaf(p, w, -0.00367342844f);
    p = fmaf(p, w, 0.00573950773f);
    p = fmaf(p, w, -0.0076224613f);
    p = fmaf(p, w, 0.00943887047f);
    p = fmaf(p, w, 1.00167406f);
    p = fmaf(p, w, 2.83297682f);
  }
  return p * x;
}

__device__ __forceinline__ float jax_normal_f32(uint32_t k0, uint32_t k1, uint32_t idx) {
  uint32_t bits = jax_bits32(k0, k1, idx);
  float u = bits_to_u01(bits);
  const float lo = -0.99999994f;
  float v = u * (1.0f - lo) + lo;
  v = fmaxf(lo, v);
  return 1.41421356f * erfinv_f32(v);
}

__device__ __forceinline__ float jax_gumbel_f32(uint32_t k0, uint32_t k1, uint32_t idx) {
  uint32_t bits = jax_bits32(k0, k1, idx);
  float u = bits_to_u01(bits);
  const float tiny = 1.17549435e-38f;
  float v = u * (1.0f - tiny) + tiny;
  v = fmaxf(tiny, v);
  return -logf(-logf(v));
}

__device__ __forceinline__ float sp32(float x) { return fmaxf(x, 0.f) + log1pf(expf(-fabsf(x))); }
__device__ __forceinline__ float sp32cr(float x) {
  double xd = (double)x;
  return (float)(fmax(xd, 0.0) + log1p(exp(-fabs(xd))));
}
__device__ __forceinline__ double sp64(double x) { return fmax(x, 0.0) + log1p(exp(-fabs(x))); }

__device__ __forceinline__ ushort bf16rne(float f) {
  uint32_t u = __float_as_uint(f);
  uint32_t r = (u + 0x7FFFu + ((u >> 16) & 1u)) >> 16;
  return (ushort)r;
}
__device__ __forceinline__ float bf2f(ushort b) { return __uint_as_float(((uint32_t)b) << 16); }

// ---------------- encoder ----------------
__global__ __launch_bounds__(256) void k_enc_h(const float* __restrict__ y,
                                               const float* __restrict__ W1,
                                               const float* __restrict__ b1,
                                               double* __restrict__ h) {
  int n = blockIdx.x, t = threadIdx.x;
  const float* yr = y + n * INDIM_;
  double a0 = 0.0, a1 = 0.0;
  for (int d = 0; d < INDIM_; ++d) {
    double yv = (double)yr[d];
    a0 += yv * (double)W1[d * H_ + t];
    a1 += yv * (double)W1[d * H_ + t + 256];
  }
  h[n * H_ + t] = tanh(a0 + (double)b1[t]);
  h[n * H_ + t + 256] = tanh(a1 + (double)b1[t + 256]);
}

__global__ __launch_bounds__(128) void k_enc_muvar(const double* __restrict__ h,
                                                   const float* __restrict__ Wmu,
                                                   const float* __restrict__ bmu,
                                                   const float* __restrict__ Wv,
                                                   const float* __restrict__ bv,
                                                   double* __restrict__ mu,
                                                   double* __restrict__ dvec,
                                                   float* __restrict__ d32,
                                                   float* __restrict__ muph) {
  __shared__ float mu32s[D_], var32s[D_];
  int n = blockIdx.x, t = threadIdx.x;
  int c = t & 63;
  const float* Wsel = (t < 64) ? Wmu : Wv;
  const double* hr = h + n * H_;
  double acc = 0.0;
  for (int q = 0; q < H_; ++q) acc += hr[q] * (double)Wsel[q * D_ + c];
  if (t < 64) {
    double m = acc + (double)bmu[c];
    mu[n * D_ + c] = m;
    mu32s[c] = (float)m;
  } else {
    double a = acc + (double)bv[c];
    double var = sp64(a) + 1e-6;
    dvec[n * D_ + c] = -0.5 / var;
    float var32 = sp32cr((float)a) + 1e-6f;
    var32s[c] = var32;
    d32[n * D_ + c] = (-0.5f) / var32;
  }
  __syncthreads();
  if (t < 64) {
    float var32 = var32s[c];
    float dd = (-0.5f) / var32;
    float eta1 = mu32s[c] / var32;
    float neg2d = -2.0f * dd;
    muph[n * D_ + c] = eta1 / neg2d;
  }
}

// ---------------- weight re-layout to MFMA fragment order (bf16) ----------------
// chunk layout: per (ct,ks) 16x32 tile, lane l gets 8 bf16 at chunk*512 + l*8:
//   element e: W[(ks*32 + (l>>4)*8 + e)*C + ct*16 + (l&15)]
__global__ __launch_bounds__(256) void k_prep(const float* __restrict__ W1,
                                              const float* __restrict__ Wmu,
                                              const float* __restrict__ Wv,
                                              ushort* __restrict__ hF) {
  int t = blockIdx.x * 256 + threadIdx.x;
  int chunk = t >> 6, l = t & 63;
  if (chunk >= 1632) return;
  int lr = l & 15, lg = l >> 4;
  const float* src; int C, ct, ks; ushort* dst;
  if (chunk < 64)       { src = W1;  C = 512; ct = chunk >> 1;  ks = chunk & 1;
                          dst = hF + chunk * 512; }
  else if (chunk < 848) { int c2 = chunk - 64;  src = Wmu; C = 784; ct = c2 / 16; ks = c2 % 16;
                          dst = hF + 32768 + c2 * 512; }
  else                  { int c2 = chunk - 848; src = Wv;  C = 784; ct = c2 / 16; ks = c2 % 16;
                          dst = hF + 434176 + c2 * 512; }
  ushort vals[8];
#pragma unroll
  for (int e = 0; e < 8; ++e)
    vals[e] = bf16rne(src[(ks * 32 + lg * 8 + e) * C + ct * 16 + lr]);
  *(short8v*)(dst + l * 8) = *(short8v*)vals;
}

// ---------------- GMM unpack (f64 path for samples): J_k, invJ_k, log pi ----------------
__global__ __launch_bounds__(64) void k_gmm(const float* __restrict__ Lraw,
                                            const float* __restrict__ piraw,
                                            double* __restrict__ Jout,
                                            double* __restrict__ iJout,
                                            double* __restrict__ logpi) {
  __shared__ float Lk[D_][DP1];
  __shared__ double dg[D_];
  __shared__ double Li[D_][DP1];
  int k = blockIdx.x, i = threadIdx.x;
  const float* Lr = Lraw + k * D_ * D_;
  for (int j = 0; j < i; ++j) Lk[i][j] = Lr[i * D_ + j];
  dg[i] = sp64((double)Lr[i * D_ + i]);
  __syncthreads();
#define LKD(r, c) ((c) < (r) ? (double)Lk[r][c] : dg[r])
  for (int j = 0; j < D_; ++j) {
    int m = min(i, j);
    double s = 0.0;
    for (int q = 0; q <= m; ++q) s += LKD(i, q) * LKD(j, q);
    Jout[k * D_ * D_ + i * D_ + j] = -0.5 * s;
  }
  {
    int j = i;
    Li[j][j] = 1.0 / dg[j];
    for (int r = j + 1; r < D_; ++r) {
      double s = 0.0;
      for (int m = j; m < r; ++m) s += LKD(r, m) * Li[m][j];
      Li[r][j] = -s / dg[r];
    }
  }
  __syncthreads();
  for (int j = 0; j < D_; ++j) {
    int m0 = max(i, j);
    double s = 0.0;
    for (int m = m0; m < D_; ++m) s += Li[m][i] * Li[m][j];
    iJout[k * D_ * D_ + i * D_ + j] = -2.0 * s;
  }
#undef LKD
  if (k == 0 && i == 0) {
    double m = (double)piraw[0];
    for (int q = 1; q < K_; ++q) m = fmax(m, (double)piraw[q]);
    double ss = 0.0;
    for (int q = 0; q < K_; ++q) ss += exp((double)piraw[q] - m);
    double lse = m + log(ss);
    for (int q = 0; q < K_; ++q) logpi[q] = (double)piraw[q] - lse;
  }
}

// ---------------- f32 LAPACK-emulation: J32 (f32 sgemm-fold) + sgetf2 LU (per k) ----------------
__global__ __launch_bounds__(64) void k_lu32(const float* __restrict__ Lraw,
                                             float* __restrict__ J32g,
                                             float* __restrict__ LU32g,
                                             int* __restrict__ pivg) {
  __shared__ float Lk[D_][DP1];
  __shared__ float A[D_][DP1];
  __shared__ float col[D_];
  __shared__ int piv_s[D_];
  int k = blockIdx.x, i = threadIdx.x;
  const float* Lr = Lraw + k * D_ * D_;
  for (int j = 0; j < D_; ++j)
    Lk[i][j] = (j < i) ? Lr[i * D_ + j] : ((j == i) ? sp32cr(Lr[i * D_ + i]) : 0.0f);
  __syncthreads();
  for (int j = 0; j < D_; ++j) {
    float s = 0.0f;
    for (int q = 0; q < D_; ++q) s = fmaf(Lk[i][q], Lk[j][q], s);
    float v = -0.5f * s;
    A[i][j] = v;
    J32g[k * D_ * D_ + i * D_ + j] = v;
  }
  __syncthreads();
  for (int j = 0; j < D_; ++j) {
    col[i] = fabsf(A[i][j]);
    __syncthreads();
    if (i == 0) {
      int p = j; float mx = col[j];
      for (int r = j + 1; r < D_; ++r) if (col[r] > mx) { mx = col[r]; p = r; }
      piv_s[j] = p;
    }
    __syncthreads();
    int p = piv_s[j];
    if (p != j) { float tmp = A[j][i]; A[j][i] = A[p][i]; A[p][i] = tmp; }
    __syncthreads();
    float rec = 1.0f / A[j][j];
    if (i > j) A[i][j] = A[i][j] * rec;
    __syncthreads();
    if (i > j) {
      float x = A[i][j];
      for (int l = j + 1; l < D_; ++l) A[i][l] = fmaf(x, -A[j][l], A[i][l]);
    }
    __syncthreads();
  }
  for (int j = 0; j < D_; ++j) LU32g[k * D_ * D_ + i * D_ + j] = A[i][j];
  pivg[k * D_ + i] = piv_s[i];
}

// ---------------- f32-emulated quad2 per (n,k) ----------------
__global__ __launch_bounds__(64) void k_quad32(const float* __restrict__ J32g,
                                               const float* __restrict__ LU32g,
                                               const int* __restrict__ pivg,
                                               const float* __restrict__ d32g,
                                               const float* __restrict__ muphg,
                                               double* __restrict__ quadg) {
  __shared__ float LU[D_][DP1];
  __shared__ float T[D_][DP1];
  __shared__ float dsh[D_], mph[D_];
  __shared__ int piv_s[D_];
  __shared__ double red[D_];
  int nk = blockIdx.x;
  int n = nk / K_, k = nk - n * K_;
  int tj = threadIdx.x;
  for (int i2 = 0; i2 < D_; ++i2) {
    LU[i2][tj] = LU32g[k * D_ * D_ + i2 * D_ + tj];
    T[i2][tj]  = J32g[k * D_ * D_ + i2 * D_ + tj];
  }
  dsh[tj] = d32g[n * D_ + tj];
  mph[tj] = muphg[n * D_ + tj];
  piv_s[tj] = pivg[k * D_ + tj];
  __syncthreads();
  T[tj][tj] = T[tj][tj] + dsh[tj];
  __syncthreads();
  for (int j = 0; j < D_; ++j) {
    int p = piv_s[j];
    if (p != j) { float t0 = T[j][tj]; T[j][tj] = T[p][tj]; T[p][tj] = t0; }
  }
  for (int r = 0; r < D_; ++r) {
    float x = T[r][tj];
    for (int i2 = r + 1; i2 < D_; ++i2) T[i2][tj] = fmaf(LU[i2][r], -x, T[i2][tj]);
  }
  for (int r = D_ - 1; r >= 0; --r) {
    float x = T[r][tj] / LU[r][r];
    T[r][tj] = x;
    for (int i2 = 0; i2 < r; ++i2) T[i2][tj] = fmaf(LU[i2][r], -x, T[i2][tj]);
  }
  __syncthreads();
  double part = 0.0;
  for (int d2 = 0; d2 < D_; ++d2) {
    float a = dsh[d2] * T[d2][tj];
    float b = dsh[tj] * T[tj][d2];
    float w = 0.5f * (a + b);
    float t1 = mph[d2] * w;
    float t2 = t1 * mph[tj];
    part += (double)t2;
  }
  red[tj] = part; __syncthreads();
  for (int off = 32; off > 0; off >>= 1) {
    if (tj < off) red[tj] += red[tj + off];
    __syncthreads();
  }
  if (tj == 0) quadg[nk] = red[0];
}

// ---------------- shared 64x64 SPD helpers ----------------
__device__ __forceinline__ void chol64d(double (*S)[DP1], int i) {
  for (int j = 0; j < D_; ++j) {
    if (i == j) S[j][j] = sqrt(S[j][j]);
    __syncthreads();
    if (i > j) S[i][j] = S[i][j] / S[j][j];
    __syncthreads();
    if (i > j) {
      double lij = S[i][j];
      for (int l = j + 1; l <= i; ++l) S[i][l] -= lij * S[l][j];
    }
    __syncthreads();
  }
}

__device__ __forceinline__ void trisolve_fb(double (*S)[DP1], double* r, int i) {
  for (int j = 0; j < D_; ++j) {
    if (i == j) r[j] = r[j] / S[j][j];
    __syncthreads();
    if (i > j) r[i] -= S[i][j] * r[j];
    __syncthreads();
  }
  for (int j = D_ - 1; j >= 0; --j) {
    if (i == j) r[j] = r[j] / S[j][j];
    __syncthreads();
    if (i < j) r[i] -= S[j][i] * r[j];
    __syncthreads();
  }
}

__device__ __forceinline__ double redsum64(double* red, int i, double v) {
  red[i] = v; __syncthreads();
  for (int off = 32; off > 0; off >>= 1) {
    if (i < off) red[i] += red[i + off];
    __syncthreads();
  }
  double r0 = red[0];
  __syncthreads();
  return r0;
}

// ---------------- per-(n,k): logprob + x_samples ----------------
__global__ __launch_bounds__(64) void k_pernk(const double* __restrict__ dvec,
                                              const double* __restrict__ mu,
                                              const float* __restrict__ muk,
                                              const double* __restrict__ Jg,
                                              const double* __restrict__ iJg,
                                              const double* __restrict__ logpi,
                                              const double* __restrict__ quadg,
                                              double* __restrict__ logprob,
                                              float* __restrict__ xs) {
  __shared__ double S[D_][DP1];
  __shared__ double rv[D_], tv[D_], red[D_], dsh[D_], msh[D_];
  __shared__ double rr[D_][S_];
  int nk = blockIdx.x;
  int n = nk / K_, k = nk - n * K_;
  int i = threadIdx.x;

  double dn = dvec[n * D_ + i];
  double mn = mu[n * D_ + i];
  dsh[i] = dn; msh[i] = mn;
  const double* Jk = Jg + k * D_ * D_;
  const double* iJ = iJg + k * D_ * D_;

  for (int j = 0; j < D_; ++j) S[i][j] = -Jk[i * D_ + j];
  S[i][i] -= dn;
  rv[i] = (double)muk[k * D_ + i];
  __syncthreads();
  chol64d(S, i);
  trisolve_fb(S, rv, i);
  double s_nk = -redsum64(red, i, rv[i]);
  double w1 = s_nk * dn;

  for (int j = 0; j < D_; ++j) S[i][j] = -(dn * iJ[i * D_ + j] * dsh[j]);
  S[i][i] -= dn;
  __syncthreads();
  double dot_mu_w1 = redsum64(red, i, mn * w1);
  chol64d(S, i);
  double sl = redsum64(red, i, log(S[i][i]));
  rv[i] = w1;
  __syncthreads();
  trisolve_fb(S, rv, i);
  tv[i] = rv[i];
  double dot_w1_t = redsum64(red, i, w1 * rv[i]);
  if (i == 0) {
    logprob[nk] = dot_mu_w1 + quadg[nk] - 0.25 * dot_w1_t
                + 32.0 * 0.6931471805599453 + sl
                - 32.0 * 1.8378770664093453
                + logpi[k];
  }

  {
    uint32_t base = (uint32_t)((nk * D_ + i) * S_);
    for (int s = 0; s < S_; ++s)
      rr[i][s] = (double)jax_normal_f32(0u, 42u, base + s);
  }
  __syncthreads();
  for (int q = D_ - 1; q >= 0; --q) {
    if (i == q) {
      double inv = 1.0 / S[q][q];
      for (int s = 0; s < S_; ++s) rr[q][s] *= inv;
    }
    __syncthreads();
    if (i < q) {
      double l = S[q][i];
      for (int s = 0; s < S_; ++s) rr[i][s] -= l * rr[q][s];
    }
    __syncthreads();
  }
  double xm = 0.5 * tv[i];
  for (int s = 0; s < S_; ++s)
    xs[(nk * S_ + s) * D_ + i] = (float)(xm + 0.7071067811865476 * rr[i][s]);
}

// ---------------- softmax over K + categorical (s=0) + x_subsamples ----------------
__global__ __launch_bounds__(64) void k_softcat(const double* __restrict__ logprob,
                                                const float* __restrict__ xs,
                                                float* __restrict__ outz,
                                                float* __restrict__ outx) {
  __shared__ double lz[K_];
  __shared__ int zc;
  int n = blockIdx.x, t = threadIdx.x;
  if (t == 0) {
    double lp[K_];
    double m = -1e300;
    for (int q = 0; q < K_; ++q) { lp[q] = logprob[n * K_ + q]; m = fmax(m, lp[q]); }
    double ss = 0.0;
    for (int q = 0; q < K_; ++q) ss += exp(lp[q] - m);
    double lsum = log(ss);
    float best = -INFINITY; int bi = 0;
    for (int q = 0; q < K_; ++q) {
      double l = (lp[q] - m) - lsum;
      lz[q] = l;
      float g = jax_gumbel_f32(0u, 7u, (uint32_t)(n * 100 + q));
      float sc = g + (float)l;
      if (sc > best) { best = sc; bi = q; }
    }
    zc = bi;
  }
  __syncthreads();
  if (t < K_) outz[n * K_ + t] = (float)lz[t];
  outx[n * D_ + t] = xs[(n * K_ + zc) * S_ * D_ + t];
}

// ---------------- decoder: MFMA bf16, 64 rows/block, 4 waves ----------------
__global__ __launch_bounds__(256) void k_dec(const float* __restrict__ xs,
                                             const ushort* __restrict__ W1F,
                                             const ushort* __restrict__ WmuF,
                                             const ushort* __restrict__ WvF,
                                             const float* __restrict__ b1,
                                             const float* __restrict__ bmu,
                                             const float* __restrict__ bvv,
                                             float* __restrict__ outm,
                                             float* __restrict__ outv) {
  __shared__ __align__(16) ushort hd[4][16][520];   // per-wave 16x512 bf16 tile, padded
  int t = threadIdx.x;
  int w = t >> 6, l = t & 63;
  int lr = l & 15, lg = l >> 4;
  int row0 = blockIdx.x * 64 + w * 16;

  // ---- x A-fragments, bf16 split (hi+lo) for accuracy
  short8v xhi[2], xlo[2];
  {
    const float* xrow = xs + (size_t)(row0 + lr) * 64 + lg * 8;
#pragma unroll
    for (int ks = 0; ks < 2; ++ks) {
      ushort hi[8], lo[8];
#pragma unroll
      for (int e = 0; e < 8; ++e) {
        float xv = xrow[ks * 32 + e];
        ushort h16 = bf16rne(xv);
        hi[e] = h16;
        lo[e] = bf16rne(xv - bf2f(h16));
      }
      xhi[ks] = *(short8v*)hi;
      xlo[ks] = *(short8v*)lo;
    }
  }

  // ---- GEMM1: hd = tanh(x @ W1 + b1), wave-private rows
  const short8v* W1v = (const short8v*)W1F;
#pragma unroll 4
  for (int ct = 0; ct < 32; ++ct) {
    f32x4 acc = {0.f, 0.f, 0.f, 0.f};
    short8v b0 = W1v[(ct * 2 + 0) * 64 + l];
    short8v b1v = W1v[(ct * 2 + 1) * 64 + l];
    acc = __builtin_amdgcn_mfma_f32_16x16x32_bf16(xhi[0], b0, acc, 0, 0, 0);
    acc = __builtin_amdgcn_mfma_f32_16x16x32_bf16(xlo[0], b0, acc, 0, 0, 0);
    acc = __builtin_amdgcn_mfma_f32_16x16x32_bf16(xhi[1], b1v, acc, 0, 0, 0);
    acc = __builtin_amdgcn_mfma_f32_16x16x32_bf16(xlo[1], b1v, acc, 0, 0, 0);
    int c = ct * 16 + lr;
    float bb = b1[c];
#pragma unroll
    for (int r = 0; r < 4; ++r)
      hd[w][lg * 4 + r][c] = bf16rne(tanhf(acc[r] + bb));
  }
  __syncthreads();

  // ---- load 16 A-fragments of hd (this wave's 16 rows)
  short8v ha[16];
#pragma unroll
  for (int ks = 0; ks < 16; ++ks)
    ha[ks] = *(const short8v*)&hd[w][lr][ks * 32 + lg * 8];

  // ---- GEMM2: outm/outv over 49 col-tiles x 16 k-steps
  const short8v* Wmv = (const short8v*)WmuF;
  const short8v* Wvv = (const short8v*)WvF;
  for (int ct = 0; ct < 49; ++ct) {
    f32x4 aM = {0.f, 0.f, 0.f, 0.f};
    f32x4 aV = {0.f, 0.f, 0.f, 0.f};
#pragma unroll
    for (int ks = 0; ks < 16; ++ks) {
      short8v bm = Wmv[(ct * 16 + ks) * 64 + l];
      short8v bv = Wvv[(ct * 16 + ks) * 64 + l];
      aM = __builtin_amdgcn_mfma_f32_16x16x32_bf16(ha[ks], bm, aM, 0, 0, 0);
      aV = __builtin_amdgcn_mfma_f32_16x16x32_bf16(ha[ks], bv, aV, 0, 0, 0);
    }
    int c = ct * 16 + lr;
    float bm_ = bmu[c], bv_ = bvv[c];
#pragma unroll
    for (int r = 0; r < 4; ++r) {
      size_t o = (size_t)(row0 + lg * 4 + r) * INDIM_ + c;
      outm[o] = aM[r] + bm_;
      outv[o] = sp32(aV[r] + bv_) + 1e-6f;
    }
  }
}

// ---------------- launch ----------------
extern "C" void kernel_launch(void* const* d_in, const int* in_sizes, int n_in,
                              void* d_out, int out_size, void* d_ws, size_t ws_size,
                              hipStream_t stream) {
  const float* y     = (const float*)d_in[0];
  const float* eW1   = (const float*)d_in[1];
  const float* eb1   = (const float*)d_in[2];
  const float* eWmu  = (const float*)d_in[3];
  const float* ebmu  = (const float*)d_in[4];
  const float* eWv   = (const float*)d_in[5];
  const float* ebv   = (const float*)d_in[6];
  const float* muk   = (const float*)d_in[7];
  const float* Lraw  = (const float*)d_in[8];
  const float* piraw = (const float*)d_in[9];
  const float* dW1   = (const float*)d_in[10];
  const float* db1   = (const float*)d_in[11];
  const float* dWmu  = (const float*)d_in[12];
  const float* dbmu  = (const float*)d_in[13];
  const float* dWv   = (const float*)d_in[14];
  const float* dbv   = (const float*)d_in[15];

  // workspace layout
  double* W      = (double*)d_ws;
  double* h      = W;             // 262144 doubles (reused as bf16 frag store by k_prep)
  double* mu     = W + 262144;    // 32768
  double* dvec   = W + 294912;    // 32768
  double* J      = W + 327680;    // 40960
  double* iJ     = W + 368640;    // 40960
  double* logpi  = W + 409600;    // 16
  double* logpr  = W + 409616;    // 5120
  double* quadg  = W + 414736;    // 5120
  double* base2  = W + 419856;
  float*  xs     = (float*)base2;                 // 3,276,800 floats
  float*  J32    = xs + 3276800;                  // 40960 floats
  float*  LU32   = J32 + 40960;                   // 40960
  float*  d32    = LU32 + 40960;                  // 32768
  float*  muph   = d32 + 32768;                   // 32768
  int*    piv    = (int*)(muph + 32768);          // 640 ints

  ushort* hF   = (ushort*)h;      // 835,584 ushorts: W1F[32768] | WmuF[401408] | WvF[401408]
  ushort* W1F  = hF;
  ushort* WmuF = hF + 32768;
  ushort* WvF  = hF + 434176;

  float* outm = (float*)d_out;            // (N,K,S,784)
  float* outv = outm + 40140800;          // (N,K,S,784)
  float* outx = outm + 80281600;          // (N,64)
  float* outz = outm + 80314368;          // (N,10)

  k_enc_h    <<<N_, 256, 0, stream>>>(y, eW1, eb1, h);
  k_enc_muvar<<<N_, 128, 0, stream>>>(h, eWmu, ebmu, eWv, ebv, mu, dvec, d32, muph);
  k_prep     <<<408, 256, 0, stream>>>(dW1, dWmu, dWv, hF);   // h is dead after k_enc_muvar
  k_gmm      <<<K_, 64, 0, stream>>>(Lraw, piraw, J, iJ, logpi);
  k_lu32     <<<K_, 64, 0, stream>>>(Lraw, J32, LU32, piv);
  k_quad32   <<<N_ * K_, 64, 0, stream>>>(J32, LU32, piv, d32, muph, quadg);
  k_pernk    <<<N_ * K_, 64, 0, stream>>>(dvec, mu, muk, J, iJ, logpi, quadg, logpr, xs);
  k_softcat  <<<N_, 64, 0, stream>>>(logpr, xs, outz, outx);
  k_dec      <<<800, 256, 0, stream>>>(xs, W1F, WmuF, WvF, db1, dbmu, dbv, outm, outv);
}

// Round 6
// 2306.665 us; speedup vs baseline: 2.2900x; 1.4120x over previous
//
#include <hip/hip_runtime.h>
#include <math.h>
#include <stdint.h>

#define N_ 512
#define D_ 64
#define K_ 10
#define S_ 10
#define INDIM_ 784
#define H_ 512
#define DP1 (D_ + 1)

typedef __attribute__((ext_vector_type(8))) short short8v;
typedef __attribute__((ext_vector_type(4))) float f32x4;

// ---------------- JAX Threefry-2x32 (20 rounds) ----------------
__device__ __forceinline__ uint32_t rotl32(uint32_t v, int r) { return (v << r) | (v >> (32 - r)); }

__device__ __forceinline__ void threefry2x32(uint32_t k0, uint32_t k1,
                                             uint32_t x0, uint32_t x1,
                                             uint32_t& o0, uint32_t& o1) {
  uint32_t k2 = k0 ^ k1 ^ 0x1BD11BDAu;
  x0 += k0; x1 += k1;
#define TFR(r) { x0 += x1; x1 = rotl32(x1, r); x1 ^= x0; }
  TFR(13) TFR(15) TFR(26) TFR(6)
  x0 += k1; x1 += k2 + 1u;
  TFR(17) TFR(29) TFR(16) TFR(24)
  x0 += k2; x1 += k0 + 2u;
  TFR(13) TFR(15) TFR(26) TFR(6)
  x0 += k0; x1 += k1 + 3u;
  TFR(17) TFR(29) TFR(16) TFR(24)
  x0 += k1; x1 += k2 + 4u;
  TFR(13) TFR(15) TFR(26) TFR(6)
  x0 += k2; x1 += k0 + 5u;
#undef TFR
  o0 = x0; o1 = x1;
}

__device__ __forceinline__ uint32_t jax_bits32(uint32_t k0, uint32_t k1, uint32_t idx) {
  uint32_t o0, o1; threefry2x32(k0, k1, 0u, idx, o0, o1);
  return o0 ^ o1;
}

__device__ __forceinline__ float bits_to_u01(uint32_t bits) {
  return __uint_as_float((bits >> 9) | 0x3F800000u) - 1.0f;
}

__device__ __forceinline__ float erfinv_f32(float x) {
  float w = -log1pf(-x * x);
  float p;
  if (w < 5.0f) {
    w = w - 2.5f;
    p = 2.81022636e-08f;
    p = fmaf(p, w, 3.43273939e-07f);
    p = fmaf(p, w, -3.5233877e-06f);
    p = fmaf(p, w, -4.39150654e-06f);
    p = fmaf(p, w, 0.00021858087f);
    p = fmaf(p, w, -0.00125372503f);
    p = fmaf(p, w, -0.00417768164f);
    p = fmaf(p, w, 0.246640727f);
    p = fmaf(p, w, 1.50140941f);
  } else {
    w = sqrtf(w) - 3.0f;
    p = -0.000200214257f;
    p = fmaf(p, w, 0.000100950558f);
    p = fmaf(p, w, 0.00134934322f);
    p = fmaf(p, w, -0.00367342844f);
    p = fmaf(p, w, 0.00573950773f);
    p = fmaf(p, w, -0.0076224613f);
    p = fmaf(p, w, 0.00943887047f);
    p = fmaf(p, w, 1.00167406f);
    p = fmaf(p, w, 2.83297682f);
  }
  return p * x;
}

__device__ __forceinline__ float jax_normal_f32(uint32_t k0, uint32_t k1, uint32_t idx) {
  uint32_t bits = jax_bits32(k0, k1, idx);
  float u = bits_to_u01(bits);
  const float lo = -0.99999994f;
  float v = u * (1.0f - lo) + lo;
  v = fmaxf(lo, v);
  return 1.41421356f * erfinv_f32(v);
}

__device__ __forceinline__ float jax_gumbel_f32(uint32_t k0, uint32_t k1, uint32_t idx) {
  uint32_t bits = jax_bits32(k0, k1, idx);
  float u = bits_to_u01(bits);
  const float tiny = 1.17549435e-38f;
  float v = u * (1.0f - tiny) + tiny;
  v = fmaxf(tiny, v);
  return -logf(-logf(v));
}

__device__ __forceinline__ float sp32(float x) { return fmaxf(x, 0.f) + log1pf(expf(-fabsf(x))); }
__device__ __forceinline__ float sp32cr(float x) {
  double xd = (double)x;
  return (float)(fmax(xd, 0.0) + log1p(exp(-fabs(xd))));
}
__device__ __forceinline__ double sp64(double x) { return fmax(x, 0.0) + log1p(exp(-fabs(x))); }

__device__ __forceinline__ ushort bf16rne(float f) {
  uint32_t u = __float_as_uint(f);
  uint32_t r = (u + 0x7FFFu + ((u >> 16) & 1u)) >> 16;
  return (ushort)r;
}
__device__ __forceinline__ float bf2f(ushort b) { return __uint_as_float(((uint32_t)b) << 16); }

// ---------------- encoder ----------------
__global__ __launch_bounds__(256) void k_enc_h(const float* __restrict__ y,
                                               const float* __restrict__ W1,
                                               const float* __restrict__ b1,
                                               double* __restrict__ h) {
  int n = blockIdx.x, t = threadIdx.x;
  const float* yr = y + n * INDIM_;
  double a0 = 0.0, a1 = 0.0;
  for (int d = 0; d < INDIM_; ++d) {
    double yv = (double)yr[d];
    a0 += yv * (double)W1[d * H_ + t];
    a1 += yv * (double)W1[d * H_ + t + 256];
  }
  h[n * H_ + t] = tanh(a0 + (double)b1[t]);
  h[n * H_ + t + 256] = tanh(a1 + (double)b1[t + 256]);
}

__global__ __launch_bounds__(128) void k_enc_muvar(const double* __restrict__ h,
                                                   const float* __restrict__ Wmu,
                                                   const float* __restrict__ bmu,
                                                   const float* __restrict__ Wv,
                                                   const float* __restrict__ bv,
                                                   double* __restrict__ mu,
                                                   double* __restrict__ dvec,
                                                   float* __restrict__ d32,
                                                   float* __restrict__ muph) {
  __shared__ float mu32s[D_], var32s[D_];
  int n = blockIdx.x, t = threadIdx.x;
  int c = t & 63;
  const float* Wsel = (t < 64) ? Wmu : Wv;
  const double* hr = h + n * H_;
  double acc = 0.0;
  for (int q = 0; q < H_; ++q) acc += hr[q] * (double)Wsel[q * D_ + c];
  if (t < 64) {
    double m = acc + (double)bmu[c];
    mu[n * D_ + c] = m;
    mu32s[c] = (float)m;
  } else {
    double a = acc + (double)bv[c];
    double var = sp64(a) + 1e-6;
    dvec[n * D_ + c] = -0.5 / var;
    float var32 = sp32cr((float)a) + 1e-6f;
    var32s[c] = var32;
    d32[n * D_ + c] = (-0.5f) / var32;
  }
  __syncthreads();
  if (t < 64) {
    float var32 = var32s[c];
    float dd = (-0.5f) / var32;
    float eta1 = mu32s[c] / var32;
    float neg2d = -2.0f * dd;
    muph[n * D_ + c] = eta1 / neg2d;
  }
}

// ---------------- weight re-layout to MFMA fragment order (bf16) ----------------
__global__ __launch_bounds__(256) void k_prep(const float* __restrict__ W1,
                                              const float* __restrict__ Wmu,
                                              const float* __restrict__ Wv,
                                              ushort* __restrict__ hF) {
  int t = blockIdx.x * 256 + threadIdx.x;
  int chunk = t >> 6, l = t & 63;
  if (chunk >= 1632) return;
  int lr = l & 15, lg = l >> 4;
  const float* src; int C, ct, ks; ushort* dst;
  if (chunk < 64)       { src = W1;  C = 512; ct = chunk >> 1;  ks = chunk & 1;
                          dst = hF + chunk * 512; }
  else if (chunk < 848) { int c2 = chunk - 64;  src = Wmu; C = 784; ct = c2 / 16; ks = c2 % 16;
                          dst = hF + 32768 + c2 * 512; }
  else                  { int c2 = chunk - 848; src = Wv;  C = 784; ct = c2 / 16; ks = c2 % 16;
                          dst = hF + 434176 + c2 * 512; }
  ushort vals[8];
#pragma unroll
  for (int e = 0; e < 8; ++e)
    vals[e] = bf16rne(src[(ks * 32 + lg * 8 + e) * C + ct * 16 + lr]);
  *(short8v*)(dst + l * 8) = *(short8v*)vals;
}

// ---------------- GMM unpack (f64 path): J_k, invJ_k, log pi ----------------
__global__ __launch_bounds__(64) void k_gmm(const float* __restrict__ Lraw,
                                            const float* __restrict__ piraw,
                                            double* __restrict__ Jout,
                                            double* __restrict__ iJout,
                                            double* __restrict__ logpi) {
  __shared__ float Lk[D_][DP1];
  __shared__ double dg[D_];
  __shared__ double Li[D_][DP1];
  int k = blockIdx.x, i = threadIdx.x;
  const float* Lr = Lraw + k * D_ * D_;
  for (int j = 0; j < i; ++j) Lk[i][j] = Lr[i * D_ + j];
  dg[i] = sp64((double)Lr[i * D_ + i]);
  __syncthreads();
#define LKD(r, c) ((c) < (r) ? (double)Lk[r][c] : dg[r])
  for (int j = 0; j < D_; ++j) {
    int m = min(i, j);
    double s = 0.0;
    for (int q = 0; q <= m; ++q) s += LKD(i, q) * LKD(j, q);
    Jout[k * D_ * D_ + i * D_ + j] = -0.5 * s;
  }
  {
    int j = i;
    Li[j][j] = 1.0 / dg[j];
    for (int r = j + 1; r < D_; ++r) {
      double s = 0.0;
      for (int m = j; m < r; ++m) s += LKD(r, m) * Li[m][j];
      Li[r][j] = -s / dg[r];
    }
  }
  __syncthreads();
  for (int j = 0; j < D_; ++j) {
    int m0 = max(i, j);
    double s = 0.0;
    for (int m = m0; m < D_; ++m) s += Li[m][i] * Li[m][j];
    iJout[k * D_ * D_ + i * D_ + j] = -2.0 * s;
  }
#undef LKD
  if (k == 0 && i == 0) {
    double m = (double)piraw[0];
    for (int q = 1; q < K_; ++q) m = fmax(m, (double)piraw[q]);
    double ss = 0.0;
    for (int q = 0; q < K_; ++q) ss += exp((double)piraw[q] - m);
    double lse = m + log(ss);
    for (int q = 0; q < K_; ++q) logpi[q] = (double)piraw[q] - lse;
  }
}

// ---------------- f32 LAPACK-emulation: J32 (f32 sgemm-fold) + sgetf2 LU (per k) ----------------
__global__ __launch_bounds__(64) void k_lu32(const float* __restrict__ Lraw,
                                             float* __restrict__ J32g,
                                             float* __restrict__ LU32g,
                                             int* __restrict__ pivg) {
  __shared__ float Lk[D_][DP1];
  __shared__ float A[D_][DP1];
  __shared__ float col[D_];
  __shared__ int piv_s[D_];
  int k = blockIdx.x, i = threadIdx.x;
  const float* Lr = Lraw + k * D_ * D_;
  for (int j = 0; j < D_; ++j)
    Lk[i][j] = (j < i) ? Lr[i * D_ + j] : ((j == i) ? sp32cr(Lr[i * D_ + i]) : 0.0f);
  __syncthreads();
  for (int j = 0; j < D_; ++j) {
    float s = 0.0f;
    for (int q = 0; q < D_; ++q) s = fmaf(Lk[i][q], Lk[j][q], s);
    float v = -0.5f * s;
    A[i][j] = v;
    J32g[k * D_ * D_ + i * D_ + j] = v;
  }
  __syncthreads();
  for (int j = 0; j < D_; ++j) {
    col[i] = fabsf(A[i][j]);
    __syncthreads();
    if (i == 0) {
      int p = j; float mx = col[j];
      for (int r = j + 1; r < D_; ++r) if (col[r] > mx) { mx = col[r]; p = r; }
      piv_s[j] = p;
    }
    __syncthreads();
    int p = piv_s[j];
    if (p != j) { float tmp = A[j][i]; A[j][i] = A[p][i]; A[p][i] = tmp; }
    __syncthreads();
    float rec = 1.0f / A[j][j];
    if (i > j) A[i][j] = A[i][j] * rec;
    __syncthreads();
    if (i > j) {
      float x = A[i][j];
      for (int l = j + 1; l < D_; ++l) A[i][l] = fmaf(x, -A[j][l], A[i][l]);
    }
    __syncthreads();
  }
  for (int j = 0; j < D_; ++j) LU32g[k * D_ * D_ + i * D_ + j] = A[i][j];
  pivg[k * D_ + i] = piv_s[i];
}

// ---------------- f32-emulated quad2 per (n,k) — register-column solves ----------------
__global__ __launch_bounds__(64) void k_quad32(const float* __restrict__ J32g,
                                               const float* __restrict__ LU32g,
                                               const int* __restrict__ pivg,
                                               const float* __restrict__ d32g,
                                               const float* __restrict__ muphg,
                                               double* __restrict__ quadg) {
  __shared__ float LUs[D_][DP1];
  __shared__ float dsh[D_], mph[D_];
  __shared__ int pshare[D_];
  __shared__ double red[D_];
  int nk = blockIdx.x;
  int n = nk / K_, k = nk - n * K_;
  int tj = threadIdx.x;
  for (int r = 0; r < D_; ++r) LUs[r][tj] = LU32g[k * 4096 + r * 64 + tj];
  dsh[tj] = d32g[n * 64 + tj];
  mph[tj] = muphg[n * 64 + tj];
  // build row permutation equivalent to sequential LASWP swaps
  int pv = pivg[k * 64 + tj];
  int perm = tj;
  for (int j = 0; j < 64; ++j) {
    int pj = __shfl(pv, j, 64);
    int vj = __shfl(perm, j, 64);
    int vp = __shfl(perm, pj, 64);
    if (tj == j) perm = vp;
    else if (tj == pj) perm = vj;
  }
  pshare[tj] = perm;
  __syncthreads();
  // permuted load of (J + diag(d)) column tj into registers (static indices)
  float Tc[64];
#pragma unroll
  for (int i2 = 0; i2 < 64; ++i2) {
    int pr = pshare[i2];
    float v = J32g[k * 4096 + pr * 64 + tj];
    if (pr == tj) v = v + dsh[tj];
    Tc[i2] = v;
  }
  // trsm unit-lower forward (identical per-element f32 DAG as before)
#pragma unroll
  for (int r = 0; r < 64; ++r) {
    float x = Tc[r];
#pragma unroll
    for (int i2 = r + 1; i2 < 64; ++i2)
      Tc[i2] = fmaf(LUs[i2][r], -x, Tc[i2]);
  }
  // trsm upper non-unit backward
#pragma unroll
  for (int r = 63; r >= 0; --r) {
    float x = Tc[r] / LUs[r][r];
    Tc[r] = x;
#pragma unroll
    for (int i2 = 0; i2 < r; ++i2)
      Tc[i2] = fmaf(LUs[i2][r], -x, Tc[i2]);
  }
  __syncthreads();                 // done reading LUs as LU
#pragma unroll
  for (int i2 = 0; i2 < 64; ++i2) LUs[i2][tj] = Tc[i2];   // now LUs = solved T
  __syncthreads();
  double part = 0.0;
#pragma unroll
  for (int d2 = 0; d2 < 64; ++d2) {
    float a = dsh[d2] * Tc[d2];
    float b = dsh[tj] * LUs[tj][d2];
    float w = 0.5f * (a + b);
    float t1 = mph[d2] * w;
    float t2 = t1 * mph[tj];
    part += (double)t2;
  }
  red[tj] = part; __syncthreads();
  for (int off = 32; off > 0; off >>= 1) {
    if (tj < off) red[tj] += red[tj + off];
    __syncthreads();
  }
  if (tj == 0) quadg[nk] = red[0];
}

// ---------------- per-(n,k): packed-triangle f64 chol, shfl broadcasts ----------------
__global__ __launch_bounds__(64) void k_pernk(const double* __restrict__ dvec,
                                              const double* __restrict__ mu,
                                              const float* __restrict__ muk,
                                              const double* __restrict__ Jg,
                                              const double* __restrict__ iJg,
                                              const double* __restrict__ logpi,
                                              const double* __restrict__ quadg,
                                              double* __restrict__ logprob,
                                              float* __restrict__ xs) {
  __shared__ double Sp[2080];      // packed lower triangle, row i at i(i+1)/2
  __shared__ double dsh[D_];
  int nk = blockIdx.x;
  int n = nk / K_, k = nk - n * K_;
  int i = threadIdx.x;
  int Ti = (i * (i + 1)) >> 1;

  double dn = dvec[n * 64 + i];
  double mn = mu[n * 64 + i];
  dsh[i] = dn;
  const double* Jk = Jg + k * 4096;
  const double* iJ = iJg + k * 4096;

  // ---- Phase A: A1 = -(J + diag(d)); chol; solve A1 z = mu_k
  for (int r = 0; r < 64; ++r) {
    double v = -Jk[r * 64 + i];              // coalesced
    if (i <= r) Sp[((r * (r + 1)) >> 1) + i] = v;
  }
  double rv = (double)muk[k * 64 + i];
  __syncthreads();
  double dii = Sp[Ti + i] - dn;
  double linv_a = 0.0;
  for (int j = 0; j < 64; ++j) {
    double s_ = sqrt(dii);                   // valid on lane j (others unused)
    double lv = 1.0 / s_;
    double linv_b = __shfl(lv, j, 64);
    double lij = 0.0;
    if (i == j) { linv_a = lv; Sp[Ti + j] = s_; }
    else if (i > j) {
      lij = Sp[Ti + j] * linv_b;
      Sp[Ti + j] = lij;
      dii -= lij * lij;
    }
    __syncthreads();
    int cb = (((j + 1) * (j + 2)) >> 1) + j; // &S[j+1][j]
    for (int l = j + 1; l < i; ++l) {
      Sp[Ti + l] -= lij * Sp[cb];
      cb += l + 1;
    }
    __syncthreads();
  }
  // forward solve L y = rv
  for (int j = 0; j < 64; ++j) {
    double xj = __shfl(rv * linv_a, j, 64);
    if (i == j) rv = xj;
    else if (i > j) rv -= Sp[Ti + j] * xj;
  }
  // backward solve L^T x = y
  for (int j = 63; j >= 0; --j) {
    double xj = __shfl(rv * linv_a, j, 64);
    if (i == j) rv = xj;
    else if (i < j) rv -= Sp[((j * (j + 1)) >> 1) + i] * xj;
  }
  double zsum = rv;
  for (int o = 32; o > 0; o >>= 1) zsum += __shfl_xor(zsum, o, 64);
  double s_nk = -zsum;
  double w1 = s_nk * dn;
  double dmw = mn * w1;
  for (int o = 32; o > 0; o >>= 1) dmw += __shfl_xor(dmw, o, 64);

  // ---- Phase B: P = -(Dg iJ Dg) - Dg ; chol ; logdet ; t = P^{-1} w1
  __syncthreads();
  for (int r = 0; r < 64; ++r) {
    double v = -(dsh[r] * iJ[r * 64 + i] * dsh[i]);   // coalesced b64
    if (i <= r) Sp[((r * (r + 1)) >> 1) + i] = v;
  }
  __syncthreads();
  dii = Sp[Ti + i] - dn;
  double myljj = 1.0;
  for (int j = 0; j < 64; ++j) {
    double s_ = sqrt(dii);
    double lv = 1.0 / s_;
    double linv_b = __shfl(lv, j, 64);
    double lij = 0.0;
    if (i == j) { linv_a = lv; myljj = s_; Sp[Ti + j] = s_; }
    else if (i > j) {
      lij = Sp[Ti + j] * linv_b;
      Sp[Ti + j] = lij;
      dii -= lij * lij;
    }
    __syncthreads();
    int cb = (((j + 1) * (j + 2)) >> 1) + j;
    for (int l = j + 1; l < i; ++l) {
      Sp[Ti + l] -= lij * Sp[cb];
      cb += l + 1;
    }
    __syncthreads();
  }
  double sl = log(myljj);
  for (int o = 32; o > 0; o >>= 1) sl += __shfl_xor(sl, o, 64);
  // t-solve
  double tv = w1;
  for (int j = 0; j < 64; ++j) {
    double xj = __shfl(tv * linv_a, j, 64);
    if (i == j) tv = xj;
    else if (i > j) tv -= Sp[Ti + j] * xj;
  }
  for (int j = 63; j >= 0; --j) {
    double xj = __shfl(tv * linv_a, j, 64);
    if (i == j) tv = xj;
    else if (i < j) tv -= Sp[((j * (j + 1)) >> 1) + i] * xj;
  }
  double dwt = w1 * tv;
  for (int o = 32; o > 0; o >>= 1) dwt += __shfl_xor(dwt, o, 64);
  if (i == 0) {
    logprob[nk] = dmw + quadg[nk] - 0.25 * dwt
                + 32.0 * 0.6931471805599453 + sl
                - 32.0 * 1.8378770664093453
                + logpi[k];
  }

  // ---- samples: rr in registers, L^T solve with shfl broadcasts
  double rr[S_];
  {
    uint32_t base = (uint32_t)((nk * 64 + i) * S_);
#pragma unroll
    for (int s = 0; s < S_; ++s)
      rr[s] = (double)jax_normal_f32(0u, 42u, base + s);
  }
  for (int q = 63; q >= 0; --q) {
    double rq[S_];
#pragma unroll
    for (int s = 0; s < S_; ++s) rq[s] = __shfl(rr[s] * linv_a, q, 64);
    if (i == q) {
#pragma unroll
      for (int s = 0; s < S_; ++s) rr[s] = rq[s];
    } else if (i < q) {
      double l = Sp[((q * (q + 1)) >> 1) + i];
#pragma unroll
      for (int s = 0; s < S_; ++s) rr[s] -= l * rq[s];
    }
  }
  double xm = 0.5 * tv;
#pragma unroll
  for (int s = 0; s < S_; ++s)
    xs[(nk * S_ + s) * 64 + i] = (float)(xm + 0.7071067811865476 * rr[s]);
}

// ---------------- softmax over K + categorical (s=0) + x_subsamples ----------------
__global__ __launch_bounds__(64) void k_softcat(const double* __restrict__ logprob,
                                                const float* __restrict__ xs,
                                                float* __restrict__ outz,
                                                float* __restrict__ outx) {
  __shared__ double lz[K_];
  __shared__ int zc;
  int n = blockIdx.x, t = threadIdx.x;
  if (t == 0) {
    double lp[K_];
    double m = -1e300;
    for (int q = 0; q < K_; ++q) { lp[q] = logprob[n * K_ + q]; m = fmax(m, lp[q]); }
    double ss = 0.0;
    for (int q = 0; q < K_; ++q) ss += exp(lp[q] - m);
    double lsum = log(ss);
    float best = -INFINITY; int bi = 0;
    for (int q = 0; q < K_; ++q) {
      double l = (lp[q] - m) - lsum;
      lz[q] = l;
      float g = jax_gumbel_f32(0u, 7u, (uint32_t)(n * 100 + q));
      float sc = g + (float)l;
      if (sc > best) { best = sc; bi = q; }
    }
    zc = bi;
  }
  __syncthreads();
  if (t < K_) outz[n * K_ + t] = (float)lz[t];
  outx[n * D_ + t] = xs[(n * K_ + zc) * S_ * D_ + t];
}

// ---------------- decoder: MFMA bf16, 64 rows/block, 4 waves ----------------
__global__ __launch_bounds__(256) void k_dec(const float* __restrict__ xs,
                                             const ushort* __restrict__ W1F,
                                             const ushort* __restrict__ WmuF,
                                             const ushort* __restrict__ WvF,
                                             const float* __restrict__ b1,
                                             const float* __restrict__ bmu,
                                             const float* __restrict__ bvv,
                                             float* __restrict__ outm,
                                             float* __restrict__ outv) {
  __shared__ __align__(16) ushort hd[4][16][520];
  int t = threadIdx.x;
  int w = t >> 6, l = t & 63;
  int lr = l & 15, lg = l >> 4;
  int row0 = blockIdx.x * 64 + w * 16;

  short8v xhi[2], xlo[2];
  {
    const float* xrow = xs + (size_t)(row0 + lr) * 64 + lg * 8;
#pragma unroll
    for (int ks = 0; ks < 2; ++ks) {
      ushort hi[8], lo[8];
#pragma unroll
      for (int e = 0; e < 8; ++e) {
        float xv = xrow[ks * 32 + e];
        ushort h16 = bf16rne(xv);
        hi[e] = h16;
        lo[e] = bf16rne(xv - bf2f(h16));
      }
      xhi[ks] = *(short8v*)hi;
      xlo[ks] = *(short8v*)lo;
    }
  }

  const short8v* W1v = (const short8v*)W1F;
#pragma unroll 4
  for (int ct = 0; ct < 32; ++ct) {
    f32x4 acc = {0.f, 0.f, 0.f, 0.f};
    short8v b0 = W1v[(ct * 2 + 0) * 64 + l];
    short8v b1v = W1v[(ct * 2 + 1) * 64 + l];
    acc = __builtin_amdgcn_mfma_f32_16x16x32_bf16(xhi[0], b0, acc, 0, 0, 0);
    acc = __builtin_amdgcn_mfma_f32_16x16x32_bf16(xlo[0], b0, acc, 0, 0, 0);
    acc = __builtin_amdgcn_mfma_f32_16x16x32_bf16(xhi[1], b1v, acc, 0, 0, 0);
    acc = __builtin_amdgcn_mfma_f32_16x16x32_bf16(xlo[1], b1v, acc, 0, 0, 0);
    int c = ct * 16 + lr;
    float bb = b1[c];
#pragma unroll
    for (int r = 0; r < 4; ++r)
      hd[w][lg * 4 + r][c] = bf16rne(tanhf(acc[r] + bb));
  }
  __syncthreads();

  short8v ha[16];
#pragma unroll
  for (int ks = 0; ks < 16; ++ks)
    ha[ks] = *(const short8v*)&hd[w][lr][ks * 32 + lg * 8];

  const short8v* Wmv = (const short8v*)WmuF;
  const short8v* Wvv = (const short8v*)WvF;
  for (int ct = 0; ct < 49; ++ct) {
    f32x4 aM = {0.f, 0.f, 0.f, 0.f};
    f32x4 aV = {0.f, 0.f, 0.f, 0.f};
#pragma unroll
    for (int ks = 0; ks < 16; ++ks) {
      short8v bm = Wmv[(ct * 16 + ks) * 64 + l];
      short8v bv = Wvv[(ct * 16 + ks) * 64 + l];
      aM = __builtin_amdgcn_mfma_f32_16x16x32_bf16(ha[ks], bm, aM, 0, 0, 0);
      aV = __builtin_amdgcn_mfma_f32_16x16x32_bf16(ha[ks], bv, aV, 0, 0, 0);
    }
    int c = ct * 16 + lr;
    float bm_ = bmu[c], bv_ = bvv[c];
#pragma unroll
    for (int r = 0; r < 4; ++r) {
      size_t o = (size_t)(row0 + lg * 4 + r) * INDIM_ + c;
      outm[o] = aM[r] + bm_;
      outv[o] = sp32(aV[r] + bv_) + 1e-6f;
    }
  }
}

// ---------------- launch ----------------
extern "C" void kernel_launch(void* const* d_in, const int* in_sizes, int n_in,
                              void* d_out, int out_size, void* d_ws, size_t ws_size,
                              hipStream_t stream) {
  const float* y     = (const float*)d_in[0];
  const float* eW1   = (const float*)d_in[1];
  const float* eb1   = (const float*)d_in[2];
  const float* eWmu  = (const float*)d_in[3];
  const float* ebmu  = (const float*)d_in[4];
  const float* eWv   = (const float*)d_in[5];
  const float* ebv   = (const float*)d_in[6];
  const float* muk   = (const float*)d_in[7];
  const float* Lraw  = (const float*)d_in[8];
  const float* piraw = (const float*)d_in[9];
  const float* dW1   = (const float*)d_in[10];
  const float* db1   = (const float*)d_in[11];
  const float* dWmu  = (const float*)d_in[12];
  const float* dbmu  = (const float*)d_in[13];
  const float* dWv   = (const float*)d_in[14];
  const float* dbv   = (const float*)d_in[15];

  double* W      = (double*)d_ws;
  double* h      = W;             // 262144 doubles (reused as bf16 frag store by k_prep)
  double* mu     = W + 262144;    // 32768
  double* dvec   = W + 294912;    // 32768
  double* J      = W + 327680;    // 40960
  double* iJ     = W + 368640;    // 40960
  double* logpi  = W + 409600;    // 16
  double* logpr  = W + 409616;    // 5120
  double* quadg  = W + 414736;    // 5120
  double* base2  = W + 419856;
  float*  xs     = (float*)base2;                 // 3,276,800 floats
  float*  J32    = xs + 3276800;                  // 40960 floats
  float*  LU32   = J32 + 40960;                   // 40960
  float*  d32    = LU32 + 40960;                  // 32768
  float*  muph   = d32 + 32768;                   // 32768
  int*    piv    = (int*)(muph + 32768);          // 640 ints

  ushort* hF   = (ushort*)h;
  ushort* W1F  = hF;
  ushort* WmuF = hF + 32768;
  ushort* WvF  = hF + 434176;

  float* outm = (float*)d_out;            // (N,K,S,784)
  float* outv = outm + 40140800;          // (N,K,S,784)
  float* outx = outm + 80281600;          // (N,64)
  float* outz = outm + 80314368;          // (N,10)

  k_enc_h    <<<N_, 256, 0, stream>>>(y, eW1, eb1, h);
  k_enc_muvar<<<N_, 128, 0, stream>>>(h, eWmu, ebmu, eWv, ebv, mu, dvec, d32, muph);
  k_prep     <<<408, 256, 0, stream>>>(dW1, dWmu, dWv, hF);
  k_gmm      <<<K_, 64, 0, stream>>>(Lraw, piraw, J, iJ, logpi);
  k_lu32     <<<K_, 64, 0, stream>>>(Lraw, J32, LU32, piv);
  k_quad32   <<<N_ * K_, 64, 0, stream>>>(J32, LU32, piv, d32, muph, quadg);
  k_pernk    <<<N_ * K_, 64, 0, stream>>>(dvec, mu, muk, J, iJ, logpi, quadg, logpr, xs);
  k_softcat  <<<N_, 64, 0, stream>>>(logpr, xs, outz, outx);
  k_dec      <<<800, 256, 0, stream>>>(xs, W1F, WmuF, WvF, db1, dbmu, dbv, outm, outv);
}

// Round 7
// 1520.364 us; speedup vs baseline: 3.4743x; 1.5172x over previous
//
#include <hip/hip_runtime.h>
#include <math.h>
#include <stdint.h>

#define N_ 512
#define D_ 64
#define K_ 10
#define S_ 10
#define INDIM_ 784
#define H_ 512
#define DP1 (D_ + 1)

typedef __attribute__((ext_vector_type(8))) short short8v;
typedef __attribute__((ext_vector_type(4))) float f32x4;

// ---------------- JAX Threefry-2x32 (20 rounds) ----------------
__device__ __forceinline__ uint32_t rotl32(uint32_t v, int r) { return (v << r) | (v >> (32 - r)); }

__device__ __forceinline__ void threefry2x32(uint32_t k0, uint32_t k1,
                                             uint32_t x0, uint32_t x1,
                                             uint32_t& o0, uint32_t& o1) {
  uint32_t k2 = k0 ^ k1 ^ 0x1BD11BDAu;
  x0 += k0; x1 += k1;
#define TFR(r) { x0 += x1; x1 = rotl32(x1, r); x1 ^= x0; }
  TFR(13) TFR(15) TFR(26) TFR(6)
  x0 += k1; x1 += k2 + 1u;
  TFR(17) TFR(29) TFR(16) TFR(24)
  x0 += k2; x1 += k0 + 2u;
  TFR(13) TFR(15) TFR(26) TFR(6)
  x0 += k0; x1 += k1 + 3u;
  TFR(17) TFR(29) TFR(16) TFR(24)
  x0 += k1; x1 += k2 + 4u;
  TFR(13) TFR(15) TFR(26) TFR(6)
  x0 += k2; x1 += k0 + 5u;
#undef TFR
  o0 = x0; o1 = x1;
}

__device__ __forceinline__ uint32_t jax_bits32(uint32_t k0, uint32_t k1, uint32_t idx) {
  uint32_t o0, o1; threefry2x32(k0, k1, 0u, idx, o0, o1);
  return o0 ^ o1;
}

__device__ __forceinline__ float bits_to_u01(uint32_t bits) {
  return __uint_as_float((bits >> 9) | 0x3F800000u) - 1.0f;
}

__device__ __forceinline__ float erfinv_f32(float x) {
  float w = -log1pf(-x * x);
  float p;
  if (w < 5.0f) {
    w = w - 2.5f;
    p = 2.81022636e-08f;
    p = fmaf(p, w, 3.43273939e-07f);
    p = fmaf(p, w, -3.5233877e-06f);
    p = fmaf(p, w, -4.39150654e-06f);
    p = fmaf(p, w, 0.00021858087f);
    p = fmaf(p, w, -0.00125372503f);
    p = fmaf(p, w, -0.00417768164f);
    p = fmaf(p, w, 0.246640727f);
    p = fmaf(p, w, 1.50140941f);
  } else {
    w = sqrtf(w) - 3.0f;
    p = -0.000200214257f;
    p = fmaf(p, w, 0.000100950558f);
    p = fmaf(p, w, 0.00134934322f);
    p = fmaf(p, w, -0.00367342844f);
    p = fmaf(p, w, 0.00573950773f);
    p = fmaf(p, w, -0.0076224613f);
    p = fmaf(p, w, 0.00943887047f);
    p = fmaf(p, w, 1.00167406f);
    p = fmaf(p, w, 2.83297682f);
  }
  return p * x;
}

__device__ __forceinline__ float jax_normal_f32(uint32_t k0, uint32_t k1, uint32_t idx) {
  uint32_t bits = jax_bits32(k0, k1, idx);
  float u = bits_to_u01(bits);
  const float lo = -0.99999994f;
  float v = u * (1.0f - lo) + lo;
  v = fmaxf(lo, v);
  return 1.41421356f * erfinv_f32(v);
}

__device__ __forceinline__ float jax_gumbel_f32(uint32_t k0, uint32_t k1, uint32_t idx) {
  uint32_t bits = jax_bits32(k0, k1, idx);
  float u = bits_to_u01(bits);
  const float tiny = 1.17549435e-38f;
  float v = u * (1.0f - tiny) + tiny;
  v = fmaxf(tiny, v);
  return -logf(-logf(v));
}

__device__ __forceinline__ float sp32(float x) { return fmaxf(x, 0.f) + log1pf(expf(-fabsf(x))); }
__device__ __forceinline__ float sp32cr(float x) {
  double xd = (double)x;
  return (float)(fmax(xd, 0.0) + log1p(exp(-fabs(xd))));
}
__device__ __forceinline__ double sp64(double x) { return fmax(x, 0.0) + log1p(exp(-fabs(x))); }

__device__ __forceinline__ ushort bf16rne(float f) {
  uint32_t u = __float_as_uint(f);
  uint32_t r = (u + 0x7FFFu + ((u >> 16) & 1u)) >> 16;
  return (ushort)r;
}
__device__ __forceinline__ float bf2f(ushort b) { return __uint_as_float(((uint32_t)b) << 16); }

// f64 broadcast from lane l via v_readlane (SGPR path, off the LDS pipe)
__device__ __forceinline__ double rdlane(double v, int l) {
  union { double d; uint32_t u[2]; } x; x.d = v;
  uint32_t lo = __builtin_amdgcn_readlane((int)x.u[0], l);
  uint32_t hi = __builtin_amdgcn_readlane((int)x.u[1], l);
  union { double d; uint32_t u[2]; } y; y.u[0] = lo; y.u[1] = hi;
  return y.d;
}

// ---------------- encoder ----------------
__global__ __launch_bounds__(256) void k_enc_h(const float* __restrict__ y,
                                               const float* __restrict__ W1,
                                               const float* __restrict__ b1,
                                               double* __restrict__ h) {
  int n = blockIdx.x, t = threadIdx.x;
  const float* yr = y + n * INDIM_;
  double a0 = 0.0, a1 = 0.0;
  for (int d = 0; d < INDIM_; ++d) {
    double yv = (double)yr[d];
    a0 += yv * (double)W1[d * H_ + t];
    a1 += yv * (double)W1[d * H_ + t + 256];
  }
  h[n * H_ + t] = tanh(a0 + (double)b1[t]);
  h[n * H_ + t + 256] = tanh(a1 + (double)b1[t + 256]);
}

__global__ __launch_bounds__(128) void k_enc_muvar(const double* __restrict__ h,
                                                   const float* __restrict__ Wmu,
                                                   const float* __restrict__ bmu,
                                                   const float* __restrict__ Wv,
                                                   const float* __restrict__ bv,
                                                   double* __restrict__ mu,
                                                   double* __restrict__ dvec,
                                                   float* __restrict__ d32,
                                                   float* __restrict__ muph) {
  __shared__ float mu32s[D_], var32s[D_];
  int n = blockIdx.x, t = threadIdx.x;
  int c = t & 63;
  const float* Wsel = (t < 64) ? Wmu : Wv;
  const double* hr = h + n * H_;
  double acc = 0.0;
  for (int q = 0; q < H_; ++q) acc += hr[q] * (double)Wsel[q * D_ + c];
  if (t < 64) {
    double m = acc + (double)bmu[c];
    mu[n * D_ + c] = m;
    mu32s[c] = (float)m;
  } else {
    double a = acc + (double)bv[c];
    double var = sp64(a) + 1e-6;
    dvec[n * D_ + c] = -0.5 / var;
    float var32 = sp32cr((float)a) + 1e-6f;
    var32s[c] = var32;
    d32[n * D_ + c] = (-0.5f) / var32;
  }
  __syncthreads();
  if (t < 64) {
    float var32 = var32s[c];
    float dd = (-0.5f) / var32;
    float eta1 = mu32s[c] / var32;
    float neg2d = -2.0f * dd;
    muph[n * D_ + c] = eta1 / neg2d;
  }
}

// ---------------- weight re-layout to MFMA fragment order (bf16) ----------------
__global__ __launch_bounds__(256) void k_prep(const float* __restrict__ W1,
                                              const float* __restrict__ Wmu,
                                              const float* __restrict__ Wv,
                                              ushort* __restrict__ hF) {
  int t = blockIdx.x * 256 + threadIdx.x;
  int chunk = t >> 6, l = t & 63;
  if (chunk >= 1632) return;
  int lr = l & 15, lg = l >> 4;
  const float* src; int C, ct, ks; ushort* dst;
  if (chunk < 64)       { src = W1;  C = 512; ct = chunk >> 1;  ks = chunk & 1;
                          dst = hF + chunk * 512; }
  else if (chunk < 848) { int c2 = chunk - 64;  src = Wmu; C = 784; ct = c2 / 16; ks = c2 % 16;
                          dst = hF + 32768 + c2 * 512; }
  else                  { int c2 = chunk - 848; src = Wv;  C = 784; ct = c2 / 16; ks = c2 % 16;
                          dst = hF + 434176 + c2 * 512; }
  ushort vals[8];
#pragma unroll
  for (int e = 0; e < 8; ++e)
    vals[e] = bf16rne(src[(ks * 32 + lg * 8 + e) * C + ct * 16 + lr]);
  *(short8v*)(dst + l * 8) = *(short8v*)vals;
}

// ---------------- GMM unpack: invJ_k, g_k = B^{-1}mu_k, log pi ----------------
__global__ __launch_bounds__(64) void k_gmm(const float* __restrict__ Lraw,
                                            const float* __restrict__ piraw,
                                            const float* __restrict__ muk,
                                            double* __restrict__ iJout,
                                            double* __restrict__ gko,
                                            double* __restrict__ logpi) {
  __shared__ float Lk[D_][DP1];
  __shared__ double dg[D_];
  __shared__ double Li[D_][DP1];
  int k = blockIdx.x, i = threadIdx.x;
  const float* Lr = Lraw + k * D_ * D_;
  for (int j = 0; j < i; ++j) Lk[i][j] = Lr[i * D_ + j];
  dg[i] = sp64((double)Lr[i * D_ + i]);
  __syncthreads();
#define LKD(r, c) ((c) < (r) ? (double)Lk[r][c] : dg[r])
  {
    int j = i;
    Li[j][j] = 1.0 / dg[j];
    for (int r = j + 1; r < D_; ++r) {
      double s = 0.0;
      for (int m = j; m < r; ++m) s += LKD(r, m) * Li[m][j];
      Li[r][j] = -s / dg[r];
    }
  }
  __syncthreads();
  for (int j = 0; j < D_; ++j) {
    int m0 = max(i, j);
    double s = 0.0;
    for (int m = m0; m < D_; ++m) s += Li[m][i] * Li[m][j];
    iJout[k * D_ * D_ + i * D_ + j] = -2.0 * s;
  }
#undef LKD
  // g_k = 2 * Lk^{-T} (Lk^{-1} mu_k)   (B = 0.5 Lk Lk^T)
  {
    double rv = (double)muk[k * D_ + i];
    for (int j = 0; j < D_; ++j) {
      double xj = __shfl(rv, j, 64) / dg[j];
      if (i == j) rv = xj;
      else if (i > j) rv -= (double)Lk[i][j] * xj;
    }
    for (int j = D_ - 1; j >= 0; --j) {
      double xj = __shfl(rv, j, 64) / dg[j];
      if (i == j) rv = xj;
      else if (i < j) rv -= (double)Lk[j][i] * xj;
    }
    gko[k * D_ + i] = 2.0 * rv;
  }
  if (k == 0 && i == 0) {
    double m = (double)piraw[0];
    for (int q = 1; q < K_; ++q) m = fmax(m, (double)piraw[q]);
    double ss = 0.0;
    for (int q = 0; q < K_; ++q) ss += exp((double)piraw[q] - m);
    double lse = m + log(ss);
    for (int q = 0; q < K_; ++q) logpi[q] = (double)piraw[q] - lse;
  }
}

// ---------------- f32 LAPACK-emulation: J32 (f32 sgemm-fold) + sgetf2 LU (per k) ----------------
__global__ __launch_bounds__(64) void k_lu32(const float* __restrict__ Lraw,
                                             float* __restrict__ J32g,
                                             float* __restrict__ LU32g,
                                             int* __restrict__ pivg) {
  __shared__ float Lk[D_][DP1];
  __shared__ float A[D_][DP1];
  __shared__ float col[D_];
  __shared__ int piv_s[D_];
  int k = blockIdx.x, i = threadIdx.x;
  const float* Lr = Lraw + k * D_ * D_;
  for (int j = 0; j < D_; ++j)
    Lk[i][j] = (j < i) ? Lr[i * D_ + j] : ((j == i) ? sp32cr(Lr[i * D_ + i]) : 0.0f);
  __syncthreads();
  for (int j = 0; j < D_; ++j) {
    float s = 0.0f;
    for (int q = 0; q < D_; ++q) s = fmaf(Lk[i][q], Lk[j][q], s);
    float v = -0.5f * s;
    A[i][j] = v;
    J32g[k * D_ * D_ + i * D_ + j] = v;
  }
  __syncthreads();
  for (int j = 0; j < D_; ++j) {
    col[i] = fabsf(A[i][j]);
    __syncthreads();
    if (i == 0) {
      int p = j; float mx = col[j];
      for (int r = j + 1; r < D_; ++r) if (col[r] > mx) { mx = col[r]; p = r; }
      piv_s[j] = p;
    }
    __syncthreads();
    int p = piv_s[j];
    if (p != j) { float tmp = A[j][i]; A[j][i] = A[p][i]; A[p][i] = tmp; }
    __syncthreads();
    float rec = 1.0f / A[j][j];
    if (i > j) A[i][j] = A[i][j] * rec;
    __syncthreads();
    if (i > j) {
      float x = A[i][j];
      for (int l = j + 1; l < D_; ++l) A[i][l] = fmaf(x, -A[j][l], A[i][l]);
    }
    __syncthreads();
  }
  for (int j = 0; j < D_; ++j) LU32g[k * D_ * D_ + i * D_ + j] = A[i][j];
  pivg[k * D_ + i] = piv_s[i];
}

// ---------------- f32-emulated quad2 per (n,k) — register-column solves ----------------
__global__ __launch_bounds__(64) void k_quad32(const float* __restrict__ J32g,
                                               const float* __restrict__ LU32g,
                                               const int* __restrict__ pivg,
                                               const float* __restrict__ d32g,
                                               const float* __restrict__ muphg,
                                               double* __restrict__ quadg) {
  __shared__ float LUs[D_][DP1];
  __shared__ float dsh[D_], mph[D_];
  __shared__ int pshare[D_];
  __shared__ double red[D_];
  int nk = blockIdx.x;
  int n = nk / K_, k = nk - n * K_;
  int tj = threadIdx.x;
  for (int r = 0; r < D_; ++r) LUs[r][tj] = LU32g[k * 4096 + r * 64 + tj];
  dsh[tj] = d32g[n * 64 + tj];
  mph[tj] = muphg[n * 64 + tj];
  int pv = pivg[k * 64 + tj];
  int perm = tj;
  for (int j = 0; j < 64; ++j) {
    int pj = __shfl(pv, j, 64);
    int vj = __shfl(perm, j, 64);
    int vp = __shfl(perm, pj, 64);
    if (tj == j) perm = vp;
    else if (tj == pj) perm = vj;
  }
  pshare[tj] = perm;
  __syncthreads();
  float Tc[64];
#pragma unroll
  for (int i2 = 0; i2 < 64; ++i2) {
    int pr = pshare[i2];
    float v = J32g[k * 4096 + pr * 64 + tj];
    if (pr == tj) v = v + dsh[tj];
    Tc[i2] = v;
  }
#pragma unroll
  for (int r = 0; r < 64; ++r) {
    float x = Tc[r];
#pragma unroll
    for (int i2 = r + 1; i2 < 64; ++i2)
      Tc[i2] = fmaf(LUs[i2][r], -x, Tc[i2]);
  }
#pragma unroll
  for (int r = 63; r >= 0; --r) {
    float x = Tc[r] / LUs[r][r];
    Tc[r] = x;
#pragma unroll
    for (int i2 = 0; i2 < r; ++i2)
      Tc[i2] = fmaf(LUs[i2][r], -x, Tc[i2]);
  }
  __syncthreads();
#pragma unroll
  for (int i2 = 0; i2 < 64; ++i2) LUs[i2][tj] = Tc[i2];
  __syncthreads();
  double part = 0.0;
#pragma unroll
  for (int d2 = 0; d2 < 64; ++d2) {
    float a = dsh[d2] * Tc[d2];
    float b = dsh[tj] * LUs[tj][d2];
    float w = 0.5f * (a + b);
    float t1 = mph[d2] * w;
    float t2 = t1 * mph[tj];
    part += (double)t2;
  }
  red[tj] = part; __syncthreads();
  for (int off = 32; off > 0; off >>= 1) {
    if (tj < off) red[tj] += red[tj + off];
    __syncthreads();
  }
  if (tj == 0) quadg[nk] = red[0];
}

// ---------------- per-(n,k): register chol of P, one factorization, 12 RHS ----------------
__global__ __launch_bounds__(64) void k_pernk(const double* __restrict__ dvec,
                                              const double* __restrict__ mu,
                                              const double* __restrict__ gk,
                                              const double* __restrict__ iJg,
                                              const double* __restrict__ logpi,
                                              const double* __restrict__ quadg,
                                              double* __restrict__ logprob,
                                              float* __restrict__ xs) {
  __shared__ double Sp[2080];      // packed lower L, row j at j(j+1)/2
  int nk = blockIdx.x;
  int n = nk / K_, k = nk - n * K_;
  int i = threadIdx.x;
  int Ti = (i * (i + 1)) >> 1;

  double dn = dvec[n * 64 + i];
  double mn = mu[n * 64 + i];
  const double* iJ = iJg + k * 4096;

  // ---- form P row i in registers: P[i][r] = -(d_i * iJ[i][r] * d_r) - (r==i)d_i
  double a[64];
#pragma unroll
  for (int r = 0; r < 64; ++r) {
    double drr = rdlane(dn, r);
    double v = -(dn * iJ[r * 64 + i] * drr);   // iJ symmetric; coalesced load
    if (r == i) v -= dn;
    a[r] = v;
  }

  // ---- register Cholesky (readlane broadcasts, unconditional trailing update)
  double linv_a = 0.0, myljj = 1.0;
#pragma unroll
  for (int j = 0; j < 64; ++j) {
    double s_ = sqrt(a[j]);                 // valid on lane j
    double lv = 1.0 / s_;
    double lb = rdlane(lv, j);
    if (i == j) { linv_a = lv; myljj = s_; a[j] = s_; }
    else a[j] = a[j] * lb;                  // lij for lanes i>j (garbage elsewhere, unused)
    double lij = a[j];
#pragma unroll
    for (int l = j + 1; l < 64; ++l) {
      double t = rdlane(a[j], l);           // L[l][j] from lane l
      a[l] = fma(-lij, t, a[l]);            // lanes i<l: garbage slot, never read
    }
  }

  // ---- write packed L to LDS for backward/sample solves
#pragma unroll
  for (int j = 0; j < 64; ++j)
    if (j <= i) Sp[Ti + j] = a[j];
  __syncthreads();

  // ---- z = P^{-1} (E g_k): s_nk = -sum(z)
  double rv = (-dn) * gk[k * 64 + i];
#pragma unroll
  for (int j = 0; j < 64; ++j) {
    double xj = __shfl(rv * linv_a, j, 64);
    if (i == j) rv = xj;
    else if (i > j) rv = fma(-a[j], xj, rv);
  }
#pragma unroll
  for (int j = 63; j >= 0; --j) {
    double xj = __shfl(rv * linv_a, j, 64);
    if (i == j) rv = xj;
    else if (i < j) rv = fma(-Sp[((j * (j + 1)) >> 1) + i], xj, rv);
  }
  double zsum = rv;
  for (int o = 32; o > 0; o >>= 1) zsum += __shfl_xor(zsum, o, 64);
  double s_nk = -zsum;
  double w1 = s_nk * dn;
  double dmw = mn * w1;
  for (int o = 32; o > 0; o >>= 1) dmw += __shfl_xor(dmw, o, 64);
  double sl = log(myljj);
  for (int o = 32; o > 0; o >>= 1) sl += __shfl_xor(sl, o, 64);

  // ---- t = P^{-1} w1
  double tv = w1;
#pragma unroll
  for (int j = 0; j < 64; ++j) {
    double xj = __shfl(tv * linv_a, j, 64);
    if (i == j) tv = xj;
    else if (i > j) tv = fma(-a[j], xj, tv);
  }
#pragma unroll
  for (int j = 63; j >= 0; --j) {
    double xj = __shfl(tv * linv_a, j, 64);
    if (i == j) tv = xj;
    else if (i < j) tv = fma(-Sp[((j * (j + 1)) >> 1) + i], xj, tv);
  }
  double dwt = w1 * tv;
  for (int o = 32; o > 0; o >>= 1) dwt += __shfl_xor(dwt, o, 64);
  if (i == 0) {
    logprob[nk] = dmw + quadg[nk] - 0.25 * dwt
                + 32.0 * 0.6931471805599453 + sl
                - 32.0 * 1.8378770664093453
                + logpi[k];
  }

  // ---- samples: L^T e = eps (10 RHS), x = 0.5 t + eps/sqrt(2)
  double rr[S_];
  {
    uint32_t base = (uint32_t)((nk * 64 + i) * S_);
#pragma unroll
    for (int s = 0; s < S_; ++s)
      rr[s] = (double)jax_normal_f32(0u, 42u, base + s);
  }
  for (int q = 63; q >= 0; --q) {
    double l_ = (i < q) ? Sp[((q * (q + 1)) >> 1) + i] : 0.0;
#pragma unroll
    for (int s = 0; s < S_; ++s) {
      double rq = __shfl(rr[s] * linv_a, q, 64);
      if (i == q) rr[s] = rq;
      else rr[s] = fma(-l_, rq, rr[s]);
    }
  }
  double xm = 0.5 * tv;
#pragma unroll
  for (int s = 0; s < S_; ++s)
    xs[(nk * S_ + s) * 64 + i] = (float)(xm + 0.7071067811865476 * rr[s]);
}

// ---------------- softmax over K + categorical (s=0) + x_subsamples ----------------
__global__ __launch_bounds__(64) void k_softcat(const double* __restrict__ logprob,
                                                const float* __restrict__ xs,
                                                float* __restrict__ outz,
                                                float* __restrict__ outx) {
  __shared__ double lz[K_];
  __shared__ int zc;
  int n = blockIdx.x, t = threadIdx.x;
  if (t == 0) {
    double lp[K_];
    double m = -1e300;
    for (int q = 0; q < K_; ++q) { lp[q] = logprob[n * K_ + q]; m = fmax(m, lp[q]); }
    double ss = 0.0;
    for (int q = 0; q < K_; ++q) ss += exp(lp[q] - m);
    double lsum = log(ss);
    float best = -INFINITY; int bi = 0;
    for (int q = 0; q < K_; ++q) {
      double l = (lp[q] - m) - lsum;
      lz[q] = l;
      float g = jax_gumbel_f32(0u, 7u, (uint32_t)(n * 100 + q));
      float sc = g + (float)l;
      if (sc > best) { best = sc; bi = q; }
    }
    zc = bi;
  }
  __syncthreads();
  if (t < K_) outz[n * K_ + t] = (float)lz[t];
  outx[n * D_ + t] = xs[(n * K_ + zc) * S_ * D_ + t];
}

// ---------------- decoder: MFMA bf16, 64 rows/block, 4 waves ----------------
__global__ __launch_bounds__(256) void k_dec(const float* __restrict__ xs,
                                             const ushort* __restrict__ W1F,
                                             const ushort* __restrict__ WmuF,
                                             const ushort* __restrict__ WvF,
                                             const float* __restrict__ b1,
                                             const float* __restrict__ bmu,
                                             const float* __restrict__ bvv,
                                             float* __restrict__ outm,
                                             float* __restrict__ outv) {
  __shared__ __align__(16) ushort hd[4][16][520];
  int t = threadIdx.x;
  int w = t >> 6, l = t & 63;
  int lr = l & 15, lg = l >> 4;
  int row0 = blockIdx.x * 64 + w * 16;

  short8v xhi[2], xlo[2];
  {
    const float* xrow = xs + (size_t)(row0 + lr) * 64 + lg * 8;
#pragma unroll
    for (int ks = 0; ks < 2; ++ks) {
      ushort hi[8], lo[8];
#pragma unroll
      for (int e = 0; e < 8; ++e) {
        float xv = xrow[ks * 32 + e];
        ushort h16 = bf16rne(xv);
        hi[e] = h16;
        lo[e] = bf16rne(xv - bf2f(h16));
      }
      xhi[ks] = *(short8v*)hi;
      xlo[ks] = *(short8v*)lo;
    }
  }

  const short8v* W1v = (const short8v*)W1F;
#pragma unroll 4
  for (int ct = 0; ct < 32; ++ct) {
    f32x4 acc = {0.f, 0.f, 0.f, 0.f};
    short8v b0 = W1v[(ct * 2 + 0) * 64 + l];
    short8v b1v = W1v[(ct * 2 + 1) * 64 + l];
    acc = __builtin_amdgcn_mfma_f32_16x16x32_bf16(xhi[0], b0, acc, 0, 0, 0);
    acc = __builtin_amdgcn_mfma_f32_16x16x32_bf16(xlo[0], b0, acc, 0, 0, 0);
    acc = __builtin_amdgcn_mfma_f32_16x16x32_bf16(xhi[1], b1v, acc, 0, 0, 0);
    acc = __builtin_amdgcn_mfma_f32_16x16x32_bf16(xlo[1], b1v, acc, 0, 0, 0);
    int c = ct * 16 + lr;
    float bb = b1[c];
#pragma unroll
    for (int r = 0; r < 4; ++r)
      hd[w][lg * 4 + r][c] = bf16rne(tanhf(acc[r] + bb));
  }
  __syncthreads();

  short8v ha[16];
#pragma unroll
  for (int ks = 0; ks < 16; ++ks)
    ha[ks] = *(const short8v*)&hd[w][lr][ks * 32 + lg * 8];

  const short8v* Wmv = (const short8v*)WmuF;
  const short8v* Wvv = (const short8v*)WvF;
  for (int ct = 0; ct < 49; ++ct) {
    f32x4 aM = {0.f, 0.f, 0.f, 0.f};
    f32x4 aV = {0.f, 0.f, 0.f, 0.f};
#pragma unroll
    for (int ks = 0; ks < 16; ++ks) {
      short8v bm = Wmv[(ct * 16 + ks) * 64 + l];
      short8v bv = Wvv[(ct * 16 + ks) * 64 + l];
      aM = __builtin_amdgcn_mfma_f32_16x16x32_bf16(ha[ks], bm, aM, 0, 0, 0);
      aV = __builtin_amdgcn_mfma_f32_16x16x32_bf16(ha[ks], bv, aV, 0, 0, 0);
    }
    int c = ct * 16 + lr;
    float bm_ = bmu[c], bv_ = bvv[c];
#pragma unroll
    for (int r = 0; r < 4; ++r) {
      size_t o = (size_t)(row0 + lg * 4 + r) * INDIM_ + c;
      outm[o] = aM[r] + bm_;
      outv[o] = sp32(aV[r] + bv_) + 1e-6f;
    }
  }
}

// ---------------- launch ----------------
extern "C" void kernel_launch(void* const* d_in, const int* in_sizes, int n_in,
                              void* d_out, int out_size, void* d_ws, size_t ws_size,
                              hipStream_t stream) {
  const float* y     = (const float*)d_in[0];
  const float* eW1   = (const float*)d_in[1];
  const float* eb1   = (const float*)d_in[2];
  const float* eWmu  = (const float*)d_in[3];
  const float* ebmu  = (const float*)d_in[4];
  const float* eWv   = (const float*)d_in[5];
  const float* ebv   = (const float*)d_in[6];
  const float* muk   = (const float*)d_in[7];
  const float* Lraw  = (const float*)d_in[8];
  const float* piraw = (const float*)d_in[9];
  const float* dW1   = (const float*)d_in[10];
  const float* db1   = (const float*)d_in[11];
  const float* dWmu  = (const float*)d_in[12];
  const float* dbmu  = (const float*)d_in[13];
  const float* dWv   = (const float*)d_in[14];
  const float* dbv   = (const float*)d_in[15];

  double* W      = (double*)d_ws;
  double* h      = W;             // 262144 doubles (reused as bf16 frag store by k_prep)
  double* mu     = W + 262144;    // 32768
  double* dvec   = W + 294912;    // 32768
  double* gk     = W + 327680;    // 640 (was J)
  double* iJ     = W + 368640;    // 40960
  double* logpi  = W + 409600;    // 16
  double* logpr  = W + 409616;    // 5120
  double* quadg  = W + 414736;    // 5120
  double* base2  = W + 419856;
  float*  xs     = (float*)base2;                 // 3,276,800 floats
  float*  J32    = xs + 3276800;                  // 40960 floats
  float*  LU32   = J32 + 40960;                   // 40960
  float*  d32    = LU32 + 40960;                  // 32768
  float*  muph   = d32 + 32768;                   // 32768
  int*    piv    = (int*)(muph + 32768);          // 640 ints

  ushort* hF   = (ushort*)h;
  ushort* W1F  = hF;
  ushort* WmuF = hF + 32768;
  ushort* WvF  = hF + 434176;

  float* outm = (float*)d_out;            // (N,K,S,784)
  float* outv = outm + 40140800;          // (N,K,S,784)
  float* outx = outm + 80281600;          // (N,64)
  float* outz = outm + 80314368;          // (N,10)

  k_enc_h    <<<N_, 256, 0, stream>>>(y, eW1, eb1, h);
  k_enc_muvar<<<N_, 128, 0, stream>>>(h, eWmu, ebmu, eWv, ebv, mu, dvec, d32, muph);
  k_prep     <<<408, 256, 0, stream>>>(dW1, dWmu, dWv, hF);
  k_gmm      <<<K_, 64, 0, stream>>>(Lraw, piraw, muk, iJ, gk, logpi);
  k_lu32     <<<K_, 64, 0, stream>>>(Lraw, J32, LU32, piv);
  k_quad32   <<<N_ * K_, 64, 0, stream>>>(J32, LU32, piv, d32, muph, quadg);
  k_pernk    <<<N_ * K_, 64, 0, stream>>>(dvec, mu, gk, iJ, logpi, quadg, logpr, xs);
  k_softcat  <<<N_, 64, 0, stream>>>(logpr, xs, outz, outx);
  k_dec      <<<800, 256, 0, stream>>>(xs, W1F, WmuF, WvF, db1, dbmu, dbv, outm, outv);
}

// Round 8
// 1451.240 us; speedup vs baseline: 3.6398x; 1.0476x over previous
//
#include <hip/hip_runtime.h>
#include <math.h>
#include <stdint.h>

#define N_ 512
#define D_ 64
#define K_ 10
#define S_ 10
#define INDIM_ 784
#define H_ 512
#define DP1 (D_ + 1)

typedef __attribute__((ext_vector_type(8))) short short8v;
typedef __attribute__((ext_vector_type(4))) float f32x4;

// ---------------- JAX Threefry-2x32 (20 rounds) ----------------
__device__ __forceinline__ uint32_t rotl32(uint32_t v, int r) { return (v << r) | (v >> (32 - r)); }

__device__ __forceinline__ void threefry2x32(uint32_t k0, uint32_t k1,
                                             uint32_t x0, uint32_t x1,
                                             uint32_t& o0, uint32_t& o1) {
  uint32_t k2 = k0 ^ k1 ^ 0x1BD11BDAu;
  x0 += k0; x1 += k1;
#define TFR(r) { x0 += x1; x1 = rotl32(x1, r); x1 ^= x0; }
  TFR(13) TFR(15) TFR(26) TFR(6)
  x0 += k1; x1 += k2 + 1u;
  TFR(17) TFR(29) TFR(16) TFR(24)
  x0 += k2; x1 += k0 + 2u;
  TFR(13) TFR(15) TFR(26) TFR(6)
  x0 += k0; x1 += k1 + 3u;
  TFR(17) TFR(29) TFR(16) TFR(24)
  x0 += k1; x1 += k2 + 4u;
  TFR(13) TFR(15) TFR(26) TFR(6)
  x0 += k2; x1 += k0 + 5u;
#undef TFR
  o0 = x0; o1 = x1;
}

__device__ __forceinline__ uint32_t jax_bits32(uint32_t k0, uint32_t k1, uint32_t idx) {
  uint32_t o0, o1; threefry2x32(k0, k1, 0u, idx, o0, o1);
  return o0 ^ o1;
}

__device__ __forceinline__ float bits_to_u01(uint32_t bits) {
  return __uint_as_float((bits >> 9) | 0x3F800000u) - 1.0f;
}

__device__ __forceinline__ float erfinv_f32(float x) {
  float w = -log1pf(-x * x);
  float p;
  if (w < 5.0f) {
    w = w - 2.5f;
    p = 2.81022636e-08f;
    p = fmaf(p, w, 3.43273939e-07f);
    p = fmaf(p, w, -3.5233877e-06f);
    p = fmaf(p, w, -4.39150654e-06f);
    p = fmaf(p, w, 0.00021858087f);
    p = fmaf(p, w, -0.00125372503f);
    p = fmaf(p, w, -0.00417768164f);
    p = fmaf(p, w, 0.246640727f);
    p = fmaf(p, w, 1.50140941f);
  } else {
    w = sqrtf(w) - 3.0f;
    p = -0.000200214257f;
    p = fmaf(p, w, 0.000100950558f);
    p = fmaf(p, w, 0.00134934322f);
    p = fmaf(p, w, -0.00367342844f);
    p = fmaf(p, w, 0.00573950773f);
    p = fmaf(p, w, -0.0076224613f);
    p = fmaf(p, w, 0.00943887047f);
    p = fmaf(p, w, 1.00167406f);
    p = fmaf(p, w, 2.83297682f);
  }
  return p * x;
}

__device__ __forceinline__ float jax_normal_f32(uint32_t k0, uint32_t k1, uint32_t idx) {
  uint32_t bits = jax_bits32(k0, k1, idx);
  float u = bits_to_u01(bits);
  const float lo = -0.99999994f;
  float v = u * (1.0f - lo) + lo;
  v = fmaxf(lo, v);
  return 1.41421356f * erfinv_f32(v);
}

__device__ __forceinline__ float jax_gumbel_f32(uint32_t k0, uint32_t k1, uint32_t idx) {
  uint32_t bits = jax_bits32(k0, k1, idx);
  float u = bits_to_u01(bits);
  const float tiny = 1.17549435e-38f;
  float v = u * (1.0f - tiny) + tiny;
  v = fmaxf(tiny, v);
  return -logf(-logf(v));
}

__device__ __forceinline__ float sp32(float x) { return fmaxf(x, 0.f) + log1pf(expf(-fabsf(x))); }
__device__ __forceinline__ float sp32cr(float x) {
  double xd = (double)x;
  return (float)(fmax(xd, 0.0) + log1p(exp(-fabs(xd))));
}
__device__ __forceinline__ double sp64(double x) { return fmax(x, 0.0) + log1p(exp(-fabs(x))); }

__device__ __forceinline__ ushort bf16rne(float f) {
  uint32_t u = __float_as_uint(f);
  uint32_t r = (u + 0x7FFFu + ((u >> 16) & 1u)) >> 16;
  return (ushort)r;
}
__device__ __forceinline__ float bf2f(ushort b) { return __uint_as_float(((uint32_t)b) << 16); }

// ---------------- encoder ----------------
__global__ __launch_bounds__(256) void k_enc_h(const float* __restrict__ y,
                                               const float* __restrict__ W1,
                                               const float* __restrict__ b1,
                                               double* __restrict__ h) {
  int n = blockIdx.x, t = threadIdx.x;
  const float* yr = y + n * INDIM_;
  double a0 = 0.0, a1 = 0.0;
  for (int d = 0; d < INDIM_; ++d) {
    double yv = (double)yr[d];
    a0 += yv * (double)W1[d * H_ + t];
    a1 += yv * (double)W1[d * H_ + t + 256];
  }
  h[n * H_ + t] = tanh(a0 + (double)b1[t]);
  h[n * H_ + t + 256] = tanh(a1 + (double)b1[t + 256]);
}

__global__ __launch_bounds__(128) void k_enc_muvar(const double* __restrict__ h,
                                                   const float* __restrict__ Wmu,
                                                   const float* __restrict__ bmu,
                                                   const float* __restrict__ Wv,
                                                   const float* __restrict__ bv,
                                                   double* __restrict__ mu,
                                                   double* __restrict__ dvec,
                                                   float* __restrict__ d32,
                                                   float* __restrict__ muph) {
  __shared__ float mu32s[D_], var32s[D_];
  int n = blockIdx.x, t = threadIdx.x;
  int c = t & 63;
  const float* Wsel = (t < 64) ? Wmu : Wv;
  const double* hr = h + n * H_;
  double acc = 0.0;
  for (int q = 0; q < H_; ++q) acc += hr[q] * (double)Wsel[q * D_ + c];
  if (t < 64) {
    double m = acc + (double)bmu[c];
    mu[n * D_ + c] = m;
    mu32s[c] = (float)m;
  } else {
    double a = acc + (double)bv[c];
    double var = sp64(a) + 1e-6;
    dvec[n * D_ + c] = -0.5 / var;
    float var32 = sp32cr((float)a) + 1e-6f;
    var32s[c] = var32;
    d32[n * D_ + c] = (-0.5f) / var32;
  }
  __syncthreads();
  if (t < 64) {
    float var32 = var32s[c];
    float dd = (-0.5f) / var32;
    float eta1 = mu32s[c] / var32;
    float neg2d = -2.0f * dd;
    muph[n * D_ + c] = eta1 / neg2d;
  }
}

// ---------------- weight re-layout to MFMA fragment order (bf16) ----------------
__global__ __launch_bounds__(256) void k_prep(const float* __restrict__ W1,
                                              const float* __restrict__ Wmu,
                                              const float* __restrict__ Wv,
                                              ushort* __restrict__ hF) {
  int t = blockIdx.x * 256 + threadIdx.x;
  int chunk = t >> 6, l = t & 63;
  if (chunk >= 1632) return;
  int lr = l & 15, lg = l >> 4;
  const float* src; int C, ct, ks; ushort* dst;
  if (chunk < 64)       { src = W1;  C = 512; ct = chunk >> 1;  ks = chunk & 1;
                          dst = hF + chunk * 512; }
  else if (chunk < 848) { int c2 = chunk - 64;  src = Wmu; C = 784; ct = c2 / 16; ks = c2 % 16;
                          dst = hF + 32768 + c2 * 512; }
  else                  { int c2 = chunk - 848; src = Wv;  C = 784; ct = c2 / 16; ks = c2 % 16;
                          dst = hF + 434176 + c2 * 512; }
  ushort vals[8];
#pragma unroll
  for (int e = 0; e < 8; ++e)
    vals[e] = bf16rne(src[(ks * 32 + lg * 8 + e) * C + ct * 16 + lr]);
  *(short8v*)(dst + l * 8) = *(short8v*)vals;
}

// ---------------- GMM unpack: invJ_k, g_k = B^{-1}mu_k, log pi ----------------
__global__ __launch_bounds__(64) void k_gmm(const float* __restrict__ Lraw,
                                            const float* __restrict__ piraw,
                                            const float* __restrict__ muk,
                                            double* __restrict__ iJout,
                                            double* __restrict__ gko,
                                            double* __restrict__ logpi) {
  __shared__ float Lk[D_][DP1];
  __shared__ double dg[D_];
  __shared__ double Li[D_][DP1];
  int k = blockIdx.x, i = threadIdx.x;
  const float* Lr = Lraw + k * D_ * D_;
  for (int j = 0; j < i; ++j) Lk[i][j] = Lr[i * D_ + j];
  dg[i] = sp64((double)Lr[i * D_ + i]);
  __syncthreads();
#define LKD(r, c) ((c) < (r) ? (double)Lk[r][c] : dg[r])
  {
    int j = i;
    Li[j][j] = 1.0 / dg[j];
    for (int r = j + 1; r < D_; ++r) {
      double s = 0.0;
      for (int m = j; m < r; ++m) s += LKD(r, m) * Li[m][j];
      Li[r][j] = -s / dg[r];
    }
  }
  __syncthreads();
  for (int j = 0; j < D_; ++j) {
    int m0 = max(i, j);
    double s = 0.0;
    for (int m = m0; m < D_; ++m) s += Li[m][i] * Li[m][j];
    iJout[k * D_ * D_ + i * D_ + j] = -2.0 * s;
  }
#undef LKD
  // g_k = 2 * Lk^{-T} (Lk^{-1} mu_k)   (B = 0.5 Lk Lk^T)
  {
    double rv = (double)muk[k * D_ + i];
    for (int j = 0; j < D_; ++j) {
      double xj = __shfl(rv, j, 64) / dg[j];
      if (i == j) rv = xj;
      else if (i > j) rv -= (double)Lk[i][j] * xj;
    }
    for (int j = D_ - 1; j >= 0; --j) {
      double xj = __shfl(rv, j, 64) / dg[j];
      if (i == j) rv = xj;
      else if (i < j) rv -= (double)Lk[j][i] * xj;
    }
    gko[k * D_ + i] = 2.0 * rv;
  }
  if (k == 0 && i == 0) {
    double m = (double)piraw[0];
    for (int q = 1; q < K_; ++q) m = fmax(m, (double)piraw[q]);
    double ss = 0.0;
    for (int q = 0; q < K_; ++q) ss += exp((double)piraw[q] - m);
    double lse = m + log(ss);
    for (int q = 0; q < K_; ++q) logpi[q] = (double)piraw[q] - lse;
  }
}

// ---------------- f32 LAPACK-emulation: J32 (f32 sgemm-fold) + sgetf2 LU (per k) ----------------
__global__ __launch_bounds__(64) void k_lu32(const float* __restrict__ Lraw,
                                             float* __restrict__ J32g,
                                             float* __restrict__ LU32g,
                                             int* __restrict__ pivg) {
  __shared__ float Lk[D_][DP1];
  __shared__ float A[D_][DP1];
  __shared__ float col[D_];
  __shared__ int piv_s[D_];
  int k = blockIdx.x, i = threadIdx.x;
  const float* Lr = Lraw + k * D_ * D_;
  for (int j = 0; j < D_; ++j)
    Lk[i][j] = (j < i) ? Lr[i * D_ + j] : ((j == i) ? sp32cr(Lr[i * D_ + i]) : 0.0f);
  __syncthreads();
  for (int j = 0; j < D_; ++j) {
    float s = 0.0f;
    for (int q = 0; q < D_; ++q) s = fmaf(Lk[i][q], Lk[j][q], s);
    float v = -0.5f * s;
    A[i][j] = v;
    J32g[k * D_ * D_ + i * D_ + j] = v;
  }
  __syncthreads();
  for (int j = 0; j < D_; ++j) {
    col[i] = fabsf(A[i][j]);
    __syncthreads();
    if (i == 0) {
      int p = j; float mx = col[j];
      for (int r = j + 1; r < D_; ++r) if (col[r] > mx) { mx = col[r]; p = r; }
      piv_s[j] = p;
    }
    __syncthreads();
    int p = piv_s[j];
    if (p != j) { float tmp = A[j][i]; A[j][i] = A[p][i]; A[p][i] = tmp; }
    __syncthreads();
    float rec = 1.0f / A[j][j];
    if (i > j) A[i][j] = A[i][j] * rec;
    __syncthreads();
    if (i > j) {
      float x = A[i][j];
      for (int l = j + 1; l < D_; ++l) A[i][l] = fmaf(x, -A[j][l], A[i][l]);
    }
    __syncthreads();
  }
  for (int j = 0; j < D_; ++j) LU32g[k * D_ * D_ + i * D_ + j] = A[i][j];
  pivg[k * D_ + i] = piv_s[i];
}

// ---------------- f32-emulated quad2 per (n,k) — register-column solves ----------------
__global__ __launch_bounds__(64) void k_quad32(const float* __restrict__ J32g,
                                               const float* __restrict__ LU32g,
                                               const int* __restrict__ pivg,
                                               const float* __restrict__ d32g,
                                               const float* __restrict__ muphg,
                                               double* __restrict__ quadg) {
  __shared__ float LUs[D_][DP1];
  __shared__ float dsh[D_], mph[D_];
  __shared__ int pshare[D_];
  __shared__ double red[D_];
  int nk = blockIdx.x;
  int n = nk / K_, k = nk - n * K_;
  int tj = threadIdx.x;
  for (int r = 0; r < D_; ++r) LUs[r][tj] = LU32g[k * 4096 + r * 64 + tj];
  dsh[tj] = d32g[n * 64 + tj];
  mph[tj] = muphg[n * 64 + tj];
  int pv = pivg[k * 64 + tj];
  int perm = tj;
  for (int j = 0; j < 64; ++j) {
    int pj = __shfl(pv, j, 64);
    int vj = __shfl(perm, j, 64);
    int vp = __shfl(perm, pj, 64);
    if (tj == j) perm = vp;
    else if (tj == pj) perm = vj;
  }
  pshare[tj] = perm;
  __syncthreads();
  float Tc[64];
#pragma unroll
  for (int i2 = 0; i2 < 64; ++i2) {
    int pr = pshare[i2];
    float v = J32g[k * 4096 + pr * 64 + tj];
    if (pr == tj) v = v + dsh[tj];
    Tc[i2] = v;
  }
#pragma unroll
  for (int r = 0; r < 64; ++r) {
    float x = Tc[r];
#pragma unroll
    for (int i2 = r + 1; i2 < 64; ++i2)
      Tc[i2] = fmaf(LUs[i2][r], -x, Tc[i2]);
  }
#pragma unroll
  for (int r = 63; r >= 0; --r) {
    float x = Tc[r] / LUs[r][r];
    Tc[r] = x;
#pragma unroll
    for (int i2 = 0; i2 < r; ++i2)
      Tc[i2] = fmaf(LUs[i2][r], -x, Tc[i2]);
  }
  __syncthreads();
#pragma unroll
  for (int i2 = 0; i2 < 64; ++i2) LUs[i2][tj] = Tc[i2];
  __syncthreads();
  double part = 0.0;
#pragma unroll
  for (int d2 = 0; d2 < 64; ++d2) {
    float a = dsh[d2] * Tc[d2];
    float b = dsh[tj] * LUs[tj][d2];
    float w = 0.5f * (a + b);
    float t1 = mph[d2] * w;
    float t2 = t1 * mph[tj];
    part += (double)t2;
  }
  red[tj] = part; __syncthreads();
  for (int off = 32; off > 0; off >>= 1) {
    if (tj < off) red[tj] += red[tj + off];
    __syncthreads();
  }
  if (tj == 0) quadg[nk] = red[0];
}

// ---------------- per-(n,k): left-looking LDS Cholesky, low-VGPR ----------------
__global__ __launch_bounds__(64) void k_pernk(const double* __restrict__ dvec,
                                              const double* __restrict__ mu,
                                              const double* __restrict__ gk,
                                              const double* __restrict__ iJg,
                                              const double* __restrict__ logpi,
                                              const double* __restrict__ quadg,
                                              double* __restrict__ logprob,
                                              float* __restrict__ xs) {
  __shared__ double Sp[2080];      // packed lower L, row r at r(r+1)/2
  int nk = blockIdx.x;
  int n = nk / K_, k = nk - n * K_;
  int i = threadIdx.x;
  int Ti = (i * (i + 1)) >> 1;

  double dn = dvec[n * 64 + i];
  double mn = mu[n * 64 + i];
  const double* iJ = iJg + k * 4096;

  // ---- left-looking Cholesky of P = -(Dg iJ Dg) - Dg, column by column
  double linv = 0.0, ljj = 1.0;
  for (int j = 0; j < 64; ++j) {
    double dj = __shfl(dn, j, 64);
    double v = -(dn * iJ[j * 64 + i] * dj);   // P[i][j] (iJ symmetric, coalesced)
    if (i == j) v -= dn;
    int Tj = (j * (j + 1)) >> 1;
    double acc = 0.0;
    for (int q = 0; q < j; ++q)
      acc = fma(Sp[Ti + q], Sp[Tj + q], acc); // own-row x broadcast row-j
    v -= acc;
    double sj = __shfl(v, j, 64);             // d_jj
    double s_ = sqrt(sj);
    double li = v / s_;                       // lane j: = s_ ; lanes i>j: L[i][j]
    if (i >= j) Sp[Ti + j] = li;
    if (i == j) { linv = 1.0 / s_; ljj = s_; }
    __syncthreads();
  }

  // ---- two-RHS solve: z = P^{-1}(E g_k)  and  u = P^{-1} d  (t = s_nk*u)
  double rv = (-dn) * gk[k * 64 + i];
  double uv = dn;
  for (int j = 0; j < 64; ++j) {
    double xz = __shfl(rv * linv, j, 64);
    double xu = __shfl(uv * linv, j, 64);
    double lij = (i > j) ? Sp[Ti + j] : 0.0;
    if (i == j) { rv = xz; uv = xu; }
    else { rv = fma(-lij, xz, rv); uv = fma(-lij, xu, uv); }
  }
  for (int j = 63; j >= 0; --j) {
    double xz = __shfl(rv * linv, j, 64);
    double xu = __shfl(uv * linv, j, 64);
    double lij = (i < j) ? Sp[((j * (j + 1)) >> 1) + i] : 0.0;
    if (i == j) { rv = xz; uv = xu; }
    else { rv = fma(-lij, xz, rv); uv = fma(-lij, xu, uv); }
  }
  double zsum = rv;
  for (int o = 32; o > 0; o >>= 1) zsum += __shfl_xor(zsum, o, 64);
  double s_nk = -zsum;
  double w1 = s_nk * dn;
  double tv = s_nk * uv;
  double dmw = mn * w1;
  for (int o = 32; o > 0; o >>= 1) dmw += __shfl_xor(dmw, o, 64);
  double dwt = w1 * tv;
  for (int o = 32; o > 0; o >>= 1) dwt += __shfl_xor(dwt, o, 64);
  double sl = log(ljj);
  for (int o = 32; o > 0; o >>= 1) sl += __shfl_xor(sl, o, 64);
  if (i == 0) {
    logprob[nk] = dmw + quadg[nk] - 0.25 * dwt
                + 32.0 * 0.6931471805599453 + sl
                - 32.0 * 1.8378770664093453
                + logpi[k];
  }

  // ---- samples: L^T e = eps (10 RHS), x = 0.5 t + eps/sqrt(2)
  double rr[S_];
  {
    uint32_t base = (uint32_t)((nk * 64 + i) * S_);
#pragma unroll
    for (int s = 0; s < S_; ++s)
      rr[s] = (double)jax_normal_f32(0u, 42u, base + s);
  }
  for (int q = 63; q >= 0; --q) {
    double lq = (i < q) ? Sp[((q * (q + 1)) >> 1) + i] : 0.0;
#pragma unroll
    for (int s = 0; s < S_; ++s) {
      double rq = __shfl(rr[s] * linv, q, 64);
      if (i == q) rr[s] = rq;
      else rr[s] = fma(-lq, rq, rr[s]);
    }
  }
  double xm = 0.5 * tv;
#pragma unroll
  for (int s = 0; s < S_; ++s)
    xs[(nk * S_ + s) * 64 + i] = (float)(xm + 0.7071067811865476 * rr[s]);
}

// ---------------- softmax over K + categorical (s=0) + x_subsamples ----------------
__global__ __launch_bounds__(64) void k_softcat(const double* __restrict__ logprob,
                                                const float* __restrict__ xs,
                                                float* __restrict__ outz,
                                                float* __restrict__ outx) {
  __shared__ double lz[K_];
  __shared__ int zc;
  int n = blockIdx.x, t = threadIdx.x;
  if (t == 0) {
    double lp[K_];
    double m = -1e300;
    for (int q = 0; q < K_; ++q) { lp[q] = logprob[n * K_ + q]; m = fmax(m, lp[q]); }
    double ss = 0.0;
    for (int q = 0; q < K_; ++q) ss += exp(lp[q] - m);
    double lsum = log(ss);
    float best = -INFINITY; int bi = 0;
    for (int q = 0; q < K_; ++q) {
      double l = (lp[q] - m) - lsum;
      lz[q] = l;
      float g = jax_gumbel_f32(0u, 7u, (uint32_t)(n * 100 + q));
      float sc = g + (float)l;
      if (sc > best) { best = sc; bi = q; }
    }
    zc = bi;
  }
  __syncthreads();
  if (t < K_) outz[n * K_ + t] = (float)lz[t];
  outx[n * D_ + t] = xs[(n * K_ + zc) * S_ * D_ + t];
}

// ---------------- decoder: MFMA bf16, 64 rows/block, 4 waves ----------------
__global__ __launch_bounds__(256) void k_dec(const float* __restrict__ xs,
                                             const ushort* __restrict__ W1F,
                                             const ushort* __restrict__ WmuF,
                                             const ushort* __restrict__ WvF,
                                             const float* __restrict__ b1,
                                             const float* __restrict__ bmu,
                                             const float* __restrict__ bvv,
                                             float* __restrict__ outm,
                                             float* __restrict__ outv) {
  __shared__ __align__(16) ushort hd[4][16][520];
  int t = threadIdx.x;
  int w = t >> 6, l = t & 63;
  int lr = l & 15, lg = l >> 4;
  int row0 = blockIdx.x * 64 + w * 16;

  short8v xhi[2], xlo[2];
  {
    const float* xrow = xs + (size_t)(row0 + lr) * 64 + lg * 8;
#pragma unroll
    for (int ks = 0; ks < 2; ++ks) {
      ushort hi[8], lo[8];
#pragma unroll
      for (int e = 0; e < 8; ++e) {
        float xv = xrow[ks * 32 + e];
        ushort h16 = bf16rne(xv);
        hi[e] = h16;
        lo[e] = bf16rne(xv - bf2f(h16));
      }
      xhi[ks] = *(short8v*)hi;
      xlo[ks] = *(short8v*)lo;
    }
  }

  const short8v* W1v = (const short8v*)W1F;
#pragma unroll 4
  for (int ct = 0; ct < 32; ++ct) {
    f32x4 acc = {0.f, 0.f, 0.f, 0.f};
    short8v b0 = W1v[(ct * 2 + 0) * 64 + l];
    short8v b1v = W1v[(ct * 2 + 1) * 64 + l];
    acc = __builtin_amdgcn_mfma_f32_16x16x32_bf16(xhi[0], b0, acc, 0, 0, 0);
    acc = __builtin_amdgcn_mfma_f32_16x16x32_bf16(xlo[0], b0, acc, 0, 0, 0);
    acc = __builtin_amdgcn_mfma_f32_16x16x32_bf16(xhi[1], b1v, acc, 0, 0, 0);
    acc = __builtin_amdgcn_mfma_f32_16x16x32_bf16(xlo[1], b1v, acc, 0, 0, 0);
    int c = ct * 16 + lr;
    float bb = b1[c];
#pragma unroll
    for (int r = 0; r < 4; ++r)
      hd[w][lg * 4 + r][c] = bf16rne(tanhf(acc[r] + bb));
  }
  __syncthreads();

  short8v ha[16];
#pragma unroll
  for (int ks = 0; ks < 16; ++ks)
    ha[ks] = *(const short8v*)&hd[w][lr][ks * 32 + lg * 8];

  const short8v* Wmv = (const short8v*)WmuF;
  const short8v* Wvv = (const short8v*)WvF;
  for (int ct = 0; ct < 49; ++ct) {
    f32x4 aM = {0.f, 0.f, 0.f, 0.f};
    f32x4 aV = {0.f, 0.f, 0.f, 0.f};
#pragma unroll
    for (int ks = 0; ks < 16; ++ks) {
      short8v bm = Wmv[(ct * 16 + ks) * 64 + l];
      short8v bv = Wvv[(ct * 16 + ks) * 64 + l];
      aM = __builtin_amdgcn_mfma_f32_16x16x32_bf16(ha[ks], bm, aM, 0, 0, 0);
      aV = __builtin_amdgcn_mfma_f32_16x16x32_bf16(ha[ks], bv, aV, 0, 0, 0);
    }
    int c = ct * 16 + lr;
    float bm_ = bmu[c], bv_ = bvv[c];
#pragma unroll
    for (int r = 0; r < 4; ++r) {
      size_t o = (size_t)(row0 + lg * 4 + r) * INDIM_ + c;
      outm[o] = aM[r] + bm_;
      outv[o] = sp32(aV[r] + bv_) + 1e-6f;
    }
  }
}

// ---------------- launch ----------------
extern "C" void kernel_launch(void* const* d_in, const int* in_sizes, int n_in,
                              void* d_out, int out_size, void* d_ws, size_t ws_size,
                              hipStream_t stream) {
  const float* y     = (const float*)d_in[0];
  const float* eW1   = (const float*)d_in[1];
  const float* eb1   = (const float*)d_in[2];
  const float* eWmu  = (const float*)d_in[3];
  const float* ebmu  = (const float*)d_in[4];
  const float* eWv   = (const float*)d_in[5];
  const float* ebv   = (const float*)d_in[6];
  const float* muk   = (const float*)d_in[7];
  const float* Lraw  = (const float*)d_in[8];
  const float* piraw = (const float*)d_in[9];
  const float* dW1   = (const float*)d_in[10];
  const float* db1   = (const float*)d_in[11];
  const float* dWmu  = (const float*)d_in[12];
  const float* dbmu  = (const float*)d_in[13];
  const float* dWv   = (const float*)d_in[14];
  const float* dbv   = (const float*)d_in[15];

  double* W      = (double*)d_ws;
  double* h      = W;             // 262144 doubles (reused as bf16 frag store by k_prep)
  double* mu     = W + 262144;    // 32768
  double* dvec   = W + 294912;    // 32768
  double* gk     = W + 327680;    // 640
  double* iJ     = W + 368640;    // 40960
  double* logpi  = W + 409600;    // 16
  double* logpr  = W + 409616;    // 5120
  double* quadg  = W + 414736;    // 5120
  double* base2  = W + 419856;
  float*  xs     = (float*)base2;                 // 3,276,800 floats
  float*  J32    = xs + 3276800;                  // 40960 floats
  float*  LU32   = J32 + 40960;                   // 40960
  float*  d32    = LU32 + 40960;                  // 32768
  float*  muph   = d32 + 32768;                   // 32768
  int*    piv    = (int*)(muph + 32768);          // 640 ints

  ushort* hF   = (ushort*)h;
  ushort* W1F  = hF;
  ushort* WmuF = hF + 32768;
  ushort* WvF  = hF + 434176;

  float* outm = (float*)d_out;            // (N,K,S,784)
  float* outv = outm + 40140800;          // (N,K,S,784)
  float* outx = outm + 80281600;          // (N,64)
  float* outz = outm + 80314368;          // (N,10)

  k_enc_h    <<<N_, 256, 0, stream>>>(y, eW1, eb1, h);
  k_enc_muvar<<<N_, 128, 0, stream>>>(h, eWmu, ebmu, eWv, ebv, mu, dvec, d32, muph);
  k_prep     <<<408, 256, 0, stream>>>(dW1, dWmu, dWv, hF);
  k_gmm      <<<K_, 64, 0, stream>>>(Lraw, piraw, muk, iJ, gk, logpi);
  k_lu32     <<<K_, 64, 0, stream>>>(Lraw, J32, LU32, piv);
  k_quad32   <<<N_ * K_, 64, 0, stream>>>(J32, LU32, piv, d32, muph, quadg);
  k_pernk    <<<N_ * K_, 64, 0, stream>>>(dvec, mu, gk, iJ, logpi, quadg, logpr, xs);
  k_softcat  <<<N_, 64, 0, stream>>>(logpr, xs, outz, outx);
  k_dec      <<<800, 256, 0, stream>>>(xs, W1F, WmuF, WvF, db1, dbmu, dbv, outm, outv);
}

// Round 9
// 1320.346 us; speedup vs baseline: 4.0007x; 1.0991x over previous
//
#include <hip/hip_runtime.h>
#include <math.h>
#include <stdint.h>

#define N_ 512
#define D_ 64
#define K_ 10
#define S_ 10
#define INDIM_ 784
#define H_ 512
#define DP1 (D_ + 1)

typedef __attribute__((ext_vector_type(8))) short short8v;
typedef __attribute__((ext_vector_type(4))) float f32x4;

// ---------------- JAX Threefry-2x32 (20 rounds) ----------------
__device__ __forceinline__ uint32_t rotl32(uint32_t v, int r) { return (v << r) | (v >> (32 - r)); }

__device__ __forceinline__ void threefry2x32(uint32_t k0, uint32_t k1,
                                             uint32_t x0, uint32_t x1,
                                             uint32_t& o0, uint32_t& o1) {
  uint32_t k2 = k0 ^ k1 ^ 0x1BD11BDAu;
  x0 += k0; x1 += k1;
#define TFR(r) { x0 += x1; x1 = rotl32(x1, r); x1 ^= x0; }
  TFR(13) TFR(15) TFR(26) TFR(6)
  x0 += k1; x1 += k2 + 1u;
  TFR(17) TFR(29) TFR(16) TFR(24)
  x0 += k2; x1 += k0 + 2u;
  TFR(13) TFR(15) TFR(26) TFR(6)
  x0 += k0; x1 += k1 + 3u;
  TFR(17) TFR(29) TFR(16) TFR(24)
  x0 += k1; x1 += k2 + 4u;
  TFR(13) TFR(15) TFR(26) TFR(6)
  x0 += k2; x1 += k0 + 5u;
#undef TFR
  o0 = x0; o1 = x1;
}

__device__ __forceinline__ uint32_t jax_bits32(uint32_t k0, uint32_t k1, uint32_t idx) {
  uint32_t o0, o1; threefry2x32(k0, k1, 0u, idx, o0, o1);
  return o0 ^ o1;
}

__device__ __forceinline__ float bits_to_u01(uint32_t bits) {
  return __uint_as_float((bits >> 9) | 0x3F800000u) - 1.0f;
}

__device__ __forceinline__ float erfinv_f32(float x) {
  float w = -log1pf(-x * x);
  float p;
  if (w < 5.0f) {
    w = w - 2.5f;
    p = 2.81022636e-08f;
    p = fmaf(p, w, 3.43273939e-07f);
    p = fmaf(p, w, -3.5233877e-06f);
    p = fmaf(p, w, -4.39150654e-06f);
    p = fmaf(p, w, 0.00021858087f);
    p = fmaf(p, w, -0.00125372503f);
    p = fmaf(p, w, -0.00417768164f);
    p = fmaf(p, w, 0.246640727f);
    p = fmaf(p, w, 1.50140941f);
  } else {
    w = sqrtf(w) - 3.0f;
    p = -0.000200214257f;
    p = fmaf(p, w, 0.000100950558f);
    p = fmaf(p, w, 0.00134934322f);
    p = fmaf(p, w, -0.00367342844f);
    p = fmaf(p, w, 0.00573950773f);
    p = fmaf(p, w, -0.0076224613f);
    p = fmaf(p, w, 0.00943887047f);
    p = fmaf(p, w, 1.00167406f);
    p = fmaf(p, w, 2.83297682f);
  }
  return p * x;
}

__device__ __forceinline__ float jax_normal_f32(uint32_t k0, uint32_t k1, uint32_t idx) {
  uint32_t bits = jax_bits32(k0, k1, idx);
  float u = bits_to_u01(bits);
  const float lo = -0.99999994f;
  float v = u * (1.0f - lo) + lo;
  v = fmaxf(lo, v);
  return 1.41421356f * erfinv_f32(v);
}

__device__ __forceinline__ float jax_gumbel_f32(uint32_t k0, uint32_t k1, uint32_t idx) {
  uint32_t bits = jax_bits32(k0, k1, idx);
  float u = bits_to_u01(bits);
  const float tiny = 1.17549435e-38f;
  float v = u * (1.0f - tiny) + tiny;
  v = fmaxf(tiny, v);
  return -logf(-logf(v));
}

__device__ __forceinline__ float sp32(float x) { return fmaxf(x, 0.f) + log1pf(expf(-fabsf(x))); }
__device__ __forceinline__ float sp32cr(float x) {
  double xd = (double)x;
  return (float)(fmax(xd, 0.0) + log1p(exp(-fabs(xd))));
}
__device__ __forceinline__ double sp64(double x) { return fmax(x, 0.0) + log1p(exp(-fabs(x))); }

__device__ __forceinline__ ushort bf16rne(float f) {
  uint32_t u = __float_as_uint(f);
  uint32_t r = (u + 0x7FFFu + ((u >> 16) & 1u)) >> 16;
  return (ushort)r;
}
__device__ __forceinline__ float bf2f(ushort b) { return __uint_as_float(((uint32_t)b) << 16); }

// ---------------- encoder ----------------
__global__ __launch_bounds__(256) void k_enc_h(const float* __restrict__ y,
                                               const float* __restrict__ W1,
                                               const float* __restrict__ b1,
                                               double* __restrict__ h) {
  int n = blockIdx.x, t = threadIdx.x;
  const float* yr = y + n * INDIM_;
  double a0 = 0.0, a1 = 0.0;
  for (int d = 0; d < INDIM_; ++d) {
    double yv = (double)yr[d];
    a0 += yv * (double)W1[d * H_ + t];
    a1 += yv * (double)W1[d * H_ + t + 256];
  }
  h[n * H_ + t] = tanh(a0 + (double)b1[t]);
  h[n * H_ + t + 256] = tanh(a1 + (double)b1[t + 256]);
}

__global__ __launch_bounds__(128) void k_enc_muvar(const double* __restrict__ h,
                                                   const float* __restrict__ Wmu,
                                                   const float* __restrict__ bmu,
                                                   const float* __restrict__ Wv,
                                                   const float* __restrict__ bv,
                                                   double* __restrict__ mu,
                                                   double* __restrict__ dvec,
                                                   float* __restrict__ d32,
                                                   float* __restrict__ muph) {
  __shared__ float mu32s[D_], var32s[D_];
  int n = blockIdx.x, t = threadIdx.x;
  int c = t & 63;
  const float* Wsel = (t < 64) ? Wmu : Wv;
  const double* hr = h + n * H_;
  double acc = 0.0;
  for (int q = 0; q < H_; ++q) acc += hr[q] * (double)Wsel[q * D_ + c];
  if (t < 64) {
    double m = acc + (double)bmu[c];
    mu[n * D_ + c] = m;
    mu32s[c] = (float)m;
  } else {
    double a = acc + (double)bv[c];
    double var = sp64(a) + 1e-6;
    dvec[n * D_ + c] = -0.5 / var;
    float var32 = sp32cr((float)a) + 1e-6f;
    var32s[c] = var32;
    d32[n * D_ + c] = (-0.5f) / var32;
  }
  __syncthreads();
  if (t < 64) {
    float var32 = var32s[c];
    float dd = (-0.5f) / var32;
    float eta1 = mu32s[c] / var32;
    float neg2d = -2.0f * dd;
    muph[n * D_ + c] = eta1 / neg2d;
  }
}

// ---------------- weight re-layout to MFMA fragment order (bf16) ----------------
__global__ __launch_bounds__(256) void k_prep(const float* __restrict__ W1,
                                              const float* __restrict__ Wmu,
                                              const float* __restrict__ Wv,
                                              ushort* __restrict__ hF) {
  int t = blockIdx.x * 256 + threadIdx.x;
  int chunk = t >> 6, l = t & 63;
  if (chunk >= 1632) return;
  int lr = l & 15, lg = l >> 4;
  const float* src; int C, ct, ks; ushort* dst;
  if (chunk < 64)       { src = W1;  C = 512; ct = chunk >> 1;  ks = chunk & 1;
                          dst = hF + chunk * 512; }
  else if (chunk < 848) { int c2 = chunk - 64;  src = Wmu; C = 784; ct = c2 / 16; ks = c2 % 16;
                          dst = hF + 32768 + c2 * 512; }
  else                  { int c2 = chunk - 848; src = Wv;  C = 784; ct = c2 / 16; ks = c2 % 16;
                          dst = hF + 434176 + c2 * 512; }
  ushort vals[8];
#pragma unroll
  for (int e = 0; e < 8; ++e)
    vals[e] = bf16rne(src[(ks * 32 + lg * 8 + e) * C + ct * 16 + lr]);
  *(short8v*)(dst + l * 8) = *(short8v*)vals;
}

// ---------------- GMM unpack: invJ_k, g_k = B^{-1}mu_k, log pi ----------------
__global__ __launch_bounds__(64) void k_gmm(const float* __restrict__ Lraw,
                                            const float* __restrict__ piraw,
                                            const float* __restrict__ muk,
                                            double* __restrict__ iJout,
                                            double* __restrict__ gko,
                                            double* __restrict__ logpi) {
  __shared__ float Lk[D_][DP1];
  __shared__ double dg[D_];
  __shared__ double Li[D_][DP1];
  int k = blockIdx.x, i = threadIdx.x;
  const float* Lr = Lraw + k * D_ * D_;
  for (int j = 0; j < i; ++j) Lk[i][j] = Lr[i * D_ + j];
  dg[i] = sp64((double)Lr[i * D_ + i]);
  __syncthreads();
#define LKD(r, c) ((c) < (r) ? (double)Lk[r][c] : dg[r])
  {
    int j = i;
    Li[j][j] = 1.0 / dg[j];
    for (int r = j + 1; r < D_; ++r) {
      double s = 0.0;
      for (int m = j; m < r; ++m) s += LKD(r, m) * Li[m][j];
      Li[r][j] = -s / dg[r];
    }
  }
  __syncthreads();
  for (int j = 0; j < D_; ++j) {
    int m0 = max(i, j);
    double s = 0.0;
    for (int m = m0; m < D_; ++m) s += Li[m][i] * Li[m][j];
    iJout[k * D_ * D_ + i * D_ + j] = -2.0 * s;
  }
#undef LKD
  // g_k = 2 * Lk^{-T} (Lk^{-1} mu_k)   (B = 0.5 Lk Lk^T)
  {
    double rv = (double)muk[k * D_ + i];
    for (int j = 0; j < D_; ++j) {
      double xj = __shfl(rv, j, 64) / dg[j];
      if (i == j) rv = xj;
      else if (i > j) rv -= (double)Lk[i][j] * xj;
    }
    for (int j = D_ - 1; j >= 0; --j) {
      double xj = __shfl(rv, j, 64) / dg[j];
      if (i == j) rv = xj;
      else if (i < j) rv -= (double)Lk[j][i] * xj;
    }
    gko[k * D_ + i] = 2.0 * rv;
  }
  if (k == 0 && i == 0) {
    double m = (double)piraw[0];
    for (int q = 1; q < K_; ++q) m = fmax(m, (double)piraw[q]);
    double ss = 0.0;
    for (int q = 0; q < K_; ++q) ss += exp((double)piraw[q] - m);
    double lse = m + log(ss);
    for (int q = 0; q < K_; ++q) logpi[q] = (double)piraw[q] - lse;
  }
}

// ---------------- f32 LAPACK-emulation: J32 (f32 sgemm-fold) + sgetf2 LU (per k) ----------------
__global__ __launch_bounds__(64) void k_lu32(const float* __restrict__ Lraw,
                                             float* __restrict__ J32g,
                                             float* __restrict__ LU32g,
                                             int* __restrict__ pivg) {
  __shared__ float Lk[D_][DP1];
  __shared__ float A[D_][DP1];
  __shared__ float col[D_];
  __shared__ int piv_s[D_];
  int k = blockIdx.x, i = threadIdx.x;
  const float* Lr = Lraw + k * D_ * D_;
  for (int j = 0; j < D_; ++j)
    Lk[i][j] = (j < i) ? Lr[i * D_ + j] : ((j == i) ? sp32cr(Lr[i * D_ + i]) : 0.0f);
  __syncthreads();
  for (int j = 0; j < D_; ++j) {
    float s = 0.0f;
    for (int q = 0; q < D_; ++q) s = fmaf(Lk[i][q], Lk[j][q], s);
    float v = -0.5f * s;
    A[i][j] = v;
    J32g[k * D_ * D_ + i * D_ + j] = v;
  }
  __syncthreads();
  for (int j = 0; j < D_; ++j) {
    col[i] = fabsf(A[i][j]);
    __syncthreads();
    if (i == 0) {
      int p = j; float mx = col[j];
      for (int r = j + 1; r < D_; ++r) if (col[r] > mx) { mx = col[r]; p = r; }
      piv_s[j] = p;
    }
    __syncthreads();
    int p = piv_s[j];
    if (p != j) { float tmp = A[j][i]; A[j][i] = A[p][i]; A[p][i] = tmp; }
    __syncthreads();
    float rec = 1.0f / A[j][j];
    if (i > j) A[i][j] = A[i][j] * rec;
    __syncthreads();
    if (i > j) {
      float x = A[i][j];
      for (int l = j + 1; l < D_; ++l) A[i][l] = fmaf(x, -A[j][l], A[i][l]);
    }
    __syncthreads();
  }
  for (int j = 0; j < D_; ++j) LU32g[k * D_ * D_ + i * D_ + j] = A[i][j];
  pivg[k * D_ + i] = piv_s[i];
}

// ---------------- f32-emulated quad2 per (n,k) — register-column solves ----------------
__global__ __launch_bounds__(64) void k_quad32(const float* __restrict__ J32g,
                                               const float* __restrict__ LU32g,
                                               const int* __restrict__ pivg,
                                               const float* __restrict__ d32g,
                                               const float* __restrict__ muphg,
                                               double* __restrict__ quadg) {
  __shared__ float LUs[D_][DP1];
  __shared__ float dsh[D_], mph[D_];
  __shared__ int pshare[D_];
  __shared__ double red[D_];
  int nk = blockIdx.x;
  int n = nk / K_, k = nk - n * K_;
  int tj = threadIdx.x;
  for (int r = 0; r < D_; ++r) LUs[r][tj] = LU32g[k * 4096 + r * 64 + tj];
  dsh[tj] = d32g[n * 64 + tj];
  mph[tj] = muphg[n * 64 + tj];
  int pv = pivg[k * 64 + tj];
  int perm = tj;
  for (int j = 0; j < 64; ++j) {
    int pj = __shfl(pv, j, 64);
    int vj = __shfl(perm, j, 64);
    int vp = __shfl(perm, pj, 64);
    if (tj == j) perm = vp;
    else if (tj == pj) perm = vj;
  }
  pshare[tj] = perm;
  __syncthreads();
  float Tc[64];
#pragma unroll
  for (int i2 = 0; i2 < 64; ++i2) {
    int pr = pshare[i2];
    float v = J32g[k * 4096 + pr * 64 + tj];
    if (pr == tj) v = v + dsh[tj];
    Tc[i2] = v;
  }
#pragma unroll
  for (int r = 0; r < 64; ++r) {
    float x = Tc[r];
#pragma unroll
    for (int i2 = r + 1; i2 < 64; ++i2)
      Tc[i2] = fmaf(LUs[i2][r], -x, Tc[i2]);
  }
#pragma unroll
  for (int r = 63; r >= 0; --r) {
    float x = Tc[r] / LUs[r][r];
    Tc[r] = x;
#pragma unroll
    for (int i2 = 0; i2 < r; ++i2)
      Tc[i2] = fmaf(LUs[i2][r], -x, Tc[i2]);
  }
  __syncthreads();
#pragma unroll
  for (int i2 = 0; i2 < 64; ++i2) LUs[i2][tj] = Tc[i2];
  __syncthreads();
  double part = 0.0;
#pragma unroll
  for (int d2 = 0; d2 < 64; ++d2) {
    float a = dsh[d2] * Tc[d2];
    float b = dsh[tj] * LUs[tj][d2];
    float w = 0.5f * (a + b);
    float t1 = mph[d2] * w;
    float t2 = t1 * mph[tj];
    part += (double)t2;
  }
  red[tj] = part; __syncthreads();
  for (int off = 32; off > 0; off >>= 1) {
    if (tj < off) red[tj] += red[tj + off];
    __syncthreads();
  }
  if (tj == 0) quadg[nk] = red[0];
}

// ---------------- per-(n,k): left-looking LDS Cholesky, low-VGPR ----------------
__global__ __launch_bounds__(64) void k_pernk(const double* __restrict__ dvec,
                                              const double* __restrict__ mu,
                                              const double* __restrict__ gk,
                                              const double* __restrict__ iJg,
                                              const double* __restrict__ logpi,
                                              const double* __restrict__ quadg,
                                              double* __restrict__ logprob,
                                              float* __restrict__ xs) {
  __shared__ double Sp[2080];      // packed lower L, row r at r(r+1)/2
  int nk = blockIdx.x;
  int n = nk / K_, k = nk - n * K_;
  int i = threadIdx.x;
  int Ti = (i * (i + 1)) >> 1;

  double dn = dvec[n * 64 + i];
  double mn = mu[n * 64 + i];
  const double* iJ = iJg + k * 4096;

  // ---- left-looking Cholesky of P = -(Dg iJ Dg) - Dg, column by column
  double linv = 0.0, ljj = 1.0;
  for (int j = 0; j < 64; ++j) {
    double dj = __shfl(dn, j, 64);
    double v = -(dn * iJ[j * 64 + i] * dj);   // P[i][j] (iJ symmetric, coalesced)
    if (i == j) v -= dn;
    int Tj = (j * (j + 1)) >> 1;
    double acc = 0.0;
    for (int q = 0; q < j; ++q)
      acc = fma(Sp[Ti + q], Sp[Tj + q], acc); // own-row x broadcast row-j
    v -= acc;
    double sj = __shfl(v, j, 64);             // d_jj
    double s_ = sqrt(sj);
    double li = v / s_;                       // lane j: = s_ ; lanes i>j: L[i][j]
    if (i >= j) Sp[Ti + j] = li;
    if (i == j) { linv = 1.0 / s_; ljj = s_; }
    __syncthreads();
  }

  // ---- two-RHS solve: z = P^{-1}(E g_k)  and  u = P^{-1} d  (t = s_nk*u)
  double rv = (-dn) * gk[k * 64 + i];
  double uv = dn;
  for (int j = 0; j < 64; ++j) {
    double xz = __shfl(rv * linv, j, 64);
    double xu = __shfl(uv * linv, j, 64);
    double lij = (i > j) ? Sp[Ti + j] : 0.0;
    if (i == j) { rv = xz; uv = xu; }
    else { rv = fma(-lij, xz, rv); uv = fma(-lij, xu, uv); }
  }
  for (int j = 63; j >= 0; --j) {
    double xz = __shfl(rv * linv, j, 64);
    double xu = __shfl(uv * linv, j, 64);
    double lij = (i < j) ? Sp[((j * (j + 1)) >> 1) + i] : 0.0;
    if (i == j) { rv = xz; uv = xu; }
    else { rv = fma(-lij, xz, rv); uv = fma(-lij, xu, uv); }
  }
  double zsum = rv;
  for (int o = 32; o > 0; o >>= 1) zsum += __shfl_xor(zsum, o, 64);
  double s_nk = -zsum;
  double w1 = s_nk * dn;
  double tv = s_nk * uv;
  double dmw = mn * w1;
  for (int o = 32; o > 0; o >>= 1) dmw += __shfl_xor(dmw, o, 64);
  double dwt = w1 * tv;
  for (int o = 32; o > 0; o >>= 1) dwt += __shfl_xor(dwt, o, 64);
  double sl = log(ljj);
  for (int o = 32; o > 0; o >>= 1) sl += __shfl_xor(sl, o, 64);
  if (i == 0) {
    logprob[nk] = dmw + quadg[nk] - 0.25 * dwt
                + 32.0 * 0.6931471805599453 + sl
                - 32.0 * 1.8378770664093453
                + logpi[k];
  }

  // ---- samples: L^T e = eps (10 RHS), x = 0.5 t + eps/sqrt(2)
  double rr[S_];
  {
    uint32_t base = (uint32_t)((nk * 64 + i) * S_);
#pragma unroll
    for (int s = 0; s < S_; ++s)
      rr[s] = (double)jax_normal_f32(0u, 42u, base + s);
  }
  for (int q = 63; q >= 0; --q) {
    double lq = (i < q) ? Sp[((q * (q + 1)) >> 1) + i] : 0.0;
#pragma unroll
    for (int s = 0; s < S_; ++s) {
      double rq = __shfl(rr[s] * linv, q, 64);
      if (i == q) rr[s] = rq;
      else rr[s] = fma(-lq, rq, rr[s]);
    }
  }
  double xm = 0.5 * tv;
#pragma unroll
  for (int s = 0; s < S_; ++s)
    xs[(nk * S_ + s) * 64 + i] = (float)(xm + 0.7071067811865476 * rr[s]);
}

// ---------------- softmax over K + categorical (s=0) + x_subsamples ----------------
__global__ __launch_bounds__(64) void k_softcat(const double* __restrict__ logprob,
                                                const float* __restrict__ xs,
                                                float* __restrict__ outz,
                                                float* __restrict__ outx) {
  __shared__ double lz[K_];
  __shared__ int zc;
  int n = blockIdx.x, t = threadIdx.x;
  if (t == 0) {
    double lp[K_];
    double m = -1e300;
    for (int q = 0; q < K_; ++q) { lp[q] = logprob[n * K_ + q]; m = fmax(m, lp[q]); }
    double ss = 0.0;
    for (int q = 0; q < K_; ++q) ss += exp(lp[q] - m);
    double lsum = log(ss);
    float best = -INFINITY; int bi = 0;
    for (int q = 0; q < K_; ++q) {
      double l = (lp[q] - m) - lsum;
      lz[q] = l;
      float g = jax_gumbel_f32(0u, 7u, (uint32_t)(n * 100 + q));
      float sc = g + (float)l;
      if (sc > best) { best = sc; bi = q; }
    }
    zc = bi;
  }
  __syncthreads();
  if (t < K_) outz[n * K_ + t] = (float)lz[t];
  outx[n * D_ + t] = xs[(n * K_ + zc) * S_ * D_ + t];
}

// ---------------- decoder: MFMA bf16, 64 rows/block, 4 waves, ct-split GEMM2 ----------------
// hdF fragment-major layout: hdF[(rg*16+ks)*64 + lane][8] bf16, 64KB total.
// GEMM2: waves split the 49 col-tiles; each wave computes all 64 rows for its tiles,
// so B-fragments are loaded once per block (4x less L2 traffic), A read conflict-free.
__global__ __launch_bounds__(256) void k_dec(const float* __restrict__ xs,
                                             const ushort* __restrict__ W1F,
                                             const ushort* __restrict__ WmuF,
                                             const ushort* __restrict__ WvF,
                                             const float* __restrict__ b1,
                                             const float* __restrict__ bmu,
                                             const float* __restrict__ bvv,
                                             float* __restrict__ outm,
                                             float* __restrict__ outv) {
  __shared__ __align__(16) ushort hdF[32768];   // 64 KB, fragment-major
  int t = threadIdx.x;
  int w = t >> 6, l = t & 63;
  int lr = l & 15, lg = l >> 4;
  int row0 = blockIdx.x * 64;
  int wrow0 = row0 + w * 16;

  // ---- x A-fragments, bf16 split (hi+lo)
  short8v xhi[2], xlo[2];
  {
    const float* xrow = xs + (size_t)(wrow0 + lr) * 64 + lg * 8;
#pragma unroll
    for (int ks = 0; ks < 2; ++ks) {
      ushort hi[8], lo[8];
#pragma unroll
      for (int e = 0; e < 8; ++e) {
        float xv = xrow[ks * 32 + e];
        ushort h16 = bf16rne(xv);
        hi[e] = h16;
        lo[e] = bf16rne(xv - bf2f(h16));
      }
      xhi[ks] = *(short8v*)hi;
      xlo[ks] = *(short8v*)lo;
    }
  }

  // ---- GEMM1: hd = tanh(x @ W1 + b1); store in fragment-major LDS
  const short8v* W1v = (const short8v*)W1F;
#pragma unroll 4
  for (int ct = 0; ct < 32; ++ct) {
    f32x4 acc = {0.f, 0.f, 0.f, 0.f};
    short8v b0 = W1v[(ct * 2 + 0) * 64 + l];
    short8v b1v = W1v[(ct * 2 + 1) * 64 + l];
    acc = __builtin_amdgcn_mfma_f32_16x16x32_bf16(xhi[0], b0, acc, 0, 0, 0);
    acc = __builtin_amdgcn_mfma_f32_16x16x32_bf16(xlo[0], b0, acc, 0, 0, 0);
    acc = __builtin_amdgcn_mfma_f32_16x16x32_bf16(xhi[1], b1v, acc, 0, 0, 0);
    acc = __builtin_amdgcn_mfma_f32_16x16x32_bf16(xlo[1], b1v, acc, 0, 0, 0);
    int c = ct * 16 + lr;
    float bb = b1[c];
    int ks = ct >> 1;
    int blk = ((ct & 1) << 1) | (lr >> 3);
    int eo = lr & 7;
#pragma unroll
    for (int r = 0; r < 4; ++r) {
      int l2 = (lg * 4 + r) + 16 * blk;
      hdF[(((w * 16 + ks) * 64) + l2) * 8 + eo] = bf16rne(tanhf(acc[r] + bb));
    }
  }
  __syncthreads();

  // ---- GEMM2: this wave handles col-tiles ci = w, w+4, ... (all 64 rows each)
  const short8v* hdv = (const short8v*)hdF;
  const short8v* Wmv = (const short8v*)WmuF;
  const short8v* Wvv = (const short8v*)WvF;
  for (int ci = w; ci < 49; ci += 4) {
    f32x4 aM[4], aV[4];
#pragma unroll
    for (int rg = 0; rg < 4; ++rg) {
      aM[rg] = (f32x4){0.f, 0.f, 0.f, 0.f};
      aV[rg] = (f32x4){0.f, 0.f, 0.f, 0.f};
    }
#pragma unroll 4
    for (int ks = 0; ks < 16; ++ks) {
      short8v bm = Wmv[(ci * 16 + ks) * 64 + l];
      short8v bv = Wvv[(ci * 16 + ks) * 64 + l];
#pragma unroll
      for (int rg = 0; rg < 4; ++rg) {
        short8v ha = hdv[(rg * 16 + ks) * 64 + l];
        aM[rg] = __builtin_amdgcn_mfma_f32_16x16x32_bf16(ha, bm, aM[rg], 0, 0, 0);
        aV[rg] = __builtin_amdgcn_mfma_f32_16x16x32_bf16(ha, bv, aV[rg], 0, 0, 0);
      }
    }
    int c = ci * 16 + lr;
    float bm_ = bmu[c], bv_ = bvv[c];
#pragma unroll
    for (int rg = 0; rg < 4; ++rg) {
#pragma unroll
      for (int r = 0; r < 4; ++r) {
        size_t o = (size_t)(row0 + rg * 16 + lg * 4 + r) * INDIM_ + c;
        outm[o] = aM[rg][r] + bm_;
        outv[o] = sp32(aV[rg][r] + bv_) + 1e-6f;
      }
    }
  }
}

// ---------------- launch ----------------
extern "C" void kernel_launch(void* const* d_in, const int* in_sizes, int n_in,
                              void* d_out, int out_size, void* d_ws, size_t ws_size,
                              hipStream_t stream) {
  const float* y     = (const float*)d_in[0];
  const float* eW1   = (const float*)d_in[1];
  const float* eb1   = (const float*)d_in[2];
  const float* eWmu  = (const float*)d_in[3];
  const float* ebmu  = (const float*)d_in[4];
  const float* eWv   = (const float*)d_in[5];
  const float* ebv   = (const float*)d_in[6];
  const float* muk   = (const float*)d_in[7];
  const float* Lraw  = (const float*)d_in[8];
  const float* piraw = (const float*)d_in[9];
  const float* dW1   = (const float*)d_in[10];
  const float* db1   = (const float*)d_in[11];
  const float* dWmu  = (const float*)d_in[12];
  const float* dbmu  = (const float*)d_in[13];
  const float* dWv   = (const float*)d_in[14];
  const float* dbv   = (const float*)d_in[15];

  double* W      = (double*)d_ws;
  double* h      = W;             // 262144 doubles (reused as bf16 frag store by k_prep)
  double* mu     = W + 262144;    // 32768
  double* dvec   = W + 294912;    // 32768
  double* gk     = W + 327680;    // 640
  double* iJ     = W + 368640;    // 40960
  double* logpi  = W + 409600;    // 16
  double* logpr  = W + 409616;    // 5120
  double* quadg  = W + 414736;    // 5120
  double* base2  = W + 419856;
  float*  xs     = (float*)base2;                 // 3,276,800 floats
  float*  J32    = xs + 3276800;                  // 40960 floats
  float*  LU32   = J32 + 40960;                   // 40960
  float*  d32    = LU32 + 40960;                  // 32768
  float*  muph   = d32 + 32768;                   // 32768
  int*    piv    = (int*)(muph + 32768);          // 640 ints

  ushort* hF   = (ushort*)h;
  ushort* W1F  = hF;
  ushort* WmuF = hF + 32768;
  ushort* WvF  = hF + 434176;

  float* outm = (float*)d_out;            // (N,K,S,784)
  float* outv = outm + 40140800;          // (N,K,S,784)
  float* outx = outm + 80281600;          // (N,64)
  float* outz = outm + 80314368;          // (N,10)

  k_enc_h    <<<N_, 256, 0, stream>>>(y, eW1, eb1, h);
  k_enc_muvar<<<N_, 128, 0, stream>>>(h, eWmu, ebmu, eWv, ebv, mu, dvec, d32, muph);
  k_prep     <<<408, 256, 0, stream>>>(dW1, dWmu, dWv, hF);
  k_gmm      <<<K_, 64, 0, stream>>>(Lraw, piraw, muk, iJ, gk, logpi);
  k_lu32     <<<K_, 64, 0, stream>>>(Lraw, J32, LU32, piv);
  k_quad32   <<<N_ * K_, 64, 0, stream>>>(J32, LU32, piv, d32, muph, quadg);
  k_pernk    <<<N_ * K_, 64, 0, stream>>>(dvec, mu, gk, iJ, logpi, quadg, logpr, xs);
  k_softcat  <<<N_, 64, 0, stream>>>(logpr, xs, outz, outx);
  k_dec      <<<800, 256, 0, stream>>>(xs, W1F, WmuF, WvF, db1, dbmu, dbv, outm, outv);
}

// Round 10
// 1301.029 us; speedup vs baseline: 4.0601x; 1.0148x over previous
//
#include <hip/hip_runtime.h>
#include <math.h>
#include <stdint.h>

#define N_ 512
#define D_ 64
#define K_ 10
#define S_ 10
#define INDIM_ 784
#define H_ 512
#define DP1 (D_ + 1)

typedef __attribute__((ext_vector_type(8))) short short8v;
typedef __attribute__((ext_vector_type(4))) float f32x4;

// even-aligned packed-triangle row offset: row r starts at even double-index
__device__ __forceinline__ int offr(int r) {
  return (r & 1) ? (((r + 1) * (r + 1)) >> 1) : ((r * (r + 2)) >> 1);
}

// ---------------- JAX Threefry-2x32 (20 rounds) ----------------
__device__ __forceinline__ uint32_t rotl32(uint32_t v, int r) { return (v << r) | (v >> (32 - r)); }

__device__ __forceinline__ void threefry2x32(uint32_t k0, uint32_t k1,
                                             uint32_t x0, uint32_t x1,
                                             uint32_t& o0, uint32_t& o1) {
  uint32_t k2 = k0 ^ k1 ^ 0x1BD11BDAu;
  x0 += k0; x1 += k1;
#define TFR(r) { x0 += x1; x1 = rotl32(x1, r); x1 ^= x0; }
  TFR(13) TFR(15) TFR(26) TFR(6)
  x0 += k1; x1 += k2 + 1u;
  TFR(17) TFR(29) TFR(16) TFR(24)
  x0 += k2; x1 += k0 + 2u;
  TFR(13) TFR(15) TFR(26) TFR(6)
  x0 += k0; x1 += k1 + 3u;
  TFR(17) TFR(29) TFR(16) TFR(24)
  x0 += k1; x1 += k2 + 4u;
  TFR(13) TFR(15) TFR(26) TFR(6)
  x0 += k2; x1 += k0 + 5u;
#undef TFR
  o0 = x0; o1 = x1;
}

__device__ __forceinline__ uint32_t jax_bits32(uint32_t k0, uint32_t k1, uint32_t idx) {
  uint32_t o0, o1; threefry2x32(k0, k1, 0u, idx, o0, o1);
  return o0 ^ o1;
}

__device__ __forceinline__ float bits_to_u01(uint32_t bits) {
  return __uint_as_float((bits >> 9) | 0x3F800000u) - 1.0f;
}

__device__ __forceinline__ float erfinv_f32(float x) {
  float w = -log1pf(-x * x);
  float p;
  if (w < 5.0f) {
    w = w - 2.5f;
    p = 2.81022636e-08f;
    p = fmaf(p, w, 3.43273939e-07f);
    p = fmaf(p, w, -3.5233877e-06f);
    p = fmaf(p, w, -4.39150654e-06f);
    p = fmaf(p, w, 0.00021858087f);
    p = fmaf(p, w, -0.00125372503f);
    p = fmaf(p, w, -0.00417768164f);
    p = fmaf(p, w, 0.246640727f);
    p = fmaf(p, w, 1.50140941f);
  } else {
    w = sqrtf(w) - 3.0f;
    p = -0.000200214257f;
    p = fmaf(p, w, 0.000100950558f);
    p = fmaf(p, w, 0.00134934322f);
    p = fmaf(p, w, -0.00367342844f);
    p = fmaf(p, w, 0.00573950773f);
    p = fmaf(p, w, -0.0076224613f);
    p = fmaf(p, w, 0.00943887047f);
    p = fmaf(p, w, 1.00167406f);
    p = fmaf(p, w, 2.83297682f);
  }
  return p * x;
}

__device__ __forceinline__ float jax_normal_f32(uint32_t k0, uint32_t k1, uint32_t idx) {
  uint32_t bits = jax_bits32(k0, k1, idx);
  float u = bits_to_u01(bits);
  const float lo = -0.99999994f;
  float v = u * (1.0f - lo) + lo;
  v = fmaxf(lo, v);
  return 1.41421356f * erfinv_f32(v);
}

__device__ __forceinline__ float jax_gumbel_f32(uint32_t k0, uint32_t k1, uint32_t idx) {
  uint32_t bits = jax_bits32(k0, k1, idx);
  float u = bits_to_u01(bits);
  const float tiny = 1.17549435e-38f;
  float v = u * (1.0f - tiny) + tiny;
  v = fmaxf(tiny, v);
  return -logf(-logf(v));
}

__device__ __forceinline__ float sp32(float x) { return fmaxf(x, 0.f) + log1pf(expf(-fabsf(x))); }
__device__ __forceinline__ float sp32cr(float x) {
  double xd = (double)x;
  return (float)(fmax(xd, 0.0) + log1p(exp(-fabs(xd))));
}
__device__ __forceinline__ double sp64(double x) { return fmax(x, 0.0) + log1p(exp(-fabs(x))); }

__device__ __forceinline__ ushort bf16rne(float f) {
  uint32_t u = __float_as_uint(f);
  uint32_t r = (u + 0x7FFFu + ((u >> 16) & 1u)) >> 16;
  return (ushort)r;
}
__device__ __forceinline__ float bf2f(ushort b) { return __uint_as_float(((uint32_t)b) << 16); }

// ---------------- encoder ----------------
__global__ __launch_bounds__(256) void k_enc_h(const float* __restrict__ y,
                                               const float* __restrict__ W1,
                                               const float* __restrict__ b1,
                                               double* __restrict__ h) {
  int n = blockIdx.x, t = threadIdx.x;
  const float* yr = y + n * INDIM_;
  double a0 = 0.0, a1 = 0.0;
  for (int d = 0; d < INDIM_; ++d) {
    double yv = (double)yr[d];
    a0 += yv * (double)W1[d * H_ + t];
    a1 += yv * (double)W1[d * H_ + t + 256];
  }
  h[n * H_ + t] = tanh(a0 + (double)b1[t]);
  h[n * H_ + t + 256] = tanh(a1 + (double)b1[t + 256]);
}

__global__ __launch_bounds__(128) void k_enc_muvar(const double* __restrict__ h,
                                                   const float* __restrict__ Wmu,
                                                   const float* __restrict__ bmu,
                                                   const float* __restrict__ Wv,
                                                   const float* __restrict__ bv,
                                                   double* __restrict__ mu,
                                                   double* __restrict__ dvec,
                                                   float* __restrict__ d32,
                                                   float* __restrict__ muph) {
  __shared__ float mu32s[D_], var32s[D_];
  int n = blockIdx.x, t = threadIdx.x;
  int c = t & 63;
  const float* Wsel = (t < 64) ? Wmu : Wv;
  const double* hr = h + n * H_;
  double acc = 0.0;
  for (int q = 0; q < H_; ++q) acc += hr[q] * (double)Wsel[q * D_ + c];
  if (t < 64) {
    double m = acc + (double)bmu[c];
    mu[n * D_ + c] = m;
    mu32s[c] = (float)m;
  } else {
    double a = acc + (double)bv[c];
    double var = sp64(a) + 1e-6;
    dvec[n * D_ + c] = -0.5 / var;
    float var32 = sp32cr((float)a) + 1e-6f;
    var32s[c] = var32;
    d32[n * D_ + c] = (-0.5f) / var32;
  }
  __syncthreads();
  if (t < 64) {
    float var32 = var32s[c];
    float dd = (-0.5f) / var32;
    float eta1 = mu32s[c] / var32;
    float neg2d = -2.0f * dd;
    muph[n * D_ + c] = eta1 / neg2d;
  }
}

// ---------------- weight re-layout to MFMA fragment order (bf16) ----------------
__global__ __launch_bounds__(256) void k_prep(const float* __restrict__ W1,
                                              const float* __restrict__ Wmu,
                                              const float* __restrict__ Wv,
                                              ushort* __restrict__ hF) {
  int t = blockIdx.x * 256 + threadIdx.x;
  int chunk = t >> 6, l = t & 63;
  if (chunk >= 1632) return;
  int lr = l & 15, lg = l >> 4;
  const float* src; int C, ct, ks; ushort* dst;
  if (chunk < 64)       { src = W1;  C = 512; ct = chunk >> 1;  ks = chunk & 1;
                          dst = hF + chunk * 512; }
  else if (chunk < 848) { int c2 = chunk - 64;  src = Wmu; C = 784; ct = c2 / 16; ks = c2 % 16;
                          dst = hF + 32768 + c2 * 512; }
  else                  { int c2 = chunk - 848; src = Wv;  C = 784; ct = c2 / 16; ks = c2 % 16;
                          dst = hF + 434176 + c2 * 512; }
  ushort vals[8];
#pragma unroll
  for (int e = 0; e < 8; ++e)
    vals[e] = bf16rne(src[(ks * 32 + lg * 8 + e) * C + ct * 16 + lr]);
  *(short8v*)(dst + l * 8) = *(short8v*)vals;
}

// ---------------- GMM unpack: invJ_k, g_k = B^{-1}mu_k, log pi ----------------
__global__ __launch_bounds__(64) void k_gmm(const float* __restrict__ Lraw,
                                            const float* __restrict__ piraw,
                                            const float* __restrict__ muk,
                                            double* __restrict__ iJout,
                                            double* __restrict__ gko,
                                            double* __restrict__ logpi) {
  __shared__ float Lk[D_][DP1];
  __shared__ double dg[D_];
  __shared__ double Li[D_][DP1];
  int k = blockIdx.x, i = threadIdx.x;
  const float* Lr = Lraw + k * D_ * D_;
  for (int j = 0; j < i; ++j) Lk[i][j] = Lr[i * D_ + j];
  dg[i] = sp64((double)Lr[i * D_ + i]);
  __syncthreads();
#define LKD(r, c) ((c) < (r) ? (double)Lk[r][c] : dg[r])
  {
    int j = i;
    Li[j][j] = 1.0 / dg[j];
    for (int r = j + 1; r < D_; ++r) {
      double s = 0.0;
      for (int m = j; m < r; ++m) s += LKD(r, m) * Li[m][j];
      Li[r][j] = -s / dg[r];
    }
  }
  __syncthreads();
  for (int j = 0; j < D_; ++j) {
    int m0 = max(i, j);
    double s = 0.0;
    for (int m = m0; m < D_; ++m) s += Li[m][i] * Li[m][j];
    iJout[k * D_ * D_ + i * D_ + j] = -2.0 * s;
  }
#undef LKD
  // g_k = 2 * Lk^{-T} (Lk^{-1} mu_k)   (B = 0.5 Lk Lk^T)
  {
    double rv = (double)muk[k * D_ + i];
    for (int j = 0; j < D_; ++j) {
      double xj = __shfl(rv, j, 64) / dg[j];
      if (i == j) rv = xj;
      else if (i > j) rv -= (double)Lk[i][j] * xj;
    }
    for (int j = D_ - 1; j >= 0; --j) {
      double xj = __shfl(rv, j, 64) / dg[j];
      if (i == j) rv = xj;
      else if (i < j) rv -= (double)Lk[j][i] * xj;
    }
    gko[k * D_ + i] = 2.0 * rv;
  }
  if (k == 0 && i == 0) {
    double m = (double)piraw[0];
    for (int q = 1; q < K_; ++q) m = fmax(m, (double)piraw[q]);
    double ss = 0.0;
    for (int q = 0; q < K_; ++q) ss += exp((double)piraw[q] - m);
    double lse = m + log(ss);
    for (int q = 0; q < K_; ++q) logpi[q] = (double)piraw[q] - lse;
  }
}

// ---------------- f32 LAPACK-emulation: J32 (f32 sgemm-fold) + sgetf2 LU (per k) ----------------
__global__ __launch_bounds__(64) void k_lu32(const float* __restrict__ Lraw,
                                             float* __restrict__ J32g,
                                             float* __restrict__ LU32g,
                                             int* __restrict__ pivg) {
  __shared__ float Lk[D_][DP1];
  __shared__ float A[D_][DP1];
  __shared__ float col[D_];
  __shared__ int piv_s[D_];
  int k = blockIdx.x, i = threadIdx.x;
  const float* Lr = Lraw + k * D_ * D_;
  for (int j = 0; j < D_; ++j)
    Lk[i][j] = (j < i) ? Lr[i * D_ + j] : ((j == i) ? sp32cr(Lr[i * D_ + i]) : 0.0f);
  __syncthreads();
  for (int j = 0; j < D_; ++j) {
    float s = 0.0f;
    for (int q = 0; q < D_; ++q) s = fmaf(Lk[i][q], Lk[j][q], s);
    float v = -0.5f * s;
    A[i][j] = v;
    J32g[k * D_ * D_ + i * D_ + j] = v;
  }
  __syncthreads();
  for (int j = 0; j < D_; ++j) {
    col[i] = fabsf(A[i][j]);
    __syncthreads();
    if (i == 0) {
      int p = j; float mx = col[j];
      for (int r = j + 1; r < D_; ++r) if (col[r] > mx) { mx = col[r]; p = r; }
      piv_s[j] = p;
    }
    __syncthreads();
    int p = piv_s[j];
    if (p != j) { float tmp = A[j][i]; A[j][i] = A[p][i]; A[p][i] = tmp; }
    __syncthreads();
    float rec = 1.0f / A[j][j];
    if (i > j) A[i][j] = A[i][j] * rec;
    __syncthreads();
    if (i > j) {
      float x = A[i][j];
      for (int l = j + 1; l < D_; ++l) A[i][l] = fmaf(x, -A[j][l], A[i][l]);
    }
    __syncthreads();
  }
  for (int j = 0; j < D_; ++j) LU32g[k * D_ * D_ + i * D_ + j] = A[i][j];
  pivg[k * D_ + i] = piv_s[i];
}

// ---------------- f32-emulated quad2 per (n,k) — register-column solves ----------------
__global__ __launch_bounds__(64) void k_quad32(const float* __restrict__ J32g,
                                               const float* __restrict__ LU32g,
                                               const int* __restrict__ pivg,
                                               const float* __restrict__ d32g,
                                               const float* __restrict__ muphg,
                                               double* __restrict__ quadg) {
  __shared__ float LUs[D_][DP1];
  __shared__ float dsh[D_], mph[D_];
  __shared__ int pshare[D_];
  __shared__ double red[D_];
  int nk = blockIdx.x;
  int n = nk / K_, k = nk - n * K_;
  int tj = threadIdx.x;
  for (int r = 0; r < D_; ++r) LUs[r][tj] = LU32g[k * 4096 + r * 64 + tj];
  dsh[tj] = d32g[n * 64 + tj];
  mph[tj] = muphg[n * 64 + tj];
  int pv = pivg[k * 64 + tj];
  int perm = tj;
  for (int j = 0; j < 64; ++j) {
    int pj = __shfl(pv, j, 64);
    int vj = __shfl(perm, j, 64);
    int vp = __shfl(perm, pj, 64);
    if (tj == j) perm = vp;
    else if (tj == pj) perm = vj;
  }
  pshare[tj] = perm;
  __syncthreads();
  float Tc[64];
#pragma unroll
  for (int i2 = 0; i2 < 64; ++i2) {
    int pr = pshare[i2];
    float v = J32g[k * 4096 + pr * 64 + tj];
    if (pr == tj) v = v + dsh[tj];
    Tc[i2] = v;
  }
#pragma unroll
  for (int r = 0; r < 64; ++r) {
    float x = Tc[r];
#pragma unroll
    for (int i2 = r + 1; i2 < 64; ++i2)
      Tc[i2] = fmaf(LUs[i2][r], -x, Tc[i2]);
  }
#pragma unroll
  for (int r = 63; r >= 0; --r) {
    float x = Tc[r] / LUs[r][r];
    Tc[r] = x;
#pragma unroll
    for (int i2 = 0; i2 < r; ++i2)
      Tc[i2] = fmaf(LUs[i2][r], -x, Tc[i2]);
  }
  __syncthreads();
#pragma unroll
  for (int i2 = 0; i2 < 64; ++i2) LUs[i2][tj] = Tc[i2];
  __syncthreads();
  double part = 0.0;
#pragma unroll
  for (int d2 = 0; d2 < 64; ++d2) {
    float a = dsh[d2] * Tc[d2];
    float b = dsh[tj] * LUs[tj][d2];
    float w = 0.5f * (a + b);
    float t1 = mph[d2] * w;
    float t2 = t1 * mph[tj];
    part += (double)t2;
  }
  red[tj] = part; __syncthreads();
  for (int off = 32; off > 0; off >>= 1) {
    if (tj < off) red[tj] += red[tj + off];
    __syncthreads();
  }
  if (tj == 0) quadg[nk] = red[0];
}

// ---------------- per-(n,k): left-looking LDS Cholesky, b128 paired reads ----------------
__global__ __launch_bounds__(64) void k_pernk(const double* __restrict__ dvec,
                                              const double* __restrict__ mu,
                                              const double* __restrict__ gk,
                                              const double* __restrict__ iJg,
                                              const double* __restrict__ logpi,
                                              const double* __restrict__ quadg,
                                              double* __restrict__ logprob,
                                              float* __restrict__ xs) {
  __shared__ __align__(16) double Sp[2112];   // even-aligned packed lower L
  int nk = blockIdx.x;
  int n = nk / K_, k = nk - n * K_;
  int i = threadIdx.x;
  int Ti = offr(i);

  double dn = dvec[n * 64 + i];
  double mn = mu[n * 64 + i];
  const double* iJ = iJg + k * 4096;

  // ---- left-looking Cholesky of P = -(Dg iJ Dg) - Dg
  double linv = 0.0, ljj = 1.0;
  for (int j = 0; j < 64; ++j) {
    double dj = __shfl(dn, j, 64);
    double v = -(dn * iJ[j * 64 + i] * dj);   // P[i][j] (iJ symmetric, coalesced)
    if (i == j) v -= dn;
    int Tj = offr(j);
    // dot over q < j: paired b128 reads, 4 accumulators
    {
      const double2* Ri = (const double2*)(Sp + Ti);
      const double2* Rj = (const double2*)(Sp + Tj);
      double a0 = 0.0, a1 = 0.0, a2 = 0.0, a3 = 0.0;
      int pairs = j >> 1;
      int p = 0;
      for (; p + 1 < pairs; p += 2) {
        double2 x0 = Ri[p],     y0 = Rj[p];
        double2 x1 = Ri[p + 1], y1 = Rj[p + 1];
        a0 = fma(x0.x, y0.x, a0);
        a1 = fma(x0.y, y0.y, a1);
        a2 = fma(x1.x, y1.x, a2);
        a3 = fma(x1.y, y1.y, a3);
      }
      if (p < pairs) {
        double2 x0 = Ri[p], y0 = Rj[p];
        a0 = fma(x0.x, y0.x, a0);
        a1 = fma(x0.y, y0.y, a1);
      }
      if (j & 1) a2 = fma(Sp[Ti + j - 1], Sp[Tj + j - 1], a2);
      v -= ((a0 + a1) + (a2 + a3));
    }
    double sj = __shfl(v, j, 64);             // pivot d_jj from lane j
    double s_ = sqrt(sj);
    double lc = 1.0 / s_;                     // uniform; one divide per column
    double li = (i == j) ? s_ : v * lc;
    if (i >= j) Sp[Ti + j] = li;
    if (i == j) { linv = lc; ljj = s_; }
    __syncthreads();
  }

  // ---- two-RHS solve: z = P^{-1}(E g_k)  and  u = P^{-1} d  (t = s_nk*u)
  double rv = (-dn) * gk[k * 64 + i];
  double uv = dn;
  for (int j = 0; j < 64; ++j) {
    double xz = __shfl(rv * linv, j, 64);
    double xu = __shfl(uv * linv, j, 64);
    double lij = (i > j) ? Sp[Ti + j] : 0.0;
    if (i == j) { rv = xz; uv = xu; }
    else { rv = fma(-lij, xz, rv); uv = fma(-lij, xu, uv); }
  }
  for (int j = 63; j >= 0; --j) {
    double xz = __shfl(rv * linv, j, 64);
    double xu = __shfl(uv * linv, j, 64);
    double lij = (i < j) ? Sp[offr(j) + i] : 0.0;
    if (i == j) { rv = xz; uv = xu; }
    else { rv = fma(-lij, xz, rv); uv = fma(-lij, xu, uv); }
  }
  double zsum = rv;
  for (int o = 32; o > 0; o >>= 1) zsum += __shfl_xor(zsum, o, 64);
  double s_nk = -zsum;
  double w1 = s_nk * dn;
  double tv = s_nk * uv;
  double dmw = mn * w1;
  for (int o = 32; o > 0; o >>= 1) dmw += __shfl_xor(dmw, o, 64);
  double dwt = w1 * tv;
  for (int o = 32; o > 0; o >>= 1) dwt += __shfl_xor(dwt, o, 64);
  double sl = log(ljj);
  for (int o = 32; o > 0; o >>= 1) sl += __shfl_xor(sl, o, 64);
  if (i == 0) {
    logprob[nk] = dmw + quadg[nk] - 0.25 * dwt
                + 32.0 * 0.6931471805599453 + sl
                - 32.0 * 1.8378770664093453
                + logpi[k];
  }

  // ---- samples: L^T e = eps (10 RHS), x = 0.5 t + eps/sqrt(2)
  double rr[S_];
  {
    uint32_t base = (uint32_t)((nk * 64 + i) * S_);
#pragma unroll
    for (int s = 0; s < S_; ++s)
      rr[s] = (double)jax_normal_f32(0u, 42u, base + s);
  }
  for (int q = 63; q >= 0; --q) {
    double lq = (i < q) ? Sp[offr(q) + i] : 0.0;
#pragma unroll
    for (int s = 0; s < S_; ++s) {
      double rq = __shfl(rr[s] * linv, q, 64);
      if (i == q) rr[s] = rq;
      else rr[s] = fma(-lq, rq, rr[s]);
    }
  }
  double xm = 0.5 * tv;
#pragma unroll
  for (int s = 0; s < S_; ++s)
    xs[(nk * S_ + s) * 64 + i] = (float)(xm + 0.7071067811865476 * rr[s]);
}

// ---------------- softmax over K + categorical (s=0) + x_subsamples ----------------
__global__ __launch_bounds__(64) void k_softcat(const double* __restrict__ logprob,
                                                const float* __restrict__ xs,
                                                float* __restrict__ outz,
                                                float* __restrict__ outx) {
  __shared__ double lz[K_];
  __shared__ int zc;
  int n = blockIdx.x, t = threadIdx.x;
  if (t == 0) {
    double lp[K_];
    double m = -1e300;
    for (int q = 0; q < K_; ++q) { lp[q] = logprob[n * K_ + q]; m = fmax(m, lp[q]); }
    double ss = 0.0;
    for (int q = 0; q < K_; ++q) ss += exp(lp[q] - m);
    double lsum = log(ss);
    float best = -INFINITY; int bi = 0;
    for (int q = 0; q < K_; ++q) {
      double l = (lp[q] - m) - lsum;
      lz[q] = l;
      float g = jax_gumbel_f32(0u, 7u, (uint32_t)(n * 100 + q));
      float sc = g + (float)l;
      if (sc > best) { best = sc; bi = q; }
    }
    zc = bi;
  }
  __syncthreads();
  if (t < K_) outz[n * K_ + t] = (float)lz[t];
  outx[n * D_ + t] = xs[(n * K_ + zc) * S_ * D_ + t];
}

// ---------------- decoder: MFMA bf16, 64 rows/block, 4 waves, ct-split GEMM2 ----------------
__global__ __launch_bounds__(256) void k_dec(const float* __restrict__ xs,
                                             const ushort* __restrict__ W1F,
                                             const ushort* __restrict__ WmuF,
                                             const ushort* __restrict__ WvF,
                                             const float* __restrict__ b1,
                                             const float* __restrict__ bmu,
                                             const float* __restrict__ bvv,
                                             float* __restrict__ outm,
                                             float* __restrict__ outv) {
  __shared__ __align__(16) ushort hdF[32768];   // 64 KB, fragment-major
  int t = threadIdx.x;
  int w = t >> 6, l = t & 63;
  int lr = l & 15, lg = l >> 4;
  int row0 = blockIdx.x * 64;
  int wrow0 = row0 + w * 16;

  short8v xhi[2], xlo[2];
  {
    const float* xrow = xs + (size_t)(wrow0 + lr) * 64 + lg * 8;
#pragma unroll
    for (int ks = 0; ks < 2; ++ks) {
      ushort hi[8], lo[8];
#pragma unroll
      for (int e = 0; e < 8; ++e) {
        float xv = xrow[ks * 32 + e];
        ushort h16 = bf16rne(xv);
        hi[e] = h16;
        lo[e] = bf16rne(xv - bf2f(h16));
      }
      xhi[ks] = *(short8v*)hi;
      xlo[ks] = *(short8v*)lo;
    }
  }

  const short8v* W1v = (const short8v*)W1F;
#pragma unroll 4
  for (int ct = 0; ct < 32; ++ct) {
    f32x4 acc = {0.f, 0.f, 0.f, 0.f};
    short8v b0 = W1v[(ct * 2 + 0) * 64 + l];
    short8v b1v = W1v[(ct * 2 + 1) * 64 + l];
    acc = __builtin_amdgcn_mfma_f32_16x16x32_bf16(xhi[0], b0, acc, 0, 0, 0);
    acc = __builtin_amdgcn_mfma_f32_16x16x32_bf16(xlo[0], b0, acc, 0, 0, 0);
    acc = __builtin_amdgcn_mfma_f32_16x16x32_bf16(xhi[1], b1v, acc, 0, 0, 0);
    acc = __builtin_amdgcn_mfma_f32_16x16x32_bf16(xlo[1], b1v, acc, 0, 0, 0);
    int c = ct * 16 + lr;
    float bb = b1[c];
    int ks = ct >> 1;
    int blk = ((ct & 1) << 1) | (lr >> 3);
    int eo = lr & 7;
#pragma unroll
    for (int r = 0; r < 4; ++r) {
      int l2 = (lg * 4 + r) + 16 * blk;
      hdF[(((w * 16 + ks) * 64) + l2) * 8 + eo] = bf16rne(tanhf(acc[r] + bb));
    }
  }
  __syncthreads();

  const short8v* hdv = (const short8v*)hdF;
  const short8v* Wmv = (const short8v*)WmuF;
  const short8v* Wvv = (const short8v*)WvF;
  for (int ci = w; ci < 49; ci += 4) {
    f32x4 aM[4], aV[4];
#pragma unroll
    for (int rg = 0; rg < 4; ++rg) {
      aM[rg] = (f32x4){0.f, 0.f, 0.f, 0.f};
      aV[rg] = (f32x4){0.f, 0.f, 0.f, 0.f};
    }
#pragma unroll 4
    for (int ks = 0; ks < 16; ++ks) {
      short8v bm = Wmv[(ci * 16 + ks) * 64 + l];
      short8v bv = Wvv[(ci * 16 + ks) * 64 + l];
#pragma unroll
      for (int rg = 0; rg < 4; ++rg) {
        short8v ha = hdv[(rg * 16 + ks) * 64 + l];
        aM[rg] = __builtin_amdgcn_mfma_f32_16x16x32_bf16(ha, bm, aM[rg], 0, 0, 0);
        aV[rg] = __builtin_amdgcn_mfma_f32_16x16x32_bf16(ha, bv, aV[rg], 0, 0, 0);
      }
    }
    int c = ci * 16 + lr;
    float bm_ = bmu[c], bv_ = bvv[c];
#pragma unroll
    for (int rg = 0; rg < 4; ++rg) {
#pragma unroll
      for (int r = 0; r < 4; ++r) {
        size_t o = (size_t)(row0 + rg * 16 + lg * 4 + r) * INDIM_ + c;
        outm[o] = aM[rg][r] + bm_;
        outv[o] = sp32(aV[rg][r] + bv_) + 1e-6f;
      }
    }
  }
}

// ---------------- launch ----------------
extern "C" void kernel_launch(void* const* d_in, const int* in_sizes, int n_in,
                              void* d_out, int out_size, void* d_ws, size_t ws_size,
                              hipStream_t stream) {
  const float* y     = (const float*)d_in[0];
  const float* eW1   = (const float*)d_in[1];
  const float* eb1   = (const float*)d_in[2];
  const float* eWmu  = (const float*)d_in[3];
  const float* ebmu  = (const float*)d_in[4];
  const float* eWv   = (const float*)d_in[5];
  const float* ebv   = (const float*)d_in[6];
  const float* muk   = (const float*)d_in[7];
  const float* Lraw  = (const float*)d_in[8];
  const float* piraw = (const float*)d_in[9];
  const float* dW1   = (const float*)d_in[10];
  const float* db1   = (const float*)d_in[11];
  const float* dWmu  = (const float*)d_in[12];
  const float* dbmu  = (const float*)d_in[13];
  const float* dWv   = (const float*)d_in[14];
  const float* dbv   = (const float*)d_in[15];

  double* W      = (double*)d_ws;
  double* h      = W;             // 262144 doubles (reused as bf16 frag store by k_prep)
  double* mu     = W + 262144;    // 32768
  double* dvec   = W + 294912;    // 32768
  double* gk     = W + 327680;    // 640
  double* iJ     = W + 368640;    // 40960
  double* logpi  = W + 409600;    // 16
  double* logpr  = W + 409616;    // 5120
  double* quadg  = W + 414736;    // 5120
  double* base2  = W + 419856;
  float*  xs     = (float*)base2;                 // 3,276,800 floats
  float*  J32    = xs + 3276800;                  // 40960 floats
  float*  LU32   = J32 + 40960;                   // 40960
  float*  d32    = LU32 + 40960;                  // 32768
  float*  muph   = d32 + 32768;                   // 32768
  int*    piv    = (int*)(muph + 32768);          // 640 ints

  ushort* hF   = (ushort*)h;
  ushort* W1F  = hF;
  ushort* WmuF = hF + 32768;
  ushort* WvF  = hF + 434176;

  float* outm = (float*)d_out;            // (N,K,S,784)
  float* outv = outm + 40140800;          // (N,K,S,784)
  float* outx = outm + 80281600;          // (N,64)
  float* outz = outm + 80314368;          // (N,10)

  k_enc_h    <<<N_, 256, 0, stream>>>(y, eW1, eb1, h);
  k_enc_muvar<<<N_, 128, 0, stream>>>(h, eWmu, ebmu, eWv, ebv, mu, dvec, d32, muph);
  k_prep     <<<408, 256, 0, stream>>>(dW1, dWmu, dWv, hF);
  k_gmm      <<<K_, 64, 0, stream>>>(Lraw, piraw, muk, iJ, gk, logpi);
  k_lu32     <<<K_, 64, 0, stream>>>(Lraw, J32, LU32, piv);
  k_quad32   <<<N_ * K_, 64, 0, stream>>>(J32, LU32, piv, d32, muph, quadg);
  k_pernk    <<<N_ * K_, 64, 0, stream>>>(dvec, mu, gk, iJ, logpi, quadg, logpr, xs);
  k_softcat  <<<N_, 64, 0, stream>>>(logpr, xs, outz, outx);
  k_dec      <<<800, 256, 0, stream>>>(xs, W1F, WmuF, WvF, db1, dbmu, dbv, outm, outv);
}